// Round 11
// baseline (1654.102 us; speedup 1.0000x reference)
//
#include <hip/hip_runtime.h>
#include <math.h>

#define NP 65160        // 181*360
#define NPAD 65280

typedef unsigned short u16;
typedef __attribute__((ext_vector_type(8))) short bf16x8;
typedef __attribute__((ext_vector_type(8))) unsigned short us8;
typedef __attribute__((ext_vector_type(4))) float f32x4;

__device__ __forceinline__ u16 f2bf(float f){
    unsigned u = __builtin_bit_cast(unsigned, f);
    return (u16)((u + 0x7FFFu + ((u>>16)&1u)) >> 16);
}
__device__ __forceinline__ float bf2f(u16 h){
    unsigned u = ((unsigned)h)<<16;
    return __builtin_bit_cast(float, u);
}
__device__ __forceinline__ float gelu_f(float x){
    return 0.5f*x*(1.0f+erff(x*0.70710678118654752f));
}

__global__ void k_zero(u16* __restrict__ p, long n){
    long i = ((long)blockIdx.x*256 + threadIdx.x)*8;
    if(i+8 <= n){ us8 z = {0,0,0,0,0,0,0,0}; *(us8*)(p+i) = z; }
}

// ============ B packs: dst[kg][n][8], k = kg*8+e, zero padded ============
__global__ void k_pack_twf(u16* __restrict__ dst){   // [48][384][8]: k=w, n=2kw+q
    int i = blockIdx.x*256+threadIdx.x; if(i >= 48*384*8) return;
    int e = i&7, n = (i>>3)%384, kg = i/(384*8);
    int k = kg*8+e, kw = n>>1, q = n&1;
    float v = 0.0f;
    if(k < 360 && kw < 181){
        float inv = 1.0f/sqrtf(65160.0f);
        float th = 6.28318530717958647692f*(float)((k*kw)%360)/360.0f;
        v = q ? -sinf(th)*inv : cosf(th)*inv;
    }
    dst[i] = f2bf(v);
}
__global__ void k_pack_thf(u16* __restrict__ dst){   // [64][384][8]: k=2h+q, n=2kh+p
    int i = blockIdx.x*256+threadIdx.x; if(i >= 64*384*8) return;
    int e = i&7, n = (i>>3)%384, kg = i/(384*8);
    int k = kg*8+e;
    float v = 0.0f;
    if(k < 362 && n < 362){
        int h = k>>1, q = k&1, kh = n>>1, p = n&1;
        float th = 6.28318530717958647692f*(float)((h*kh)%181)/181.0f;
        float c = cosf(th), s = sinf(th);
        v = (q==0) ? (p==0? c : -s) : (p==0? s : c);
    }
    dst[i] = f2bf(v);
}
__global__ void k_pack_thi(u16* __restrict__ dst){   // [48][384][8]: k=2kh+p, n=2h+q
    int i = blockIdx.x*256+threadIdx.x; if(i >= 48*384*8) return;
    int e = i&7, n = (i>>3)%384, kg = i/(384*8);
    int k = kg*8+e;
    float v = 0.0f;
    if(k < 362 && n < 362){
        int kh = k>>1, p = k&1, h = n>>1, q = n&1;
        float th = 6.28318530717958647692f*(float)((kh*h)%181)/181.0f;
        float c = cosf(th), s = sinf(th);
        v = (q==0) ? (p==0? c : -s) : (p==0? s : c);
    }
    dst[i] = f2bf(v);
}
__global__ void k_pack_twi(u16* __restrict__ dst){   // [48][384][8]: k=2kw+q, n=w
    int i = blockIdx.x*256+threadIdx.x; if(i >= 48*384*8) return;
    int e = i&7, n = (i>>3)%384, kg = i/(384*8);
    int k = kg*8+e, kw = k>>1, q = k&1;
    float v = 0.0f;
    if(k < 362 && n < 360){
        float inv = 1.0f/sqrtf(65160.0f);
        float eps = (kw==0 || kw==180) ? 1.0f : 2.0f;
        float th = 6.28318530717958647692f*(float)((n*kw)%360)/360.0f;
        v = q ? -eps*sinf(th)*inv : eps*cosf(th)*inv;
    }
    dst[i] = f2bf(v);
}
__global__ void k_pack_cw(const float* __restrict__ src, u16* __restrict__ dst,
                          int CIN, int COUT, int lss, int lsd){
    int z = blockIdx.z;
    int Npad = 2*COUT, KG = (2*CIN)/8;
    int tot = KG*Npad*8;
    int i = blockIdx.x*256+threadIdx.x; if(i >= tot) return;
    int e = i&7, n = (i>>3)%Npad, kg = i/(Npad*8);
    int k = kg*8+e, ci = k>>1, q = k&1, co = n>>1, p = n&1;
    float re = src[(size_t)z*lss + ci*COUT + co];
    float im = src[(size_t)z*lss + CIN*COUT + ci*COUT + co];
    float v = (p==0) ? (q==0? re : -im) : (q==0? im : re);
    dst[(size_t)z*lsd + i] = f2bf(v);
}
__global__ void k_pack_rw(const float* __restrict__ src, u16* __restrict__ dst,
                          int Nn, int Ks, int KG, int lss, int lsd){
    int z = blockIdx.z;
    int tot = KG*Nn*8;
    int i = blockIdx.x*256+threadIdx.x; if(i >= tot) return;
    int e = i&7, n = (i>>3)%Nn, kg = i/(Nn*8);
    int k = kg*8+e;
    float v = (k < Ks) ? src[(size_t)z*lss + n*Ks + k] : 0.0f;
    dst[(size_t)z*lsd + i] = f2bf(v);
}

// ============ pointwise ============
__global__ void k_enc0(const float* __restrict__ x, const float* __restrict__ w,
                       const float* __restrict__ b, u16* __restrict__ out){
    int i = blockIdx.x*256+threadIdx.x;
    if(i >= NP*16) return;
    int p = i>>4, c8 = (i&15)*8;
    float x0 = x[p], x1 = x[NP+p];
    us8 o;
    #pragma unroll
    for(int j=0;j<8;j++){
        int e = c8+j;
        float v = w[e*2]*x0 + w[e*2+1]*x1 + b[e];
        o[j] = f2bf(gelu_f(v));
    }
    *(us8*)(out + (size_t)p*128 + c8) = o;
}
__global__ void k_xt2(const float* __restrict__ x, u16* __restrict__ dst){
    int p = blockIdx.x*256+threadIdx.x; if(p >= NP) return;
    us8 z = {0,0,0,0,0,0,0,0};
    z[0] = f2bf(x[p]); z[1] = f2bf(x[NP+p]);
    *(us8*)(dst + (size_t)p*32) = z;
    us8 z2 = {0,0,0,0,0,0,0,0};
    *(us8*)(dst + (size_t)p*32 + 8)  = z2;
    *(us8*)(dst + (size_t)p*32 + 16) = z2;
    *(us8*)(dst + (size_t)p*32 + 24) = z2;
}
__global__ void k_dec1(const u16* __restrict__ hid, const float* __restrict__ w,
                       float* __restrict__ out){
    int p = blockIdx.x*256+threadIdx.x; if(p >= NP) return;
    float a0=0.0f, a1=0.0f;
    #pragma unroll 4
    for(int k8=0;k8<16;k8++){
        us8 v = *(const us8*)(hid + (size_t)p*128 + k8*8);
        #pragma unroll
        for(int j=0;j<8;j++){
            float f = bf2f(v[j]);
            a0 = fmaf(w[k8*8+j], f, a0);
            a1 = fmaf(w[128+k8*8+j], f, a1);
        }
    }
    out[p] = a0; out[NP+p] = a1;
}

// ============ instance norm ============
__global__ __launch_bounds__(256) void k_istat(const u16* __restrict__ X, float* __restrict__ stat){
    int t = threadIdx.x;
    int c8 = (t&15)*8;
    float s[8], s2[8];
    #pragma unroll
    for(int j=0;j<8;j++){ s[j]=0.0f; s2[j]=0.0f; }
    for(int p = blockIdx.x*16 + (t>>4); p < NP; p += gridDim.x*16){
        us8 v = *(const us8*)(X + (size_t)p*128 + c8);
        #pragma unroll
        for(int j=0;j<8;j++){ float f = bf2f(v[j]); s[j]+=f; s2[j]=fmaf(f,f,s2[j]); }
    }
    __shared__ float L[256][8];
    #pragma unroll
    for(int j=0;j<8;j++) L[t][j]=s[j];
    __syncthreads();
    for(int st=128; st>=16; st>>=1){
        if(t<st){
            #pragma unroll
            for(int j=0;j<8;j++) L[t][j]+=L[t+st][j];
        }
        __syncthreads();
    }
    if(t<16){
        #pragma unroll
        for(int j=0;j<8;j++) atomicAdd(&stat[t*8+j], L[t][j]);
    }
    __syncthreads();
    #pragma unroll
    for(int j=0;j<8;j++) L[t][j]=s2[j];
    __syncthreads();
    for(int st=128; st>=16; st>>=1){
        if(t<st){
            #pragma unroll
            for(int j=0;j<8;j++) L[t][j]+=L[t+st][j];
        }
        __syncthreads();
    }
    if(t<16){
        #pragma unroll
        for(int j=0;j<8;j++) atomicAdd(&stat[128+t*8+j], L[t][j]);
    }
}
// apply norm -> XNP [pt][128]; also XNC[(c*192+h)*384 + w]
__global__ __launch_bounds__(256) void k_apply_t(
    const u16* __restrict__ X, u16* __restrict__ outp, u16* __restrict__ outc,
    const float* __restrict__ stat, const float* __restrict__ gw, const float* __restrict__ gb)
{
    __shared__ u16 T[128][72];
    __shared__ float SA_[128], SB_[128];
    int t = threadIdx.x;
    if(t < 128){
        float mu = stat[t]*(1.0f/(float)NP);
        float var = stat[128+t]*(1.0f/(float)NP) - mu*mu;
        var = fmaxf(var, 0.0f);
        float rstd = 1.0f/sqrtf(var + 1e-6f);
        float a = rstd*gw[t];
        SA_[t] = a; SB_[t] = gb[t] - mu*a;
    }
    __syncthreads();
    int p0 = blockIdx.x*64;
    int pl = t>>2, cc = (t&3)*32;
    int p = p0 + pl;
    if(p < NP){
        #pragma unroll
        for(int jj=0;jj<4;jj++){
            us8 v = *(const us8*)(X + (size_t)p*128 + cc + jj*8);
            us8 o;
            #pragma unroll
            for(int j=0;j<8;j++){
                int c = cc + jj*8 + j;
                o[j] = f2bf(fmaf(bf2f(v[j]), SA_[c], SB_[c]));
            }
            *(us8*)(outp + (size_t)p*128 + cc + jj*8) = o;
            #pragma unroll
            for(int j=0;j<8;j++) T[cc+jj*8+j][pl] = o[j];
        }
    }
    __syncthreads();
    int c = t>>1, half = t&1;
    int pbase = p0 + half*32;
    #pragma unroll
    for(int jj=0;jj<4;jj++){
        int pp = pbase + jj*8;
        if(pp + 8 <= NP){
            int hh = pp/360, ww = pp - hh*360;
            *(us8*)(outc + ((size_t)c*192 + hh)*384 + ww) = *(const us8*)(&T[c][half*32 + jj*8]);
        }
    }
}
__global__ __launch_bounds__(256) void k_apply(
    const u16* __restrict__ X, u16* __restrict__ outp,
    const float* __restrict__ stat, const float* __restrict__ gw, const float* __restrict__ gb)
{
    __shared__ float SA_[128], SB_[128];
    int t = threadIdx.x;
    if(t < 128){
        float mu = stat[t]*(1.0f/(float)NP);
        float var = stat[128+t]*(1.0f/(float)NP) - mu*mu;
        var = fmaxf(var, 0.0f);
        float rstd = 1.0f/sqrtf(var + 1e-6f);
        float a = rstd*gw[t];
        SA_[t] = a; SB_[t] = gb[t] - mu*a;
    }
    __syncthreads();
    int i = blockIdx.x*256 + t;
    if(i >= NP*16) return;
    int p = i>>4, c8 = (i&15)*8;
    us8 v = *(const us8*)(X + (size_t)p*128 + c8);
    us8 o;
    #pragma unroll
    for(int j=0;j<8;j++) o[j] = f2bf(fmaf(bf2f(v[j]), SA_[c8+j], SB_[c8+j]));
    *(us8*)(outp + (size_t)p*128 + c8) = o;
}
__global__ __launch_bounds__(256) void k_post(const float* __restrict__ src, u16* __restrict__ dst){
    __shared__ u16 T[128][72];
    int t = threadIdx.x;
    int p0 = blockIdx.x*64;
    int c = t>>1, half = t&1;
    int pbase = p0 + half*32;
    #pragma unroll
    for(int jj=0;jj<4;jj++){
        int pp = pbase + jj*8;
        us8 v = {0,0,0,0,0,0,0,0};
        if(pp + 8 <= NP){
            #pragma unroll
            for(int j=0;j<8;j++) v[j] = f2bf(src[(size_t)c*NP + pp + j]);
        }
        *(us8*)(&T[c][half*32 + jj*8]) = v;
    }
    __syncthreads();
    int pl = t>>2, cc = (t&3)*32;
    int p = p0 + pl;
    if(p < NP){
        #pragma unroll
        for(int jj=0;jj<4;jj++){
            us8 o;
            #pragma unroll
            for(int j=0;j<8;j++) o[j] = T[cc+jj*8+j][pl];
            *(us8*)(dst + (size_t)p*128 + cc + jj*8) = o;
        }
    }
}

// ============ fused spectral channel-MLP (S3+S4+S5) ============
__global__ __launch_bounds__(512) void k_smlp(
    const u16* __restrict__ A3, const u16* __restrict__ W0,
    const u16* __restrict__ W1, const u16* __restrict__ WO,
    u16* __restrict__ A4)
{
    __shared__ u16 Hs0[64*520];
    __shared__ u16 Hs1[64*520];
    int tid = threadIdx.x;
    int l = tid & 63, wn = tid >> 6;     // 8 col-groups
    int lm = l & 15, kg = l >> 4;
    int m0 = blockIdx.x * 64;

    f32x4 acc[4][4];
    #pragma unroll
    for(int f=0;f<4;f++)
        #pragma unroll
        for(int j2=0;j2<4;j2++) acc[f][j2] = (f32x4){0.f,0.f,0.f,0.f};
    {
        const u16* ap = A3 + (size_t)(m0 + lm)*256 + kg*8;
        #pragma unroll
        for(int k0=0;k0<256;k0+=32){
            bf16x8 af[4];
            #pragma unroll
            for(int f=0;f<4;f++) af[f] = *(const bf16x8*)(ap + f*16*256 + k0);
            const u16* Bb = W0 + (size_t)((k0>>3)+kg)*4096 + (wn*64+lm)*8;
            #pragma unroll
            for(int j2=0;j2<4;j2++){
                bf16x8 bf = *(const bf16x8*)(Bb + j2*128);
                #pragma unroll
                for(int f=0;f<4;f++)
                    acc[f][j2] = __builtin_amdgcn_mfma_f32_16x16x32_bf16(af[f], bf, acc[f][j2], 0,0,0);
            }
        }
    }
    #pragma unroll
    for(int f=0;f<4;f++)
        #pragma unroll
        for(int j2=0;j2<4;j2++)
            #pragma unroll
            for(int r=0;r<4;r++){
                int row = f*16 + kg*4 + r;
                int col = wn*64 + j2*16 + lm;
                float v = acc[f][j2][r];
                if(!(col&1)) v = fmaxf(v, 0.0f);
                Hs0[row*520 + col] = f2bf(v);
            }
    __syncthreads();
    #pragma unroll
    for(int f=0;f<4;f++)
        #pragma unroll
        for(int j2=0;j2<4;j2++) acc[f][j2] = (f32x4){0.f,0.f,0.f,0.f};
    #pragma unroll 2
    for(int k0=0;k0<512;k0+=32){
        bf16x8 af[4];
        #pragma unroll
        for(int f=0;f<4;f++) af[f] = *(const bf16x8*)(&Hs0[(f*16+lm)*520 + k0 + kg*8]);
        const u16* Bb = W1 + (size_t)((k0>>3)+kg)*4096 + (wn*64+lm)*8;
        #pragma unroll
        for(int j2=0;j2<4;j2++){
            bf16x8 bf = *(const bf16x8*)(Bb + j2*128);
            #pragma unroll
            for(int f=0;f<4;f++)
                acc[f][j2] = __builtin_amdgcn_mfma_f32_16x16x32_bf16(af[f], bf, acc[f][j2], 0,0,0);
        }
    }
    #pragma unroll
    for(int f=0;f<4;f++)
        #pragma unroll
        for(int j2=0;j2<4;j2++)
            #pragma unroll
            for(int r=0;r<4;r++){
                int row = f*16 + kg*4 + r;
                int col = wn*64 + j2*16 + lm;
                float v = acc[f][j2][r];
                if(!(col&1)) v = fmaxf(v, 0.0f);
                Hs1[row*520 + col] = f2bf(v);
            }
    __syncthreads();
    f32x4 acc3[4][2];
    #pragma unroll
    for(int f=0;f<4;f++)
        #pragma unroll
        for(int j2=0;j2<2;j2++) acc3[f][j2] = (f32x4){0.f,0.f,0.f,0.f};
    #pragma unroll 2
    for(int k0=0;k0<512;k0+=32){
        bf16x8 af[4];
        #pragma unroll
        for(int f=0;f<4;f++) af[f] = *(const bf16x8*)(&Hs1[(f*16+lm)*520 + k0 + kg*8]);
        const u16* Bb = WO + (size_t)((k0>>3)+kg)*2048 + (wn*32+lm)*8;
        #pragma unroll
        for(int j2=0;j2<2;j2++){
            bf16x8 bf = *(const bf16x8*)(Bb + j2*128);
            #pragma unroll
            for(int f=0;f<4;f++)
                acc3[f][j2] = __builtin_amdgcn_mfma_f32_16x16x32_bf16(af[f], bf, acc3[f][j2], 0,0,0);
        }
    }
    #pragma unroll
    for(int f=0;f<4;f++)
        #pragma unroll
        for(int j2=0;j2<2;j2++)
            #pragma unroll
            for(int r=0;r<4;r++){
                int row = f*16 + kg*4 + r;
                int col = wn*32 + j2*16 + lm;
                Hs0[row*258 + col] = f2bf(acc3[f][j2][r]);
            }
    __syncthreads();
    int kw = m0 / 192;
    int kh0 = m0 - kw*192;
    int c = tid >> 2, q = tid & 3;
    long base = ((long)(c*192 + kw))*384 + 2*(kh0 + q*16);
    #pragma unroll
    for(int jj=0;jj<4;jj++){
        us8 v;
        #pragma unroll
        for(int i=0;i<4;i++){
            v[2*i]   = Hs0[(q*16 + jj*4 + i)*258 + 2*c];
            v[2*i+1] = Hs0[(q*16 + jj*4 + i)*258 + 2*c+1];
        }
        *(us8*)(A4 + base + jj*8) = v;
    }
}

// ============ fused spatial MLP: fc1+gelu+fc2+outer-skip ============
__global__ __launch_bounds__(512) void k_pmlp(
    const u16* __restrict__ A, const u16* __restrict__ FC1, const u16* __restrict__ FC2,
    const float* __restrict__ b1, const float* __restrict__ b2,
    const u16* __restrict__ addb, u16* __restrict__ OUT)
{
    __shared__ u16 Hs[64][264];
    int tid = threadIdx.x;
    int l = tid & 63, wv = tid >> 6;
    int wm = wv >> 1, wn = wv & 1;
    int lm = l & 15, kg = l >> 4;
    int m0 = blockIdx.x * 64;

    f32x4 acc[8];
    #pragma unroll
    for(int j=0;j<8;j++) acc[j] = (f32x4){0.f,0.f,0.f,0.f};
    {
        const u16* ap = A + (size_t)(m0 + wm*16 + lm)*128 + kg*8;
        #pragma unroll
        for(int k0=0;k0<128;k0+=32){
            bf16x8 af = *(const bf16x8*)(ap + k0);
            const u16* Bb = FC1 + (size_t)((k0>>3)+kg)*2048 + (wn*128+lm)*8;
            #pragma unroll
            for(int j2=0;j2<8;j2++){
                bf16x8 bf = *(const bf16x8*)(Bb + j2*128);
                acc[j2] = __builtin_amdgcn_mfma_f32_16x16x32_bf16(af, bf, acc[j2], 0,0,0);
            }
        }
    }
    #pragma unroll
    for(int j2=0;j2<8;j2++)
        #pragma unroll
        for(int r=0;r<4;r++){
            int row = wm*16 + kg*4 + r;
            int col = wn*128 + j2*16 + lm;
            Hs[row][col] = f2bf(gelu_f(acc[j2][r] + b1[col]));
        }
    __syncthreads();
    f32x4 acc2[4];
    #pragma unroll
    for(int j=0;j<4;j++) acc2[j] = (f32x4){0.f,0.f,0.f,0.f};
    #pragma unroll
    for(int k0=0;k0<256;k0+=32){
        bf16x8 af = *(const bf16x8*)(&Hs[wm*16 + lm][k0 + kg*8]);
        const u16* Bb = FC2 + (size_t)((k0>>3)+kg)*1024 + (wn*64+lm)*8;
        #pragma unroll
        for(int j2=0;j2<4;j2++){
            bf16x8 bf = *(const bf16x8*)(Bb + j2*128);
            acc2[j2] = __builtin_amdgcn_mfma_f32_16x16x32_bf16(af, bf, acc2[j2], 0,0,0);
        }
    }
    #pragma unroll
    for(int j2=0;j2<4;j2++)
        #pragma unroll
        for(int r=0;r<4;r++){
            int row = wm*16 + kg*4 + r;
            long p = m0 + row;
            if(p < NP){
                int n = wn*64 + j2*16 + lm;
                float v = acc2[j2][r] + b2[n] + bf2f(addb[p*128 + n]);
                OUT[p*128 + n] = f2bf(v);
            }
        }
}

// ============ WIDE spectral GEMM: 64 rows/block, full N=384, A read once ====
// 512 thr = 8 waves, each wave 48 cols (3 j-tiles) x 64 rows (4 A-frags).
// TM=1: m=c*192+sub; base=((ng>>1)*128+c)*384 + 2*sub   (S1: sub=h; S6: sub=kw)
// TM=2: m=kw*128+c;  base=(kw*192+(ng>>1))*256 + 2*c    (S2)
// TM=5: m=h*128+c;   base=(h*360+ng)*128 + (m&127), ng<360 (S7)
template<int TMODE>
__global__ __launch_bounds__(512, 4) void k_gemmw(
    const u16* __restrict__ A, const u16* __restrict__ B, u16* __restrict__ C)
{
    __shared__ u16 Ts[64*392];
    int tid = threadIdx.x;
    int l = tid & 63, wv = tid >> 6;
    int lm = l & 15, kg = l >> 4;
    int m0 = blockIdx.x * 64;

    const u16* ap = A + (size_t)(m0 + lm)*384 + kg*8;
    int bn[3];
    #pragma unroll
    for(int j2=0;j2<3;j2++) bn[j2] = (wv*48 + j2*16 + lm)*8 + kg*3072;

    f32x4 acc[4][3];
    #pragma unroll
    for(int f=0;f<4;f++)
        #pragma unroll
        for(int j2=0;j2<3;j2++) acc[f][j2] = (f32x4){0.f,0.f,0.f,0.f};

    #pragma unroll
    for(int ks=0; ks<12; ks++){
        const int k0 = ks*32;
        bf16x8 af[4];
        #pragma unroll
        for(int f=0;f<4;f++) af[f] = *(const bf16x8*)(ap + f*16*384 + k0);
        const u16* Bb = B + (size_t)(ks*4)*3072;
        bf16x8 bf[3];
        #pragma unroll
        for(int j2=0;j2<3;j2++) bf[j2] = *(const bf16x8*)(Bb + bn[j2]);
        #pragma unroll
        for(int f=0;f<4;f++)
            #pragma unroll
            for(int j2=0;j2<3;j2++)
                acc[f][j2] = __builtin_amdgcn_mfma_f32_16x16x32_bf16(af[f], bf[j2], acc[f][j2], 0,0,0);
    }

    // stage to LDS
    #pragma unroll
    for(int f=0;f<4;f++)
        #pragma unroll
        for(int j2=0;j2<3;j2++)
            #pragma unroll
            for(int r=0;r<4;r++)
                Ts[(f*16 + kg*4 + r)*392 + wv*48 + j2*16 + lm] = f2bf(acc[f][j2][r]);
    __syncthreads();

    if constexpr (TMODE != 5){
        #pragma unroll
        for(int it=0; it<6; it++){
            int g = tid + it*512;
            int gn = g % 192, gm = g / 192;
            int ml = gm*4, nl = gn*2;
            int mg = m0 + ml, ng = nl;
            long base;
            if constexpr (TMODE == 1){
                int c = (int)(((unsigned)mg*43691u)>>23);
                int sub = mg - c*192;
                base = ((long)((ng>>1)*128 + c))*384 + 2*sub;
            } else {
                int kw = mg>>7, c = mg&127;
                base = ((long)(kw*192 + (ng>>1)))*256 + 2*c;
            }
            us8 v;
            #pragma unroll
            for(int i=0;i<4;i++){
                v[2*i]   = Ts[(ml+i)*392 + nl];
                v[2*i+1] = Ts[(ml+i)*392 + nl+1];
            }
            *(us8*)(C + base) = v;
        }
    } else {
        #pragma unroll
        for(int it=0; it<6; it++){
            int g = tid + it*512;
            int nl = g % 384, gm = g / 384;
            int ml = gm*8;
            int mg = m0 + ml;
            if(nl < 360){
                int h = mg >> 7;
                long base = ((long)(h*360 + nl))*128 + (mg & 127);
                us8 v;
                #pragma unroll
                for(int j=0;j<8;j++) v[j] = Ts[(ml+j)*392 + nl];
                *(us8*)(C + base) = v;
            }
        }
    }
}

// ============ row-major MFMA GEMM (encoder/skip/decoder) ============
template<int KSTEPS, bool SPLIT>
__global__ __launch_bounds__(256, 2) void k_gemm(
    const u16* __restrict__ A1, const u16* __restrict__ A2, int aksplit, int astr, int a2str,
    const u16* __restrict__ B, int bkstr,
    u16* __restrict__ C, int cstr,
    const float* __restrict__ bias, const u16* __restrict__ addb,
    int Mvalid, int N, int flags)
{
    int tid = threadIdx.x;
    int l = tid & 63, wv = tid >> 6;
    int wm = wv >> 1, wn = wv & 1;
    int lm = l & 15, kgl = l >> 4;
    int m0 = blockIdx.y*128 + wm*64;
    int n0 = blockIdx.x*128 + wn*64;

    int ab1[4], ab2[4];
    #pragma unroll
    for(int i2=0;i2<4;i2++){
        int mi = m0 + i2*16 + lm;
        ab1[i2] = mi*astr + kgl*8;
        ab2[i2] = mi*a2str + kgl*8;
    }
    int bn[4];
    #pragma unroll
    for(int j2=0;j2<4;j2++) bn[j2] = (n0 + j2*16 + lm)*8 + kgl*bkstr;

    f32x4 acc[4][4];
    #pragma unroll
    for(int i2=0;i2<4;i2++)
        #pragma unroll
        for(int j2=0;j2<4;j2++)
            acc[i2][j2] = (f32x4){0.0f,0.0f,0.0f,0.0f};

    #pragma unroll
    for(int ks=0; ks<KSTEPS; ks++){
        const int k0 = ks*32;
        bf16x8 af[4];
        if constexpr (SPLIT){
            int kk = k0 + kgl*8;
            bool s1v = kk < aksplit;
            #pragma unroll
            for(int i2=0;i2<4;i2++)
                af[i2] = s1v ? *(const bf16x8*)(A1 + ab1[i2] + k0)
                             : *(const bf16x8*)(A2 + ab2[i2] + k0 - aksplit);
        } else {
            #pragma unroll
            for(int i2=0;i2<4;i2++)
                af[i2] = *(const bf16x8*)(A1 + ab1[i2] + k0);
        }
        const u16* Bb = B + (size_t)(ks*4)*bkstr;
        bf16x8 bf[4];
        #pragma unroll
        for(int j2=0;j2<4;j2++)
            bf[j2] = *(const bf16x8*)(Bb + bn[j2]);
        #pragma unroll
        for(int i2=0;i2<4;i2++)
            #pragma unroll
            for(int j2=0;j2<4;j2++)
                acc[i2][j2] = __builtin_amdgcn_mfma_f32_16x16x32_bf16(af[i2], bf[j2], acc[i2][j2], 0,0,0);
    }

    #pragma unroll
    for(int i2=0;i2<4;i2++){
        #pragma unroll
        for(int r=0;r<4;r++){
            int m = m0 + i2*16 + kgl*4 + r;
            if(m >= Mvalid) continue;
            long mb = (long)m*cstr;
            #pragma unroll
            for(int j2=0;j2<4;j2++){
                int n = n0 + j2*16 + lm;
                if(n >= N) continue;
                float v = acc[i2][j2][r];
                if(bias) v += bias[n];
                if(flags & 1) v = gelu_f(v);
                long ca = mb + n;
                if(addb) v += bf2f(addb[ca]);
                C[ca] = f2bf(v);
            }
        }
    }
}

// ============ launch ============
extern "C" void kernel_launch(void* const* d_in, const int* in_sizes, int n_in,
                              void* d_out, int out_size, void* d_ws, size_t ws_size,
                              hipStream_t stream) {
    const float* x       = (const float*)d_in[0];
    const float* enc_w0  = (const float*)d_in[1];
    const float* enc_b0  = (const float*)d_in[2];
    const float* enc_w1  = (const float*)d_in[3];
    const float* pos     = (const float*)d_in[4];
    const float* n0w     = (const float*)d_in[5];
    const float* n0b     = (const float*)d_in[6];
    const float* w0      = (const float*)d_in[7];
    const float* w1      = (const float*)d_in[8];
    const float* wout    = (const float*)d_in[9];
    const float* isw     = (const float*)d_in[10];
    const float* isb     = (const float*)d_in[11];
    const float* n1w     = (const float*)d_in[12];
    const float* n1b     = (const float*)d_in[13];
    const float* fc1w    = (const float*)d_in[14];
    const float* fc1b    = (const float*)d_in[15];
    const float* fc2w    = (const float*)d_in[16];
    const float* fc2b    = (const float*)d_in[17];
    const float* dec_w0  = (const float*)d_in[18];
    const float* dec_b0  = (const float*)d_in[19];
    const float* dec_w1  = (const float*)d_in[20];
    float* out = (float*)d_out;

    u16* ws = (u16*)d_ws;
    size_t off = 0;
    auto al = [&](size_t n){ u16* p = ws + off; off += (n + 63) & ~(size_t)63; return p; };
    u16* TWF  = al(147456);
    u16* THF  = al(196608);
    u16* THI  = al(147456);               // [48][384][8]
    u16* TWI  = al(147456);
    u16* W0P  = al(524288);
    u16* W1P  = al(1048576);
    u16* WOP  = al(524288);
    u16* ISWP = al(65536);
    u16* FC1P = al(131072);
    u16* FC2P = al(131072);
    u16* EW1P = al(16384);
    u16* DW0P = al(20480);
    u16* POSP = al((size_t)NPAD*128);
    u16* XT2  = al((size_t)NPAD*32);
    u16* CURP = al((size_t)NPAD*128);
    u16* XNP  = al((size_t)NPAD*128);
    u16* YP   = al((size_t)NPAD*128);
    u16* XNC  = al((size_t)24576*384);   // [c*192+h][384]
    u16* A2b  = al((size_t)24576*384);   // [kw*128+c][2h+q]  (also A5: [h*128+c][2kw+q])
    u16* A3b  = al((size_t)36864*256);   // [kw*192+kh][2c+p]
    u16* A4b  = al((size_t)24576*384);   // [c*192+kw][2kh+p]
    u16* BIG  = al((size_t)NPAD*128);    // ENC [pt][128]
    u16* IST  = al(4096);
    float* ISTAT = (float*)IST;
    u16* A5b = A2b;
    u16* ENC = BIG;

    dim3 blk(256);
    k_zero<<<dim3(4608), blk, 0, stream>>>(XNC, (long)24576*384);
    k_zero<<<dim3(2),    blk, 0, stream>>>(IST, 4096);

    // packs
    k_pack_twf<<<dim3((147456+255)/256), blk, 0, stream>>>(TWF);
    k_pack_thf<<<dim3((196608+255)/256), blk, 0, stream>>>(THF);
    k_pack_thi<<<dim3((147456+255)/256), blk, 0, stream>>>(THI);
    k_pack_twi<<<dim3((147456+255)/256), blk, 0, stream>>>(TWI);
    k_pack_cw<<<dim3((131072+255)/256,1,4), blk, 0, stream>>>(w0,   W0P, 128, 256, 2*128*256, 131072);
    k_pack_cw<<<dim3((262144+255)/256,1,4), blk, 0, stream>>>(w1,   W1P, 256, 256, 2*256*256, 262144);
    k_pack_cw<<<dim3((131072+255)/256,1,4), blk, 0, stream>>>(wout, WOP, 256, 128, 2*256*128, 131072);
    k_pack_rw<<<dim3((16384+255)/256,1,4),  blk, 0, stream>>>(isw,  ISWP, 128, 128, 16, 128*128, 16384);
    k_pack_rw<<<dim3((32768+255)/256,1,4),  blk, 0, stream>>>(fc1w, FC1P, 256, 128, 16, 256*128, 32768);
    k_pack_rw<<<dim3((32768+255)/256,1,4),  blk, 0, stream>>>(fc2w, FC2P, 128, 256, 32, 128*256, 32768);
    k_pack_rw<<<dim3((16384+255)/256,1,1),  blk, 0, stream>>>(enc_w1, EW1P, 128, 128, 16, 0, 0);
    k_pack_rw<<<dim3((20480+255)/256,1,1),  blk, 0, stream>>>(dec_w0, DW0P, 128, 130, 20, 0, 0);
    k_post<<<dim3(1019), blk, 0, stream>>>(pos, POSP);
    k_xt2 <<<dim3((NP+255)/256), blk, 0, stream>>>(x, XT2);

    const u16* nu = nullptr;
    const float* nf = nullptr;
    const int BIGV = 1<<28;

    // encoder
    k_enc0<<<dim3((NP*16+255)/256), blk, 0, stream>>>(x, enc_w0, enc_b0, ENC);
    k_gemm<4,false><<<dim3(1,510), blk, 0, stream>>>(
        ENC, ENC, BIGV, 128, 128, EW1P, 1024, CURP, 128, nf, POSP, NP, 128, 0);

    for(int l=0; l<4; l++){
        float* st0 = ISTAT + (2*l)*256;
        float* st1 = ISTAT + (2*l+1)*256;
        k_istat<<<dim3(128), blk, 0, stream>>>(CURP, st0);
        k_apply_t<<<dim3(1019), blk, 0, stream>>>(CURP, XNP, XNC, st0, n0w+l*128, n0b+l*128);
        // S1 rdft: XNC x TWF -> A2 [kw*128+c][2h+q], stride 384
        k_gemmw<1><<<dim3(384), dim3(512), 0, stream>>>(XNC, TWF, A2b);
        // S2 H-DFT fwd: A2 x THF -> A3 [kw*192+kh][2c+p]
        k_gemmw<2><<<dim3(384), dim3(512), 0, stream>>>(A2b, THF, A3b);
        // fused spectral channel-MLP: A3 -> A4 [c*192+kw][2kh+p]
        k_smlp<<<dim3(576), dim3(512), 0, stream>>>(A3b,
            W0P + (size_t)l*131072, W1P + (size_t)l*262144, WOP + (size_t)l*131072, A4b);
        // S6 H-DFT inv: A4 x THI -> A5 [h*128+c][2kw+q], stride 384
        k_gemmw<1><<<dim3(384), dim3(512), 0, stream>>>(A4b, THI, A5b);
        // S7 irdft: A5 x TWI -> YP [pt][128]
        k_gemmw<5><<<dim3(362), dim3(512), 0, stream>>>(A5b, TWI, YP);
        // inner skip: CUR = isw*XN + isb + Y
        k_gemm<4,false><<<dim3(1,510), blk, 0, stream>>>(
            XNP, XNP, BIGV, 128, 128, ISWP + (size_t)l*16384, 1024, CURP, 128,
            isb+l*128, YP, NP, 128, 0);
        // norm1
        k_istat<<<dim3(128), blk, 0, stream>>>(CURP, st1);
        k_apply<<<dim3((NP*16+255)/256), blk, 0, stream>>>(CURP, YP, st1, n1w+l*128, n1b+l*128);
        // fused spatial MLP: fc1+gelu+fc2+outer-skip(XNP) -> CURP
        k_pmlp<<<dim3(1019), dim3(512), 0, stream>>>(YP,
            FC1P + (size_t)l*32768, FC2P + (size_t)l*32768,
            fc1b + l*256, fc2b + l*128, XNP, CURP);
    }
    // decoder conv0 (concat CUR, x) + gelu -> XNP
    k_gemm<5,true><<<dim3(1,510), blk, 0, stream>>>(
        CURP, XT2, 128, 128, 32, DW0P, 1024, XNP, 128, dec_b0, nu, NP, 128, 1);
    k_dec1<<<dim3((NP+255)/256), blk, 0, stream>>>(XNP, dec_w1, out);
}

// Round 12
// 1555.708 us; speedup vs baseline: 1.0632x; 1.0632x over previous
//
#include <hip/hip_runtime.h>
#include <math.h>

#define NP 65160        // 181*360
#define NPAD 65280

typedef unsigned short u16;
typedef __attribute__((ext_vector_type(8))) short bf16x8;
typedef __attribute__((ext_vector_type(8))) unsigned short us8;
typedef __attribute__((ext_vector_type(4))) float f32x4;

__device__ __forceinline__ u16 f2bf(float f){
    unsigned u = __builtin_bit_cast(unsigned, f);
    return (u16)((u + 0x7FFFu + ((u>>16)&1u)) >> 16);
}
__device__ __forceinline__ float bf2f(u16 h){
    unsigned u = ((unsigned)h)<<16;
    return __builtin_bit_cast(float, u);
}
__device__ __forceinline__ float gelu_f(float x){
    return 0.5f*x*(1.0f+erff(x*0.70710678118654752f));
}

__global__ void k_zero(u16* __restrict__ p, long n){
    long i = ((long)blockIdx.x*256 + threadIdx.x)*8;
    if(i+8 <= n){ us8 z = {0,0,0,0,0,0,0,0}; *(us8*)(p+i) = z; }
}

// ============ B packs: dst[kg][n][8], k = kg*8+e, zero padded ============
__global__ void k_pack_twf(u16* __restrict__ dst){   // [48][384][8]: k=w, n=2kw+q
    int i = blockIdx.x*256+threadIdx.x; if(i >= 48*384*8) return;
    int e = i&7, n = (i>>3)%384, kg = i/(384*8);
    int k = kg*8+e, kw = n>>1, q = n&1;
    float v = 0.0f;
    if(k < 360 && kw < 181){
        float inv = 1.0f/sqrtf(65160.0f);
        float th = 6.28318530717958647692f*(float)((k*kw)%360)/360.0f;
        v = q ? -sinf(th)*inv : cosf(th)*inv;
    }
    dst[i] = f2bf(v);
}
__global__ void k_pack_thf(u16* __restrict__ dst){   // [64][384][8]: k=2h+q, n=2kh+p
    int i = blockIdx.x*256+threadIdx.x; if(i >= 64*384*8) return;
    int e = i&7, n = (i>>3)%384, kg = i/(384*8);
    int k = kg*8+e;
    float v = 0.0f;
    if(k < 362 && n < 362){
        int h = k>>1, q = k&1, kh = n>>1, p = n&1;
        float th = 6.28318530717958647692f*(float)((h*kh)%181)/181.0f;
        float c = cosf(th), s = sinf(th);
        v = (q==0) ? (p==0? c : -s) : (p==0? s : c);
    }
    dst[i] = f2bf(v);
}
__global__ void k_pack_thi(u16* __restrict__ dst){   // [48][384][8]: k=2kh+p, n=2h+q
    int i = blockIdx.x*256+threadIdx.x; if(i >= 48*384*8) return;
    int e = i&7, n = (i>>3)%384, kg = i/(384*8);
    int k = kg*8+e;
    float v = 0.0f;
    if(k < 362 && n < 362){
        int kh = k>>1, p = k&1, h = n>>1, q = n&1;
        float th = 6.28318530717958647692f*(float)((kh*h)%181)/181.0f;
        float c = cosf(th), s = sinf(th);
        v = (q==0) ? (p==0? c : -s) : (p==0? s : c);
    }
    dst[i] = f2bf(v);
}
__global__ void k_pack_twi(u16* __restrict__ dst){   // [48][384][8]: k=2kw+q, n=w
    int i = blockIdx.x*256+threadIdx.x; if(i >= 48*384*8) return;
    int e = i&7, n = (i>>3)%384, kg = i/(384*8);
    int k = kg*8+e, kw = k>>1, q = k&1;
    float v = 0.0f;
    if(k < 362 && n < 360){
        float inv = 1.0f/sqrtf(65160.0f);
        float eps = (kw==0 || kw==180) ? 1.0f : 2.0f;
        float th = 6.28318530717958647692f*(float)((n*kw)%360)/360.0f;
        v = q ? -eps*sinf(th)*inv : eps*cosf(th)*inv;
    }
    dst[i] = f2bf(v);
}
__global__ void k_pack_cw(const float* __restrict__ src, u16* __restrict__ dst,
                          int CIN, int COUT, int lss, int lsd){
    int z = blockIdx.z;
    int Npad = 2*COUT, KG = (2*CIN)/8;
    int tot = KG*Npad*8;
    int i = blockIdx.x*256+threadIdx.x; if(i >= tot) return;
    int e = i&7, n = (i>>3)%Npad, kg = i/(Npad*8);
    int k = kg*8+e, ci = k>>1, q = k&1, co = n>>1, p = n&1;
    float re = src[(size_t)z*lss + ci*COUT + co];
    float im = src[(size_t)z*lss + CIN*COUT + ci*COUT + co];
    float v = (p==0) ? (q==0? re : -im) : (q==0? im : re);
    dst[(size_t)z*lsd + i] = f2bf(v);
}
__global__ void k_pack_rw(const float* __restrict__ src, u16* __restrict__ dst,
                          int Nn, int Ks, int KG, int lss, int lsd){
    int z = blockIdx.z;
    int tot = KG*Nn*8;
    int i = blockIdx.x*256+threadIdx.x; if(i >= tot) return;
    int e = i&7, n = (i>>3)%Nn, kg = i/(Nn*8);
    int k = kg*8+e;
    float v = (k < Ks) ? src[(size_t)z*lss + n*Ks + k] : 0.0f;
    dst[(size_t)z*lsd + i] = f2bf(v);
}

// ============ pointwise ============
__global__ void k_enc0(const float* __restrict__ x, const float* __restrict__ w,
                       const float* __restrict__ b, u16* __restrict__ out){
    int i = blockIdx.x*256+threadIdx.x;
    if(i >= NP*16) return;
    int p = i>>4, c8 = (i&15)*8;
    float x0 = x[p], x1 = x[NP+p];
    us8 o;
    #pragma unroll
    for(int j=0;j<8;j++){
        int e = c8+j;
        float v = w[e*2]*x0 + w[e*2+1]*x1 + b[e];
        o[j] = f2bf(gelu_f(v));
    }
    *(us8*)(out + (size_t)p*128 + c8) = o;
}
__global__ void k_xt2(const float* __restrict__ x, u16* __restrict__ dst){
    int p = blockIdx.x*256+threadIdx.x; if(p >= NP) return;
    us8 z = {0,0,0,0,0,0,0,0};
    z[0] = f2bf(x[p]); z[1] = f2bf(x[NP+p]);
    *(us8*)(dst + (size_t)p*32) = z;
    us8 z2 = {0,0,0,0,0,0,0,0};
    *(us8*)(dst + (size_t)p*32 + 8)  = z2;
    *(us8*)(dst + (size_t)p*32 + 16) = z2;
    *(us8*)(dst + (size_t)p*32 + 24) = z2;
}
__global__ void k_dec1(const u16* __restrict__ hid, const float* __restrict__ w,
                       float* __restrict__ out){
    int p = blockIdx.x*256+threadIdx.x; if(p >= NP) return;
    float a0=0.0f, a1=0.0f;
    #pragma unroll 4
    for(int k8=0;k8<16;k8++){
        us8 v = *(const us8*)(hid + (size_t)p*128 + k8*8);
        #pragma unroll
        for(int j=0;j<8;j++){
            float f = bf2f(v[j]);
            a0 = fmaf(w[k8*8+j], f, a0);
            a1 = fmaf(w[128+k8*8+j], f, a1);
        }
    }
    out[p] = a0; out[NP+p] = a1;
}

// ============ instance norm ============
__global__ __launch_bounds__(256) void k_istat(const u16* __restrict__ X, float* __restrict__ stat){
    int t = threadIdx.x;
    int c8 = (t&15)*8;
    float s[8], s2[8];
    #pragma unroll
    for(int j=0;j<8;j++){ s[j]=0.0f; s2[j]=0.0f; }
    for(int p = blockIdx.x*16 + (t>>4); p < NP; p += gridDim.x*16){
        us8 v = *(const us8*)(X + (size_t)p*128 + c8);
        #pragma unroll
        for(int j=0;j<8;j++){ float f = bf2f(v[j]); s[j]+=f; s2[j]=fmaf(f,f,s2[j]); }
    }
    __shared__ float L[256][8];
    #pragma unroll
    for(int j=0;j<8;j++) L[t][j]=s[j];
    __syncthreads();
    for(int st=128; st>=16; st>>=1){
        if(t<st){
            #pragma unroll
            for(int j=0;j<8;j++) L[t][j]+=L[t+st][j];
        }
        __syncthreads();
    }
    if(t<16){
        #pragma unroll
        for(int j=0;j<8;j++) atomicAdd(&stat[t*8+j], L[t][j]);
    }
    __syncthreads();
    #pragma unroll
    for(int j=0;j<8;j++) L[t][j]=s2[j];
    __syncthreads();
    for(int st=128; st>=16; st>>=1){
        if(t<st){
            #pragma unroll
            for(int j=0;j<8;j++) L[t][j]+=L[t+st][j];
        }
        __syncthreads();
    }
    if(t<16){
        #pragma unroll
        for(int j=0;j<8;j++) atomicAdd(&stat[128+t*8+j], L[t][j]);
    }
}
// apply norm -> XNP [pt][128]; also XNC[(c*192+h)*384 + w]
__global__ __launch_bounds__(256) void k_apply_t(
    const u16* __restrict__ X, u16* __restrict__ outp, u16* __restrict__ outc,
    const float* __restrict__ stat, const float* __restrict__ gw, const float* __restrict__ gb)
{
    __shared__ u16 T[128][72];
    __shared__ float SA_[128], SB_[128];
    int t = threadIdx.x;
    if(t < 128){
        float mu = stat[t]*(1.0f/(float)NP);
        float var = stat[128+t]*(1.0f/(float)NP) - mu*mu;
        var = fmaxf(var, 0.0f);
        float rstd = 1.0f/sqrtf(var + 1e-6f);
        float a = rstd*gw[t];
        SA_[t] = a; SB_[t] = gb[t] - mu*a;
    }
    __syncthreads();
    int p0 = blockIdx.x*64;
    int pl = t>>2, cc = (t&3)*32;
    int p = p0 + pl;
    if(p < NP){
        #pragma unroll
        for(int jj=0;jj<4;jj++){
            us8 v = *(const us8*)(X + (size_t)p*128 + cc + jj*8);
            us8 o;
            #pragma unroll
            for(int j=0;j<8;j++){
                int c = cc + jj*8 + j;
                o[j] = f2bf(fmaf(bf2f(v[j]), SA_[c], SB_[c]));
            }
            *(us8*)(outp + (size_t)p*128 + cc + jj*8) = o;
            #pragma unroll
            for(int j=0;j<8;j++) T[cc+jj*8+j][pl] = o[j];
        }
    }
    __syncthreads();
    int c = t>>1, half = t&1;
    int pbase = p0 + half*32;
    #pragma unroll
    for(int jj=0;jj<4;jj++){
        int pp = pbase + jj*8;
        if(pp + 8 <= NP){
            int hh = pp/360, ww = pp - hh*360;
            *(us8*)(outc + ((size_t)c*192 + hh)*384 + ww) = *(const us8*)(&T[c][half*32 + jj*8]);
        }
    }
}
__global__ __launch_bounds__(256) void k_post(const float* __restrict__ src, u16* __restrict__ dst){
    __shared__ u16 T[128][72];
    int t = threadIdx.x;
    int p0 = blockIdx.x*64;
    int c = t>>1, half = t&1;
    int pbase = p0 + half*32;
    #pragma unroll
    for(int jj=0;jj<4;jj++){
        int pp = pbase + jj*8;
        us8 v = {0,0,0,0,0,0,0,0};
        if(pp + 8 <= NP){
            #pragma unroll
            for(int j=0;j<8;j++) v[j] = f2bf(src[(size_t)c*NP + pp + j]);
        }
        *(us8*)(&T[c][half*32 + jj*8]) = v;
    }
    __syncthreads();
    int pl = t>>2, cc = (t&3)*32;
    int p = p0 + pl;
    if(p < NP){
        #pragma unroll
        for(int jj=0;jj<4;jj++){
            us8 o;
            #pragma unroll
            for(int j=0;j<8;j++) o[j] = T[cc+jj*8+j][pl];
            *(us8*)(dst + (size_t)p*128 + cc + jj*8) = o;
        }
    }
}

// ============ fused spectral channel-MLP (S3+S4+S5), 48 rows/block ============
// grid = 36864/48 = 768 = exactly 3 rounds of 256 CUs (no tail).
// 512 thr = 8 col-group waves; each wave covers all 48 rows (3 A-frags).
__global__ __launch_bounds__(512) void k_smlp(
    const u16* __restrict__ A3, const u16* __restrict__ W0,
    const u16* __restrict__ W1, const u16* __restrict__ WO,
    u16* __restrict__ A4)
{
    __shared__ u16 Hs0[48*520];
    __shared__ u16 Hs1[48*520];
    int tid = threadIdx.x;
    int l = tid & 63, wn = tid >> 6;     // 8 col-groups
    int lm = l & 15, kg = l >> 4;
    int m0 = blockIdx.x * 48;

    f32x4 acc[3][4];
    // ---- stage 1: Hs0[48][512] = A3 x W0 (K=256), CReLU even col ----
    #pragma unroll
    for(int f=0;f<3;f++)
        #pragma unroll
        for(int j2=0;j2<4;j2++) acc[f][j2] = (f32x4){0.f,0.f,0.f,0.f};
    {
        const u16* ap = A3 + (size_t)(m0 + lm)*256 + kg*8;
        #pragma unroll
        for(int k0=0;k0<256;k0+=32){
            bf16x8 af[3];
            #pragma unroll
            for(int f=0;f<3;f++) af[f] = *(const bf16x8*)(ap + f*16*256 + k0);
            const u16* Bb = W0 + (size_t)((k0>>3)+kg)*4096 + (wn*64+lm)*8;
            #pragma unroll
            for(int j2=0;j2<4;j2++){
                bf16x8 bf = *(const bf16x8*)(Bb + j2*128);
                #pragma unroll
                for(int f=0;f<3;f++)
                    acc[f][j2] = __builtin_amdgcn_mfma_f32_16x16x32_bf16(af[f], bf, acc[f][j2], 0,0,0);
            }
        }
    }
    #pragma unroll
    for(int f=0;f<3;f++)
        #pragma unroll
        for(int j2=0;j2<4;j2++)
            #pragma unroll
            for(int r=0;r<4;r++){
                int row = f*16 + kg*4 + r;
                int col = wn*64 + j2*16 + lm;
                float v = acc[f][j2][r];
                if(!(col&1)) v = fmaxf(v, 0.0f);
                Hs0[row*520 + col] = f2bf(v);
            }
    __syncthreads();
    // ---- stage 2: Hs1 = Hs0 x W1 (K=512), CReLU even col ----
    #pragma unroll
    for(int f=0;f<3;f++)
        #pragma unroll
        for(int j2=0;j2<4;j2++) acc[f][j2] = (f32x4){0.f,0.f,0.f,0.f};
    #pragma unroll 2
    for(int k0=0;k0<512;k0+=32){
        bf16x8 af[3];
        #pragma unroll
        for(int f=0;f<3;f++) af[f] = *(const bf16x8*)(&Hs0[(f*16+lm)*520 + k0 + kg*8]);
        const u16* Bb = W1 + (size_t)((k0>>3)+kg)*4096 + (wn*64+lm)*8;
        #pragma unroll
        for(int j2=0;j2<4;j2++){
            bf16x8 bf = *(const bf16x8*)(Bb + j2*128);
            #pragma unroll
            for(int f=0;f<3;f++)
                acc[f][j2] = __builtin_amdgcn_mfma_f32_16x16x32_bf16(af[f], bf, acc[f][j2], 0,0,0);
        }
    }
    #pragma unroll
    for(int f=0;f<3;f++)
        #pragma unroll
        for(int j2=0;j2<4;j2++)
            #pragma unroll
            for(int r=0;r<4;r++){
                int row = f*16 + kg*4 + r;
                int col = wn*64 + j2*16 + lm;
                float v = acc[f][j2][r];
                if(!(col&1)) v = fmaxf(v, 0.0f);
                Hs1[row*520 + col] = f2bf(v);
            }
    __syncthreads();
    // ---- stage 3: O[48][256] = Hs1 x WO (K=512) ----
    f32x4 acc3[3][2];
    #pragma unroll
    for(int f=0;f<3;f++)
        #pragma unroll
        for(int j2=0;j2<2;j2++) acc3[f][j2] = (f32x4){0.f,0.f,0.f,0.f};
    #pragma unroll 2
    for(int k0=0;k0<512;k0+=32){
        bf16x8 af[3];
        #pragma unroll
        for(int f=0;f<3;f++) af[f] = *(const bf16x8*)(&Hs1[(f*16+lm)*520 + k0 + kg*8]);
        const u16* Bb = WO + (size_t)((k0>>3)+kg)*2048 + (wn*32+lm)*8;
        #pragma unroll
        for(int j2=0;j2<2;j2++){
            bf16x8 bf = *(const bf16x8*)(Bb + j2*128);
            #pragma unroll
            for(int f=0;f<3;f++)
                acc3[f][j2] = __builtin_amdgcn_mfma_f32_16x16x32_bf16(af[f], bf, acc3[f][j2], 0,0,0);
        }
    }
    // O staged into Hs0 at stride 258 (all Hs0 reads done before prior barrier)
    #pragma unroll
    for(int f=0;f<3;f++)
        #pragma unroll
        for(int j2=0;j2<2;j2++)
            #pragma unroll
            for(int r=0;r<4;r++){
                int row = f*16 + kg*4 + r;
                int col = wn*32 + j2*16 + lm;
                Hs0[row*258 + col] = f2bf(acc3[f][j2][r]);
            }
    __syncthreads();
    // ---- coalesced store: A4[(c*192+kw)*384 + 2kh+p] ----
    int kw = m0 / 192;                 // 192/48==4 -> blocks never straddle kw
    int kh0 = m0 - kw*192;
    int c = tid >> 2, q = tid & 3;     // c<128, q covers 12 rows each
    long base = ((long)(c*192 + kw))*384 + 2*(kh0 + q*12);
    #pragma unroll
    for(int jj=0;jj<3;jj++){
        us8 v;
        #pragma unroll
        for(int i=0;i<4;i++){
            v[2*i]   = Hs0[(q*12 + jj*4 + i)*258 + 2*c];
            v[2*i+1] = Hs0[(q*12 + jj*4 + i)*258 + 2*c+1];
        }
        *(us8*)(A4 + base + jj*8) = v;
    }
}

// ============ fused spatial MLP: norm1+fc1+gelu+fc2+outer-skip, in-place ====
__global__ __launch_bounds__(512) void k_pmlp(
    const u16* __restrict__ A, const u16* __restrict__ FC1, const u16* __restrict__ FC2,
    const float* __restrict__ b1, const float* __restrict__ b2,
    const float* __restrict__ stat, const float* __restrict__ gw, const float* __restrict__ gb,
    const u16* __restrict__ addb, u16* __restrict__ OUT)
{
    __shared__ u16 Hs[64][264];
    __shared__ float SA_[128], SB_[128];
    int tid = threadIdx.x;
    int l = tid & 63, wv = tid >> 6;
    int wm = wv >> 1, wn = wv & 1;
    int lm = l & 15, kg = l >> 4;
    int m0 = blockIdx.x * 64;
    if(tid < 128){
        float mu = stat[tid]*(1.0f/(float)NP);
        float var = stat[128+tid]*(1.0f/(float)NP) - mu*mu;
        var = fmaxf(var, 0.0f);
        float rstd = 1.0f/sqrtf(var + 1e-6f);
        float a = rstd*gw[tid];
        SA_[tid] = a; SB_[tid] = gb[tid] - mu*a;
    }
    __syncthreads();

    f32x4 acc[8];
    #pragma unroll
    for(int j=0;j<8;j++) acc[j] = (f32x4){0.f,0.f,0.f,0.f};
    {
        const u16* ap = A + (size_t)(m0 + wm*16 + lm)*128 + kg*8;
        #pragma unroll
        for(int k0=0;k0<128;k0+=32){
            us8 raw = *(const us8*)(ap + k0);
            bf16x8 af;
            #pragma unroll
            for(int j=0;j<8;j++){
                int ch = kg*8 + k0 + j;
                af[j] = (short)f2bf(fmaf(bf2f(raw[j]), SA_[ch], SB_[ch]));
            }
            const u16* Bb = FC1 + (size_t)((k0>>3)+kg)*2048 + (wn*128+lm)*8;
            #pragma unroll
            for(int j2=0;j2<8;j2++){
                bf16x8 bf = *(const bf16x8*)(Bb + j2*128);
                acc[j2] = __builtin_amdgcn_mfma_f32_16x16x32_bf16(af, bf, acc[j2], 0,0,0);
            }
        }
    }
    #pragma unroll
    for(int j2=0;j2<8;j2++)
        #pragma unroll
        for(int r=0;r<4;r++){
            int row = wm*16 + kg*4 + r;
            int col = wn*128 + j2*16 + lm;
            Hs[row][col] = f2bf(gelu_f(acc[j2][r] + b1[col]));
        }
    __syncthreads();
    f32x4 acc2[4];
    #pragma unroll
    for(int j=0;j<4;j++) acc2[j] = (f32x4){0.f,0.f,0.f,0.f};
    #pragma unroll
    for(int k0=0;k0<256;k0+=32){
        bf16x8 af = *(const bf16x8*)(&Hs[wm*16 + lm][k0 + kg*8]);
        const u16* Bb = FC2 + (size_t)((k0>>3)+kg)*1024 + (wn*64+lm)*8;
        #pragma unroll
        for(int j2=0;j2<4;j2++){
            bf16x8 bf = *(const bf16x8*)(Bb + j2*128);
            acc2[j2] = __builtin_amdgcn_mfma_f32_16x16x32_bf16(af, bf, acc2[j2], 0,0,0);
        }
    }
    #pragma unroll
    for(int j2=0;j2<4;j2++)
        #pragma unroll
        for(int r=0;r<4;r++){
            int row = wm*16 + kg*4 + r;
            long p = m0 + row;
            if(p < NP){
                int n = wn*64 + j2*16 + lm;
                float v = acc2[j2][r] + b2[n] + bf2f(addb[p*128 + n]);
                OUT[p*128 + n] = f2bf(v);
            }
        }
}

// ============ WIDE spectral GEMM: 64 rows/block, full N=384, A read once ====
template<int TMODE>
__global__ __launch_bounds__(512, 4) void k_gemmw(
    const u16* __restrict__ A, const u16* __restrict__ B, u16* __restrict__ C)
{
    __shared__ u16 Ts[64*392];
    int tid = threadIdx.x;
    int l = tid & 63, wv = tid >> 6;
    int lm = l & 15, kg = l >> 4;
    int m0 = blockIdx.x * 64;

    const u16* ap = A + (size_t)(m0 + lm)*384 + kg*8;
    int bn[3];
    #pragma unroll
    for(int j2=0;j2<3;j2++) bn[j2] = (wv*48 + j2*16 + lm)*8 + kg*3072;

    f32x4 acc[4][3];
    #pragma unroll
    for(int f=0;f<4;f++)
        #pragma unroll
        for(int j2=0;j2<3;j2++) acc[f][j2] = (f32x4){0.f,0.f,0.f,0.f};

    #pragma unroll
    for(int ks=0; ks<12; ks++){
        const int k0 = ks*32;
        bf16x8 af[4];
        #pragma unroll
        for(int f=0;f<4;f++) af[f] = *(const bf16x8*)(ap + f*16*384 + k0);
        const u16* Bb = B + (size_t)(ks*4)*3072;
        bf16x8 bf[3];
        #pragma unroll
        for(int j2=0;j2<3;j2++) bf[j2] = *(const bf16x8*)(Bb + bn[j2]);
        #pragma unroll
        for(int f=0;f<4;f++)
            #pragma unroll
            for(int j2=0;j2<3;j2++)
                acc[f][j2] = __builtin_amdgcn_mfma_f32_16x16x32_bf16(af[f], bf[j2], acc[f][j2], 0,0,0);
    }

    #pragma unroll
    for(int f=0;f<4;f++)
        #pragma unroll
        for(int j2=0;j2<3;j2++)
            #pragma unroll
            for(int r=0;r<4;r++)
                Ts[(f*16 + kg*4 + r)*392 + wv*48 + j2*16 + lm] = f2bf(acc[f][j2][r]);
    __syncthreads();

    if constexpr (TMODE != 5){
        #pragma unroll
        for(int it=0; it<6; it++){
            int g = tid + it*512;
            int gn = g % 192, gm = g / 192;
            int ml = gm*4, nl = gn*2;
            int mg = m0 + ml, ng = nl;
            long base;
            if constexpr (TMODE == 1){
                int c = (int)(((unsigned)mg*43691u)>>23);
                int sub = mg - c*192;
                base = ((long)((ng>>1)*128 + c))*384 + 2*sub;
            } else {
                int kw = mg>>7, c = mg&127;
                base = ((long)(kw*192 + (ng>>1)))*256 + 2*c;
            }
            us8 v;
            #pragma unroll
            for(int i=0;i<4;i++){
                v[2*i]   = Ts[(ml+i)*392 + nl];
                v[2*i+1] = Ts[(ml+i)*392 + nl+1];
            }
            *(us8*)(C + base) = v;
        }
    } else {
        #pragma unroll
        for(int it=0; it<6; it++){
            int g = tid + it*512;
            int nl = g % 384, gm = g / 384;
            int ml = gm*8;
            int mg = m0 + ml;
            if(nl < 360){
                int h = mg >> 7;
                long base = ((long)(h*360 + nl))*128 + (mg & 127);
                us8 v;
                #pragma unroll
                for(int j=0;j<8;j++) v[j] = Ts[(ml+j)*392 + nl];
                *(us8*)(C + base) = v;
            }
        }
    }
}

// ============ row-major MFMA GEMM (encoder/skip/decoder) ============
template<int KSTEPS, bool SPLIT>
__global__ __launch_bounds__(256, 2) void k_gemm(
    const u16* __restrict__ A1, const u16* __restrict__ A2, int aksplit, int astr, int a2str,
    const u16* __restrict__ B, int bkstr,
    u16* __restrict__ C, int cstr,
    const float* __restrict__ bias, const u16* __restrict__ addb,
    int Mvalid, int N, int flags)
{
    int tid = threadIdx.x;
    int l = tid & 63, wv = tid >> 6;
    int wm = wv >> 1, wn = wv & 1;
    int lm = l & 15, kgl = l >> 4;
    int m0 = blockIdx.y*128 + wm*64;
    int n0 = blockIdx.x*128 + wn*64;

    int ab1[4], ab2[4];
    #pragma unroll
    for(int i2=0;i2<4;i2++){
        int mi = m0 + i2*16 + lm;
        ab1[i2] = mi*astr + kgl*8;
        ab2[i2] = mi*a2str + kgl*8;
    }
    int bn[4];
    #pragma unroll
    for(int j2=0;j2<4;j2++) bn[j2] = (n0 + j2*16 + lm)*8 + kgl*bkstr;

    f32x4 acc[4][4];
    #pragma unroll
    for(int i2=0;i2<4;i2++)
        #pragma unroll
        for(int j2=0;j2<4;j2++)
            acc[i2][j2] = (f32x4){0.0f,0.0f,0.0f,0.0f};

    #pragma unroll
    for(int ks=0; ks<KSTEPS; ks++){
        const int k0 = ks*32;
        bf16x8 af[4];
        if constexpr (SPLIT){
            int kk = k0 + kgl*8;
            bool s1v = kk < aksplit;
            #pragma unroll
            for(int i2=0;i2<4;i2++)
                af[i2] = s1v ? *(const bf16x8*)(A1 + ab1[i2] + k0)
                             : *(const bf16x8*)(A2 + ab2[i2] + k0 - aksplit);
        } else {
            #pragma unroll
            for(int i2=0;i2<4;i2++)
                af[i2] = *(const bf16x8*)(A1 + ab1[i2] + k0);
        }
        const u16* Bb = B + (size_t)(ks*4)*bkstr;
        bf16x8 bf[4];
        #pragma unroll
        for(int j2=0;j2<4;j2++)
            bf[j2] = *(const bf16x8*)(Bb + bn[j2]);
        #pragma unroll
        for(int i2=0;i2<4;i2++)
            #pragma unroll
            for(int j2=0;j2<4;j2++)
                acc[i2][j2] = __builtin_amdgcn_mfma_f32_16x16x32_bf16(af[i2], bf[j2], acc[i2][j2], 0,0,0);
    }

    #pragma unroll
    for(int i2=0;i2<4;i2++){
        #pragma unroll
        for(int r=0;r<4;r++){
            int m = m0 + i2*16 + kgl*4 + r;
            if(m >= Mvalid) continue;
            long mb = (long)m*cstr;
            #pragma unroll
            for(int j2=0;j2<4;j2++){
                int n = n0 + j2*16 + lm;
                if(n >= N) continue;
                float v = acc[i2][j2][r];
                if(bias) v += bias[n];
                if(flags & 1) v = gelu_f(v);
                long ca = mb + n;
                if(addb) v += bf2f(addb[ca]);
                C[ca] = f2bf(v);
            }
        }
    }
}

// ============ launch ============
extern "C" void kernel_launch(void* const* d_in, const int* in_sizes, int n_in,
                              void* d_out, int out_size, void* d_ws, size_t ws_size,
                              hipStream_t stream) {
    const float* x       = (const float*)d_in[0];
    const float* enc_w0  = (const float*)d_in[1];
    const float* enc_b0  = (const float*)d_in[2];
    const float* enc_w1  = (const float*)d_in[3];
    const float* pos     = (const float*)d_in[4];
    const float* n0w     = (const float*)d_in[5];
    const float* n0b     = (const float*)d_in[6];
    const float* w0      = (const float*)d_in[7];
    const float* w1      = (const float*)d_in[8];
    const float* wout    = (const float*)d_in[9];
    const float* isw     = (const float*)d_in[10];
    const float* isb     = (const float*)d_in[11];
    const float* n1w     = (const float*)d_in[12];
    const float* n1b     = (const float*)d_in[13];
    const float* fc1w    = (const float*)d_in[14];
    const float* fc1b    = (const float*)d_in[15];
    const float* fc2w    = (const float*)d_in[16];
    const float* fc2b    = (const float*)d_in[17];
    const float* dec_w0  = (const float*)d_in[18];
    const float* dec_b0  = (const float*)d_in[19];
    const float* dec_w1  = (const float*)d_in[20];
    float* out = (float*)d_out;

    u16* ws = (u16*)d_ws;
    size_t off = 0;
    auto al = [&](size_t n){ u16* p = ws + off; off += (n + 63) & ~(size_t)63; return p; };
    u16* TWF  = al(147456);
    u16* THF  = al(196608);
    u16* THI  = al(147456);
    u16* TWI  = al(147456);
    u16* W0P  = al(524288);
    u16* W1P  = al(1048576);
    u16* WOP  = al(524288);
    u16* ISWP = al(65536);
    u16* FC1P = al(131072);
    u16* FC2P = al(131072);
    u16* EW1P = al(16384);
    u16* DW0P = al(20480);
    u16* POSP = al((size_t)NPAD*128);
    u16* XT2  = al((size_t)NPAD*32);
    u16* CURP = al((size_t)NPAD*128);
    u16* XNP  = al((size_t)NPAD*128);
    u16* YP   = al((size_t)NPAD*128);
    u16* XNC  = al((size_t)24576*384);   // [c*192+h][384]
    u16* A2b  = al((size_t)24576*384);   // [kw*128+c][2h+q]  (also A5: [h*128+c][2kw+q])
    u16* A3b  = al((size_t)36864*256);   // [kw*192+kh][2c+p]
    u16* A4b  = al((size_t)24576*384);   // [c*192+kw][2kh+p]
    u16* BIG  = al((size_t)NPAD*128);    // ENC [pt][128]
    u16* IST  = al(4096);
    float* ISTAT = (float*)IST;
    u16* A5b = A2b;
    u16* ENC = BIG;

    dim3 blk(256);
    k_zero<<<dim3(4608), blk, 0, stream>>>(XNC, (long)24576*384);
    k_zero<<<dim3(2),    blk, 0, stream>>>(IST, 4096);

    // packs
    k_pack_twf<<<dim3((147456+255)/256), blk, 0, stream>>>(TWF);
    k_pack_thf<<<dim3((196608+255)/256), blk, 0, stream>>>(THF);
    k_pack_thi<<<dim3((147456+255)/256), blk, 0, stream>>>(THI);
    k_pack_twi<<<dim3((147456+255)/256), blk, 0, stream>>>(TWI);
    k_pack_cw<<<dim3((131072+255)/256,1,4), blk, 0, stream>>>(w0,   W0P, 128, 256, 2*128*256, 131072);
    k_pack_cw<<<dim3((262144+255)/256,1,4), blk, 0, stream>>>(w1,   W1P, 256, 256, 2*256*256, 262144);
    k_pack_cw<<<dim3((131072+255)/256,1,4), blk, 0, stream>>>(wout, WOP, 256, 128, 2*256*128, 131072);
    k_pack_rw<<<dim3((16384+255)/256,1,4),  blk, 0, stream>>>(isw,  ISWP, 128, 128, 16, 128*128, 16384);
    k_pack_rw<<<dim3((32768+255)/256,1,4),  blk, 0, stream>>>(fc1w, FC1P, 256, 128, 16, 256*128, 32768);
    k_pack_rw<<<dim3((32768+255)/256,1,4),  blk, 0, stream>>>(fc2w, FC2P, 128, 256, 32, 128*256, 32768);
    k_pack_rw<<<dim3((16384+255)/256,1,1),  blk, 0, stream>>>(enc_w1, EW1P, 128, 128, 16, 0, 0);
    k_pack_rw<<<dim3((20480+255)/256,1,1),  blk, 0, stream>>>(dec_w0, DW0P, 128, 130, 20, 0, 0);
    k_post<<<dim3(1019), blk, 0, stream>>>(pos, POSP);
    k_xt2 <<<dim3((NP+255)/256), blk, 0, stream>>>(x, XT2);

    const u16* nu = nullptr;
    const float* nf = nullptr;
    const int BIGV = 1<<28;

    // encoder
    k_enc0<<<dim3((NP*16+255)/256), blk, 0, stream>>>(x, enc_w0, enc_b0, ENC);
    k_gemm<4,false><<<dim3(1,510), blk, 0, stream>>>(
        ENC, ENC, BIGV, 128, 128, EW1P, 1024, CURP, 128, nf, POSP, NP, 128, 0);

    for(int l=0; l<4; l++){
        float* st0 = ISTAT + (2*l)*256;
        float* st1 = ISTAT + (2*l+1)*256;
        k_istat<<<dim3(128), blk, 0, stream>>>(CURP, st0);
        k_apply_t<<<dim3(1019), blk, 0, stream>>>(CURP, XNP, XNC, st0, n0w+l*128, n0b+l*128);
        // S1 rdft: XNC x TWF -> A2 [kw*128+c][2h+q]
        k_gemmw<1><<<dim3(384), dim3(512), 0, stream>>>(XNC, TWF, A2b);
        // S2 H-DFT fwd: A2 x THF -> A3 [kw*192+kh][2c+p]
        k_gemmw<2><<<dim3(384), dim3(512), 0, stream>>>(A2b, THF, A3b);
        // fused spectral channel-MLP: A3 -> A4 [c*192+kw][2kh+p]
        k_smlp<<<dim3(768), dim3(512), 0, stream>>>(A3b,
            W0P + (size_t)l*131072, W1P + (size_t)l*262144, WOP + (size_t)l*131072, A4b);
        // S6 H-DFT inv: A4 x THI -> A5 [h*128+c][2kw+q]
        k_gemmw<1><<<dim3(384), dim3(512), 0, stream>>>(A4b, THI, A5b);
        // S7 irdft: A5 x TWI -> YP [pt][128]
        k_gemmw<5><<<dim3(362), dim3(512), 0, stream>>>(A5b, TWI, YP);
        // inner skip: CUR = isw*XN + isb + Y
        k_gemm<4,false><<<dim3(1,510), blk, 0, stream>>>(
            XNP, XNP, BIGV, 128, 128, ISWP + (size_t)l*16384, 1024, CURP, 128,
            isb+l*128, YP, NP, 128, 0);
        // norm1 stats + fused (norm1 -> fc1 -> gelu -> fc2 -> +XNP) in-place on CURP
        k_istat<<<dim3(128), blk, 0, stream>>>(CURP, st1);
        k_pmlp<<<dim3(1019), dim3(512), 0, stream>>>(CURP,
            FC1P + (size_t)l*32768, FC2P + (size_t)l*32768,
            fc1b + l*256, fc2b + l*128,
            st1, n1w + l*128, n1b + l*128, XNP, CURP);
    }
    // decoder conv0 (concat CUR, x) + gelu -> XNP
    k_gemm<5,true><<<dim3(1,510), blk, 0, stream>>>(
        CURP, XT2, 128, 128, 32, DW0P, 1024, XNP, 128, dec_b0, nu, NP, 128, 1);
    k_dec1<<<dim3((NP+255)/256), blk, 0, stream>>>(XNP, dec_w1, out);
}

// Round 13
// 1462.323 us; speedup vs baseline: 1.1311x; 1.0639x over previous
//
#include <hip/hip_runtime.h>
#include <math.h>

#define NP 65160        // 181*360
#define NPAD 65280

typedef unsigned short u16;
typedef __attribute__((ext_vector_type(8))) short bf16x8;
typedef __attribute__((ext_vector_type(8))) unsigned short us8;
typedef __attribute__((ext_vector_type(4))) float f32x4;

__device__ __forceinline__ u16 f2bf(float f){
    unsigned u = __builtin_bit_cast(unsigned, f);
    return (u16)((u + 0x7FFFu + ((u>>16)&1u)) >> 16);
}
__device__ __forceinline__ float bf2f(u16 h){
    unsigned u = ((unsigned)h)<<16;
    return __builtin_bit_cast(float, u);
}
__device__ __forceinline__ float gelu_f(float x){
    return 0.5f*x*(1.0f+erff(x*0.70710678118654752f));
}

__global__ void k_zero(u16* __restrict__ p, long n){
    long i = ((long)blockIdx.x*256 + threadIdx.x)*8;
    if(i+8 <= n){ us8 z = {0,0,0,0,0,0,0,0}; *(us8*)(p+i) = z; }
}

// ============ B packs: dst[kg][n][8], k = kg*8+e, zero padded ============
__global__ void k_pack_twf(u16* __restrict__ dst){   // [48][384][8]: k=w, n=2kw+q
    int i = blockIdx.x*256+threadIdx.x; if(i >= 48*384*8) return;
    int e = i&7, n = (i>>3)%384, kg = i/(384*8);
    int k = kg*8+e, kw = n>>1, q = n&1;
    float v = 0.0f;
    if(k < 360 && kw < 181){
        float inv = 1.0f/sqrtf(65160.0f);
        float th = 6.28318530717958647692f*(float)((k*kw)%360)/360.0f;
        v = q ? -sinf(th)*inv : cosf(th)*inv;
    }
    dst[i] = f2bf(v);
}
__global__ void k_pack_thf(u16* __restrict__ dst){   // [64][384][8]: k=2h+q, n=2kh+p
    int i = blockIdx.x*256+threadIdx.x; if(i >= 64*384*8) return;
    int e = i&7, n = (i>>3)%384, kg = i/(384*8);
    int k = kg*8+e;
    float v = 0.0f;
    if(k < 362 && n < 362){
        int h = k>>1, q = k&1, kh = n>>1, p = n&1;
        float th = 6.28318530717958647692f*(float)((h*kh)%181)/181.0f;
        float c = cosf(th), s = sinf(th);
        v = (q==0) ? (p==0? c : -s) : (p==0? s : c);
    }
    dst[i] = f2bf(v);
}
__global__ void k_pack_thi(u16* __restrict__ dst){   // [48][384][8]: k=2kh+p, n=2h+q
    int i = blockIdx.x*256+threadIdx.x; if(i >= 48*384*8) return;
    int e = i&7, n = (i>>3)%384, kg = i/(384*8);
    int k = kg*8+e;
    float v = 0.0f;
    if(k < 362 && n < 362){
        int kh = k>>1, p = k&1, h = n>>1, q = n&1;
        float th = 6.28318530717958647692f*(float)((kh*h)%181)/181.0f;
        float c = cosf(th), s = sinf(th);
        v = (q==0) ? (p==0? c : -s) : (p==0? s : c);
    }
    dst[i] = f2bf(v);
}
__global__ void k_pack_twi(u16* __restrict__ dst){   // [48][384][8]: k=2kw+q, n=w
    int i = blockIdx.x*256+threadIdx.x; if(i >= 48*384*8) return;
    int e = i&7, n = (i>>3)%384, kg = i/(384*8);
    int k = kg*8+e, kw = k>>1, q = k&1;
    float v = 0.0f;
    if(k < 362 && n < 360){
        float inv = 1.0f/sqrtf(65160.0f);
        float eps = (kw==0 || kw==180) ? 1.0f : 2.0f;
        float th = 6.28318530717958647692f*(float)((n*kw)%360)/360.0f;
        v = q ? -eps*sinf(th)*inv : eps*cosf(th)*inv;
    }
    dst[i] = f2bf(v);
}
__global__ void k_pack_cw(const float* __restrict__ src, u16* __restrict__ dst,
                          int CIN, int COUT, int lss, int lsd){
    int z = blockIdx.z;
    int Npad = 2*COUT, KG = (2*CIN)/8;
    int tot = KG*Npad*8;
    int i = blockIdx.x*256+threadIdx.x; if(i >= tot) return;
    int e = i&7, n = (i>>3)%Npad, kg = i/(Npad*8);
    int k = kg*8+e, ci = k>>1, q = k&1, co = n>>1, p = n&1;
    float re = src[(size_t)z*lss + ci*COUT + co];
    float im = src[(size_t)z*lss + CIN*COUT + ci*COUT + co];
    float v = (p==0) ? (q==0? re : -im) : (q==0? im : re);
    dst[(size_t)z*lsd + i] = f2bf(v);
}
__global__ void k_pack_rw(const float* __restrict__ src, u16* __restrict__ dst,
                          int Nn, int Ks, int KG, int lss, int lsd){
    int z = blockIdx.z;
    int tot = KG*Nn*8;
    int i = blockIdx.x*256+threadIdx.x; if(i >= tot) return;
    int e = i&7, n = (i>>3)%Nn, kg = i/(Nn*8);
    int k = kg*8+e;
    float v = (k < Ks) ? src[(size_t)z*lss + n*Ks + k] : 0.0f;
    dst[(size_t)z*lsd + i] = f2bf(v);
}

// ============ pointwise ============
__global__ void k_enc0(const float* __restrict__ x, const float* __restrict__ w,
                       const float* __restrict__ b, u16* __restrict__ out){
    int i = blockIdx.x*256+threadIdx.x;
    if(i >= NP*16) return;
    int p = i>>4, c8 = (i&15)*8;
    float x0 = x[p], x1 = x[NP+p];
    us8 o;
    #pragma unroll
    for(int j=0;j<8;j++){
        int e = c8+j;
        float v = w[e*2]*x0 + w[e*2+1]*x1 + b[e];
        o[j] = f2bf(gelu_f(v));
    }
    *(us8*)(out + (size_t)p*128 + c8) = o;
}
__global__ void k_xt2(const float* __restrict__ x, u16* __restrict__ dst){
    int p = blockIdx.x*256+threadIdx.x; if(p >= NP) return;
    us8 z = {0,0,0,0,0,0,0,0};
    z[0] = f2bf(x[p]); z[1] = f2bf(x[NP+p]);
    *(us8*)(dst + (size_t)p*32) = z;
    us8 z2 = {0,0,0,0,0,0,0,0};
    *(us8*)(dst + (size_t)p*32 + 8)  = z2;
    *(us8*)(dst + (size_t)p*32 + 16) = z2;
    *(us8*)(dst + (size_t)p*32 + 24) = z2;
}
__global__ void k_dec1(const u16* __restrict__ hid, const float* __restrict__ w,
                       float* __restrict__ out){
    int p = blockIdx.x*256+threadIdx.x; if(p >= NP) return;
    float a0=0.0f, a1=0.0f;
    #pragma unroll 4
    for(int k8=0;k8<16;k8++){
        us8 v = *(const us8*)(hid + (size_t)p*128 + k8*8);
        #pragma unroll
        for(int j=0;j<8;j++){
            float f = bf2f(v[j]);
            a0 = fmaf(w[k8*8+j], f, a0);
            a1 = fmaf(w[128+k8*8+j], f, a1);
        }
    }
    out[p] = a0; out[NP+p] = a1;
}

// apply norm -> XNP [pt][128]; also XNC[(c*192+h)*384 + w]
__global__ __launch_bounds__(256) void k_apply_t(
    const u16* __restrict__ X, u16* __restrict__ outp, u16* __restrict__ outc,
    const float* __restrict__ stat, const float* __restrict__ gw, const float* __restrict__ gb)
{
    __shared__ u16 T[128][72];
    __shared__ float SA_[128], SB_[128];
    int t = threadIdx.x;
    if(t < 128){
        float mu = stat[t]*(1.0f/(float)NP);
        float var = stat[128+t]*(1.0f/(float)NP) - mu*mu;
        var = fmaxf(var, 0.0f);
        float rstd = 1.0f/sqrtf(var + 1e-6f);
        float a = rstd*gw[t];
        SA_[t] = a; SB_[t] = gb[t] - mu*a;
    }
    __syncthreads();
    int p0 = blockIdx.x*64;
    int pl = t>>2, cc = (t&3)*32;
    int p = p0 + pl;
    if(p < NP){
        #pragma unroll
        for(int jj=0;jj<4;jj++){
            us8 v = *(const us8*)(X + (size_t)p*128 + cc + jj*8);
            us8 o;
            #pragma unroll
            for(int j=0;j<8;j++){
                int c = cc + jj*8 + j;
                o[j] = f2bf(fmaf(bf2f(v[j]), SA_[c], SB_[c]));
            }
            *(us8*)(outp + (size_t)p*128 + cc + jj*8) = o;
            #pragma unroll
            for(int j=0;j<8;j++) T[cc+jj*8+j][pl] = o[j];
        }
    }
    __syncthreads();
    int c = t>>1, half = t&1;
    int pbase = p0 + half*32;
    #pragma unroll
    for(int jj=0;jj<4;jj++){
        int pp = pbase + jj*8;
        if(pp + 8 <= NP){
            int hh = pp/360, ww = pp - hh*360;
            *(us8*)(outc + ((size_t)c*192 + hh)*384 + ww) = *(const us8*)(&T[c][half*32 + jj*8]);
        }
    }
}
__global__ __launch_bounds__(256) void k_post(const float* __restrict__ src, u16* __restrict__ dst){
    __shared__ u16 T[128][72];
    int t = threadIdx.x;
    int p0 = blockIdx.x*64;
    int c = t>>1, half = t&1;
    int pbase = p0 + half*32;
    #pragma unroll
    for(int jj=0;jj<4;jj++){
        int pp = pbase + jj*8;
        us8 v = {0,0,0,0,0,0,0,0};
        if(pp + 8 <= NP){
            #pragma unroll
            for(int j=0;j<8;j++) v[j] = f2bf(src[(size_t)c*NP + pp + j]);
        }
        *(us8*)(&T[c][half*32 + jj*8]) = v;
    }
    __syncthreads();
    int pl = t>>2, cc = (t&3)*32;
    int p = p0 + pl;
    if(p < NP){
        #pragma unroll
        for(int jj=0;jj<4;jj++){
            us8 o;
            #pragma unroll
            for(int j=0;j<8;j++) o[j] = T[cc+jj*8+j][pl];
            *(us8*)(dst + (size_t)p*128 + cc + jj*8) = o;
        }
    }
}

// ============ fused spectral channel-MLP (S3+S4+S5), 32 rows/block ============
// LDS 66.5 KB -> 2 blocks/CU (16 waves). 8 col-waves x 2 A-frags.
__global__ __launch_bounds__(512, 4) void k_smlp(
    const u16* __restrict__ A3, const u16* __restrict__ W0,
    const u16* __restrict__ W1, const u16* __restrict__ WO,
    u16* __restrict__ A4)
{
    __shared__ u16 Hs0[32*520];
    __shared__ u16 Hs1[32*520];
    int tid = threadIdx.x;
    int l = tid & 63, wn = tid >> 6;     // 8 col-groups
    int lm = l & 15, kg = l >> 4;
    int m0 = blockIdx.x * 32;

    f32x4 acc[2][4];
    // ---- stage 1: Hs0[32][512] = A3 x W0 (K=256), CReLU even col ----
    #pragma unroll
    for(int f=0;f<2;f++)
        #pragma unroll
        for(int j2=0;j2<4;j2++) acc[f][j2] = (f32x4){0.f,0.f,0.f,0.f};
    {
        const u16* ap = A3 + (size_t)(m0 + lm)*256 + kg*8;
        #pragma unroll
        for(int k0=0;k0<256;k0+=32){
            bf16x8 af[2];
            #pragma unroll
            for(int f=0;f<2;f++) af[f] = *(const bf16x8*)(ap + f*16*256 + k0);
            const u16* Bb = W0 + (size_t)((k0>>3)+kg)*4096 + (wn*64+lm)*8;
            #pragma unroll
            for(int j2=0;j2<4;j2++){
                bf16x8 bf = *(const bf16x8*)(Bb + j2*128);
                #pragma unroll
                for(int f=0;f<2;f++)
                    acc[f][j2] = __builtin_amdgcn_mfma_f32_16x16x32_bf16(af[f], bf, acc[f][j2], 0,0,0);
            }
        }
    }
    #pragma unroll
    for(int f=0;f<2;f++)
        #pragma unroll
        for(int j2=0;j2<4;j2++)
            #pragma unroll
            for(int r=0;r<4;r++){
                int row = f*16 + kg*4 + r;
                int col = wn*64 + j2*16 + lm;
                float v = acc[f][j2][r];
                if(!(col&1)) v = fmaxf(v, 0.0f);
                Hs0[row*520 + col] = f2bf(v);
            }
    __syncthreads();
    // ---- stage 2: Hs1 = Hs0 x W1 (K=512), CReLU even col ----
    #pragma unroll
    for(int f=0;f<2;f++)
        #pragma unroll
        for(int j2=0;j2<4;j2++) acc[f][j2] = (f32x4){0.f,0.f,0.f,0.f};
    #pragma unroll 2
    for(int k0=0;k0<512;k0+=32){
        bf16x8 af[2];
        #pragma unroll
        for(int f=0;f<2;f++) af[f] = *(const bf16x8*)(&Hs0[(f*16+lm)*520 + k0 + kg*8]);
        const u16* Bb = W1 + (size_t)((k0>>3)+kg)*4096 + (wn*64+lm)*8;
        #pragma unroll
        for(int j2=0;j2<4;j2++){
            bf16x8 bf = *(const bf16x8*)(Bb + j2*128);
            #pragma unroll
            for(int f=0;f<2;f++)
                acc[f][j2] = __builtin_amdgcn_mfma_f32_16x16x32_bf16(af[f], bf, acc[f][j2], 0,0,0);
        }
    }
    #pragma unroll
    for(int f=0;f<2;f++)
        #pragma unroll
        for(int j2=0;j2<4;j2++)
            #pragma unroll
            for(int r=0;r<4;r++){
                int row = f*16 + kg*4 + r;
                int col = wn*64 + j2*16 + lm;
                float v = acc[f][j2][r];
                if(!(col&1)) v = fmaxf(v, 0.0f);
                Hs1[row*520 + col] = f2bf(v);
            }
    __syncthreads();
    // ---- stage 3: O[32][256] = Hs1 x WO (K=512) ----
    f32x4 acc3[2][2];
    #pragma unroll
    for(int f=0;f<2;f++)
        #pragma unroll
        for(int j2=0;j2<2;j2++) acc3[f][j2] = (f32x4){0.f,0.f,0.f,0.f};
    #pragma unroll 2
    for(int k0=0;k0<512;k0+=32){
        bf16x8 af[2];
        #pragma unroll
        for(int f=0;f<2;f++) af[f] = *(const bf16x8*)(&Hs1[(f*16+lm)*520 + k0 + kg*8]);
        const u16* Bb = WO + (size_t)((k0>>3)+kg)*2048 + (wn*32+lm)*8;
        #pragma unroll
        for(int j2=0;j2<2;j2++){
            bf16x8 bf = *(const bf16x8*)(Bb + j2*128);
            #pragma unroll
            for(int f=0;f<2;f++)
                acc3[f][j2] = __builtin_amdgcn_mfma_f32_16x16x32_bf16(af[f], bf, acc3[f][j2], 0,0,0);
        }
    }
    // O staged into Hs0 at stride 258 (Hs0 readers finished before prior barrier)
    #pragma unroll
    for(int f=0;f<2;f++)
        #pragma unroll
        for(int j2=0;j2<2;j2++)
            #pragma unroll
            for(int r=0;r<4;r++){
                int row = f*16 + kg*4 + r;
                int col = wn*32 + j2*16 + lm;
                Hs0[row*258 + col] = f2bf(acc3[f][j2][r]);
            }
    __syncthreads();
    // ---- coalesced store: A4[(c*192+kw)*384 + 2kh+p] ----
    int kw = m0 / 192;                 // 192%32==0 -> blocks never straddle kw
    int kh0 = m0 - kw*192;
    int c = tid >> 2, q = tid & 3;     // q covers 8 rows each
    long base = ((long)(c*192 + kw))*384 + 2*(kh0 + q*8);
    #pragma unroll
    for(int jj=0;jj<2;jj++){
        us8 v;
        #pragma unroll
        for(int i=0;i<4;i++){
            v[2*i]   = Hs0[(q*8 + jj*4 + i)*258 + 2*c];
            v[2*i+1] = Hs0[(q*8 + jj*4 + i)*258 + 2*c+1];
        }
        *(us8*)(A4 + base + jj*8) = v;
    }
}

// ============ fused spatial MLP: norm1+fc1+gelu+fc2+outer-skip + next-layer stats ====
__global__ __launch_bounds__(512) void k_pmlp(
    const u16* __restrict__ A, const u16* __restrict__ FC1, const u16* __restrict__ FC2,
    const float* __restrict__ b1, const float* __restrict__ b2,
    const float* __restrict__ stat, const float* __restrict__ gw, const float* __restrict__ gb,
    const u16* __restrict__ addb, u16* __restrict__ OUT, float* __restrict__ statout)
{
    __shared__ u16 Hs[64][264];
    __shared__ float SA_[128], SB_[128];
    __shared__ float SS[128], SS2[128];
    int tid = threadIdx.x;
    int l = tid & 63, wv = tid >> 6;
    int wm = wv >> 1, wn = wv & 1;
    int lm = l & 15, kg = l >> 4;
    int m0 = blockIdx.x * 64;
    if(tid < 128){
        float mu = stat[tid]*(1.0f/(float)NP);
        float var = stat[128+tid]*(1.0f/(float)NP) - mu*mu;
        var = fmaxf(var, 0.0f);
        float rstd = 1.0f/sqrtf(var + 1e-6f);
        float a = rstd*gw[tid];
        SA_[tid] = a; SB_[tid] = gb[tid] - mu*a;
        SS[tid] = 0.0f; SS2[tid] = 0.0f;
    }
    __syncthreads();

    f32x4 acc[8];
    #pragma unroll
    for(int j=0;j<8;j++) acc[j] = (f32x4){0.f,0.f,0.f,0.f};
    {
        const u16* ap = A + (size_t)(m0 + wm*16 + lm)*128 + kg*8;
        #pragma unroll
        for(int k0=0;k0<128;k0+=32){
            us8 raw = *(const us8*)(ap + k0);
            bf16x8 af;
            #pragma unroll
            for(int j=0;j<8;j++){
                int ch = kg*8 + k0 + j;
                af[j] = (short)f2bf(fmaf(bf2f(raw[j]), SA_[ch], SB_[ch]));
            }
            const u16* Bb = FC1 + (size_t)((k0>>3)+kg)*2048 + (wn*128+lm)*8;
            #pragma unroll
            for(int j2=0;j2<8;j2++){
                bf16x8 bf = *(const bf16x8*)(Bb + j2*128);
                acc[j2] = __builtin_amdgcn_mfma_f32_16x16x32_bf16(af, bf, acc[j2], 0,0,0);
            }
        }
    }
    #pragma unroll
    for(int j2=0;j2<8;j2++)
        #pragma unroll
        for(int r=0;r<4;r++){
            int row = wm*16 + kg*4 + r;
            int col = wn*128 + j2*16 + lm;
            Hs[row][col] = f2bf(gelu_f(acc[j2][r] + b1[col]));
        }
    __syncthreads();
    f32x4 acc2[4];
    #pragma unroll
    for(int j=0;j<4;j++) acc2[j] = (f32x4){0.f,0.f,0.f,0.f};
    #pragma unroll
    for(int k0=0;k0<256;k0+=32){
        bf16x8 af = *(const bf16x8*)(&Hs[wm*16 + lm][k0 + kg*8]);
        const u16* Bb = FC2 + (size_t)((k0>>3)+kg)*1024 + (wn*64+lm)*8;
        #pragma unroll
        for(int j2=0;j2<4;j2++){
            bf16x8 bf = *(const bf16x8*)(Bb + j2*128);
            acc2[j2] = __builtin_amdgcn_mfma_f32_16x16x32_bf16(af, bf, acc2[j2], 0,0,0);
        }
    }
    float ts[4] = {0.f,0.f,0.f,0.f}, ts2[4] = {0.f,0.f,0.f,0.f};
    #pragma unroll
    for(int j2=0;j2<4;j2++)
        #pragma unroll
        for(int r=0;r<4;r++){
            int row = wm*16 + kg*4 + r;
            long p = m0 + row;
            if(p < NP){
                int n = wn*64 + j2*16 + lm;
                float v = acc2[j2][r] + b2[n] + bf2f(addb[p*128 + n]);
                u16 hv = f2bf(v);
                OUT[p*128 + n] = hv;
                float vq = bf2f(hv);
                ts[j2] += vq; ts2[j2] = fmaf(vq, vq, ts2[j2]);
            }
        }
    #pragma unroll
    for(int j2=0;j2<4;j2++){
        int n = wn*64 + j2*16 + lm;
        atomicAdd(&SS[n], ts[j2]);
        atomicAdd(&SS2[n], ts2[j2]);
    }
    __syncthreads();
    if(tid < 128){
        atomicAdd(&statout[tid], SS[tid]);
        atomicAdd(&statout[128+tid], SS2[tid]);
    }
}

// ============ WIDE spectral GEMM: 64 rows/block, full N=384, A read once ====
template<int TMODE>
__global__ __launch_bounds__(512, 4) void k_gemmw(
    const u16* __restrict__ A, const u16* __restrict__ B, u16* __restrict__ C)
{
    __shared__ u16 Ts[64*392];
    int tid = threadIdx.x;
    int l = tid & 63, wv = tid >> 6;
    int lm = l & 15, kg = l >> 4;
    int m0 = blockIdx.x * 64;

    const u16* ap = A + (size_t)(m0 + lm)*384 + kg*8;
    int bn[3];
    #pragma unroll
    for(int j2=0;j2<3;j2++) bn[j2] = (wv*48 + j2*16 + lm)*8 + kg*3072;

    f32x4 acc[4][3];
    #pragma unroll
    for(int f=0;f<4;f++)
        #pragma unroll
        for(int j2=0;j2<3;j2++) acc[f][j2] = (f32x4){0.f,0.f,0.f,0.f};

    #pragma unroll
    for(int ks=0; ks<12; ks++){
        const int k0 = ks*32;
        bf16x8 af[4];
        #pragma unroll
        for(int f=0;f<4;f++) af[f] = *(const bf16x8*)(ap + f*16*384 + k0);
        const u16* Bb = B + (size_t)(ks*4)*3072;
        bf16x8 bf[3];
        #pragma unroll
        for(int j2=0;j2<3;j2++) bf[j2] = *(const bf16x8*)(Bb + bn[j2]);
        #pragma unroll
        for(int f=0;f<4;f++)
            #pragma unroll
            for(int j2=0;j2<3;j2++)
                acc[f][j2] = __builtin_amdgcn_mfma_f32_16x16x32_bf16(af[f], bf[j2], acc[f][j2], 0,0,0);
    }

    #pragma unroll
    for(int f=0;f<4;f++)
        #pragma unroll
        for(int j2=0;j2<3;j2++)
            #pragma unroll
            for(int r=0;r<4;r++)
                Ts[(f*16 + kg*4 + r)*392 + wv*48 + j2*16 + lm] = f2bf(acc[f][j2][r]);
    __syncthreads();

    if constexpr (TMODE != 5){
        #pragma unroll
        for(int it=0; it<6; it++){
            int g = tid + it*512;
            int gn = g % 192, gm = g / 192;
            int ml = gm*4, nl = gn*2;
            int mg = m0 + ml, ng = nl;
            long base;
            if constexpr (TMODE == 1){
                int c = (int)(((unsigned)mg*43691u)>>23);
                int sub = mg - c*192;
                base = ((long)((ng>>1)*128 + c))*384 + 2*sub;
            } else {
                int kw = mg>>7, c = mg&127;
                base = ((long)(kw*192 + (ng>>1)))*256 + 2*c;
            }
            us8 v;
            #pragma unroll
            for(int i=0;i<4;i++){
                v[2*i]   = Ts[(ml+i)*392 + nl];
                v[2*i+1] = Ts[(ml+i)*392 + nl+1];
            }
            *(us8*)(C + base) = v;
        }
    } else {
        #pragma unroll
        for(int it=0; it<6; it++){
            int g = tid + it*512;
            int nl = g % 384, gm = g / 384;
            int ml = gm*8;
            int mg = m0 + ml;
            if(nl < 360){
                int h = mg >> 7;
                long base = ((long)(h*360 + nl))*128 + (mg & 127);
                us8 v;
                #pragma unroll
                for(int j=0;j<8;j++) v[j] = Ts[(ml+j)*392 + nl];
                *(us8*)(C + base) = v;
            }
        }
    }
}

// ============ row-major MFMA GEMM (encoder/skip/decoder), optional fused stats ====
template<int KSTEPS, bool SPLIT, bool STATS>
__global__ __launch_bounds__(256, 2) void k_gemm(
    const u16* __restrict__ A1, const u16* __restrict__ A2, int aksplit, int astr, int a2str,
    const u16* __restrict__ B, int bkstr,
    u16* __restrict__ C, int cstr,
    const float* __restrict__ bias, const u16* __restrict__ addb,
    float* __restrict__ statout,
    int Mvalid, int N, int flags)
{
    __shared__ float SS[128], SS2[128];
    int tid = threadIdx.x;
    int l = tid & 63, wv = tid >> 6;
    int wm = wv >> 1, wn = wv & 1;
    int lm = l & 15, kgl = l >> 4;
    int m0 = blockIdx.y*128 + wm*64;
    int n0 = blockIdx.x*128 + wn*64;

    if constexpr (STATS){
        if(tid < 128){ SS[tid] = 0.0f; SS2[tid] = 0.0f; }
        __syncthreads();
    }

    int ab1[4], ab2[4];
    #pragma unroll
    for(int i2=0;i2<4;i2++){
        int mi = m0 + i2*16 + lm;
        ab1[i2] = mi*astr + kgl*8;
        ab2[i2] = mi*a2str + kgl*8;
    }
    int bn[4];
    #pragma unroll
    for(int j2=0;j2<4;j2++) bn[j2] = (n0 + j2*16 + lm)*8 + kgl*bkstr;

    f32x4 acc[4][4];
    #pragma unroll
    for(int i2=0;i2<4;i2++)
        #pragma unroll
        for(int j2=0;j2<4;j2++)
            acc[i2][j2] = (f32x4){0.0f,0.0f,0.0f,0.0f};

    #pragma unroll
    for(int ks=0; ks<KSTEPS; ks++){
        const int k0 = ks*32;
        bf16x8 af[4];
        if constexpr (SPLIT){
            int kk = k0 + kgl*8;
            bool s1v = kk < aksplit;
            #pragma unroll
            for(int i2=0;i2<4;i2++)
                af[i2] = s1v ? *(const bf16x8*)(A1 + ab1[i2] + k0)
                             : *(const bf16x8*)(A2 + ab2[i2] + k0 - aksplit);
        } else {
            #pragma unroll
            for(int i2=0;i2<4;i2++)
                af[i2] = *(const bf16x8*)(A1 + ab1[i2] + k0);
        }
        const u16* Bb = B + (size_t)(ks*4)*bkstr;
        bf16x8 bf[4];
        #pragma unroll
        for(int j2=0;j2<4;j2++)
            bf[j2] = *(const bf16x8*)(Bb + bn[j2]);
        #pragma unroll
        for(int i2=0;i2<4;i2++)
            #pragma unroll
            for(int j2=0;j2<4;j2++)
                acc[i2][j2] = __builtin_amdgcn_mfma_f32_16x16x32_bf16(af[i2], bf[j2], acc[i2][j2], 0,0,0);
    }

    float ts[4] = {0.f,0.f,0.f,0.f}, ts2[4] = {0.f,0.f,0.f,0.f};
    #pragma unroll
    for(int i2=0;i2<4;i2++){
        #pragma unroll
        for(int r=0;r<4;r++){
            int m = m0 + i2*16 + kgl*4 + r;
            if(m >= Mvalid) continue;
            long mb = (long)m*cstr;
            #pragma unroll
            for(int j2=0;j2<4;j2++){
                int n = n0 + j2*16 + lm;
                if(n >= N) continue;
                float v = acc[i2][j2][r];
                if(bias) v += bias[n];
                if(flags & 1) v = gelu_f(v);
                long ca = mb + n;
                if(addb) v += bf2f(addb[ca]);
                u16 hv = f2bf(v);
                C[ca] = hv;
                if constexpr (STATS){
                    float vq = bf2f(hv);
                    ts[j2] += vq; ts2[j2] = fmaf(vq, vq, ts2[j2]);
                }
            }
        }
    }
    if constexpr (STATS){
        #pragma unroll
        for(int j2=0;j2<4;j2++){
            int n = n0 + j2*16 + lm;   // grid.x==1 -> n < 128
            atomicAdd(&SS[n], ts[j2]);
            atomicAdd(&SS2[n], ts2[j2]);
        }
        __syncthreads();
        if(tid < 128){
            atomicAdd(&statout[tid], SS[tid]);
            atomicAdd(&statout[128+tid], SS2[tid]);
        }
    }
}

// ============ launch ============
extern "C" void kernel_launch(void* const* d_in, const int* in_sizes, int n_in,
                              void* d_out, int out_size, void* d_ws, size_t ws_size,
                              hipStream_t stream) {
    const float* x       = (const float*)d_in[0];
    const float* enc_w0  = (const float*)d_in[1];
    const float* enc_b0  = (const float*)d_in[2];
    const float* enc_w1  = (const float*)d_in[3];
    const float* pos     = (const float*)d_in[4];
    const float* n0w     = (const float*)d_in[5];
    const float* n0b     = (const float*)d_in[6];
    const float* w0      = (const float*)d_in[7];
    const float* w1      = (const float*)d_in[8];
    const float* wout    = (const float*)d_in[9];
    const float* isw     = (const float*)d_in[10];
    const float* isb     = (const float*)d_in[11];
    const float* n1w     = (const float*)d_in[12];
    const float* n1b     = (const float*)d_in[13];
    const float* fc1w    = (const float*)d_in[14];
    const float* fc1b    = (const float*)d_in[15];
    const float* fc2w    = (const float*)d_in[16];
    const float* fc2b    = (const float*)d_in[17];
    const float* dec_w0  = (const float*)d_in[18];
    const float* dec_b0  = (const float*)d_in[19];
    const float* dec_w1  = (const float*)d_in[20];
    float* out = (float*)d_out;

    u16* ws = (u16*)d_ws;
    size_t off = 0;
    auto al = [&](size_t n){ u16* p = ws + off; off += (n + 63) & ~(size_t)63; return p; };
    u16* TWF  = al(147456);
    u16* THF  = al(196608);
    u16* THI  = al(147456);
    u16* TWI  = al(147456);
    u16* W0P  = al(524288);
    u16* W1P  = al(1048576);
    u16* WOP  = al(524288);
    u16* ISWP = al(65536);
    u16* FC1P = al(131072);
    u16* FC2P = al(131072);
    u16* EW1P = al(16384);
    u16* DW0P = al(20480);
    u16* POSP = al((size_t)NPAD*128);
    u16* XT2  = al((size_t)NPAD*32);
    u16* CURP = al((size_t)NPAD*128);
    u16* XNP  = al((size_t)NPAD*128);
    u16* YP   = al((size_t)NPAD*128);
    u16* XNC  = al((size_t)24576*384);   // [c*192+h][384]
    u16* A2b  = al((size_t)24576*384);   // [kw*128+c][2h+q]  (also A5: [h*128+c][2kw+q])
    u16* A3b  = al((size_t)36864*256);   // [kw*192+kh][2c+p]
    u16* A4b  = al((size_t)24576*384);   // [c*192+kw][2kh+p]
    u16* BIG  = al((size_t)NPAD*128);    // ENC [pt][128]
    u16* IST  = al(5120);                // 10 stat sets x 256 f32
    float* ISTAT = (float*)IST;
    u16* A5b = A2b;
    u16* ENC = BIG;

    dim3 blk(256);
    k_zero<<<dim3(4608), blk, 0, stream>>>(XNC, (long)24576*384);
    k_zero<<<dim3(3),    blk, 0, stream>>>(IST, 5120);

    // packs
    k_pack_twf<<<dim3((147456+255)/256), blk, 0, stream>>>(TWF);
    k_pack_thf<<<dim3((196608+255)/256), blk, 0, stream>>>(THF);
    k_pack_thi<<<dim3((147456+255)/256), blk, 0, stream>>>(THI);
    k_pack_twi<<<dim3((147456+255)/256), blk, 0, stream>>>(TWI);
    k_pack_cw<<<dim3((131072+255)/256,1,4), blk, 0, stream>>>(w0,   W0P, 128, 256, 2*128*256, 131072);
    k_pack_cw<<<dim3((262144+255)/256,1,4), blk, 0, stream>>>(w1,   W1P, 256, 256, 2*256*256, 262144);
    k_pack_cw<<<dim3((131072+255)/256,1,4), blk, 0, stream>>>(wout, WOP, 256, 128, 2*256*128, 131072);
    k_pack_rw<<<dim3((16384+255)/256,1,4),  blk, 0, stream>>>(isw,  ISWP, 128, 128, 16, 128*128, 16384);
    k_pack_rw<<<dim3((32768+255)/256,1,4),  blk, 0, stream>>>(fc1w, FC1P, 256, 128, 16, 256*128, 32768);
    k_pack_rw<<<dim3((32768+255)/256,1,4),  blk, 0, stream>>>(fc2w, FC2P, 128, 256, 32, 128*256, 32768);
    k_pack_rw<<<dim3((16384+255)/256,1,1),  blk, 0, stream>>>(enc_w1, EW1P, 128, 128, 16, 0, 0);
    k_pack_rw<<<dim3((20480+255)/256,1,1),  blk, 0, stream>>>(dec_w0, DW0P, 128, 130, 20, 0, 0);
    k_post<<<dim3(1019), blk, 0, stream>>>(pos, POSP);
    k_xt2 <<<dim3((NP+255)/256), blk, 0, stream>>>(x, XT2);

    const u16* nu = nullptr;
    const float* nf = nullptr;
    const int BIGV = 1<<28;

    // encoder (+ stats for layer-0 norm0)
    k_enc0<<<dim3((NP*16+255)/256), blk, 0, stream>>>(x, enc_w0, enc_b0, ENC);
    k_gemm<4,false,true><<<dim3(1,510), blk, 0, stream>>>(
        ENC, ENC, BIGV, 128, 128, EW1P, 1024, CURP, 128, nf, POSP,
        ISTAT + 0, NP, 128, 0);

    for(int l=0; l<4; l++){
        float* st0 = ISTAT + (2*l)*256;
        float* st1 = ISTAT + (2*l+1)*256;
        float* st0n = ISTAT + (2*l+2)*256;   // next layer norm0 (l=3 -> dummy set)
        k_apply_t<<<dim3(1019), blk, 0, stream>>>(CURP, XNP, XNC, st0, n0w+l*128, n0b+l*128);
        // S1 rdft: XNC x TWF -> A2 [kw*128+c][2h+q]
        k_gemmw<1><<<dim3(384), dim3(512), 0, stream>>>(XNC, TWF, A2b);
        // S2 H-DFT fwd: A2 x THF -> A3 [kw*192+kh][2c+p]
        k_gemmw<2><<<dim3(384), dim3(512), 0, stream>>>(A2b, THF, A3b);
        // fused spectral channel-MLP: A3 -> A4 [c*192+kw][2kh+p]
        k_smlp<<<dim3(1152), dim3(512), 0, stream>>>(A3b,
            W0P + (size_t)l*131072, W1P + (size_t)l*262144, WOP + (size_t)l*131072, A4b);
        // S6 H-DFT inv: A4 x THI -> A5 [h*128+c][2kw+q]
        k_gemmw<1><<<dim3(384), dim3(512), 0, stream>>>(A4b, THI, A5b);
        // S7 irdft: A5 x TWI -> YP [pt][128]
        k_gemmw<5><<<dim3(362), dim3(512), 0, stream>>>(A5b, TWI, YP);
        // inner skip: CUR = isw*XN + isb + Y  (+ stats for norm1)
        k_gemm<4,false,true><<<dim3(1,510), blk, 0, stream>>>(
            XNP, XNP, BIGV, 128, 128, ISWP + (size_t)l*16384, 1024, CURP, 128,
            isb+l*128, YP, st1, NP, 128, 0);
        // fused (norm1 -> fc1 -> gelu -> fc2 -> +XNP) in-place on CURP (+ next norm0 stats)
        k_pmlp<<<dim3(1019), dim3(512), 0, stream>>>(CURP,
            FC1P + (size_t)l*32768, FC2P + (size_t)l*32768,
            fc1b + l*256, fc2b + l*128,
            st1, n1w + l*128, n1b + l*128, XNP, CURP, st0n);
    }
    // decoder conv0 (concat CUR, x) + gelu -> XNP
    k_gemm<5,true,false><<<dim3(1,510), blk, 0, stream>>>(
        CURP, XT2, 128, 128, 32, DW0P, 1024, XNP, 128, dec_b0, nu,
        (float*)nullptr, NP, 128, 1);
    k_dec1<<<dim3((NP+255)/256), blk, 0, stream>>>(XNP, dec_w1, out);
}

// Round 15
// 1357.418 us; speedup vs baseline: 1.2186x; 1.0773x over previous
//
#include <hip/hip_runtime.h>
#include <math.h>

#define NP 65160        // 181*360
#define NPAD 65280

typedef unsigned short u16;
typedef __attribute__((ext_vector_type(8))) short bf16x8;
typedef __attribute__((ext_vector_type(8))) unsigned short us8;
typedef __attribute__((ext_vector_type(4))) float f32x4;

__device__ __forceinline__ u16 f2bf(float f){
    unsigned u = __builtin_bit_cast(unsigned, f);
    return (u16)((u + 0x7FFFu + ((u>>16)&1u)) >> 16);
}
__device__ __forceinline__ float bf2f(u16 h){
    unsigned u = ((unsigned)h)<<16;
    return __builtin_bit_cast(float, u);
}
// tanh-form gelu, overflow-safe: t = 1 - 2/(e+1) saturates to +/-1 (never NaN)
__device__ __forceinline__ float gelu_f(float x){
    float z = 0.7978845608028654f*(x + 0.044715f*x*x*x);
    float e = __expf(2.0f*z);
    float t = 1.0f - 2.0f/(e + 1.0f);
    return 0.5f*x*(1.0f + t);
}

__global__ void k_zero(u16* __restrict__ p, long n){
    long i = ((long)blockIdx.x*256 + threadIdx.x)*8;
    if(i+8 <= n){ us8 z = {0,0,0,0,0,0,0,0}; *(us8*)(p+i) = z; }
}

// ============ B packs: dst[kg][n][8], k = kg*8+e, zero padded ============
__global__ void k_pack_twf(u16* __restrict__ dst){   // [48][384][8]: k=w, n=2kw+q
    int i = blockIdx.x*256+threadIdx.x; if(i >= 48*384*8) return;
    int e = i&7, n = (i>>3)%384, kg = i/(384*8);
    int k = kg*8+e, kw = n>>1, q = n&1;
    float v = 0.0f;
    if(k < 360 && kw < 181){
        float inv = 1.0f/sqrtf(65160.0f);
        float th = 6.28318530717958647692f*(float)((k*kw)%360)/360.0f;
        v = q ? -sinf(th)*inv : cosf(th)*inv;
    }
    dst[i] = f2bf(v);
}
__global__ void k_pack_thf(u16* __restrict__ dst){   // [64][384][8]: k=2h+q, n=2kh+p
    int i = blockIdx.x*256+threadIdx.x; if(i >= 64*384*8) return;
    int e = i&7, n = (i>>3)%384, kg = i/(384*8);
    int k = kg*8+e;
    float v = 0.0f;
    if(k < 362 && n < 362){
        int h = k>>1, q = k&1, kh = n>>1, p = n&1;
        float th = 6.28318530717958647692f*(float)((h*kh)%181)/181.0f;
        float c = cosf(th), s = sinf(th);
        v = (q==0) ? (p==0? c : -s) : (p==0? s : c);
    }
    dst[i] = f2bf(v);
}
__global__ void k_pack_thi(u16* __restrict__ dst){   // [48][384][8]: k=2kh+p, n=2h+q
    int i = blockIdx.x*256+threadIdx.x; if(i >= 48*384*8) return;
    int e = i&7, n = (i>>3)%384, kg = i/(384*8);
    int k = kg*8+e;
    float v = 0.0f;
    if(k < 362 && n < 362){
        int kh = k>>1, p = k&1, h = n>>1, q = n&1;
        float th = 6.28318530717958647692f*(float)((kh*h)%181)/181.0f;
        float c = cosf(th), s = sinf(th);
        v = (q==0) ? (p==0? c : -s) : (p==0? s : c);
    }
    dst[i] = f2bf(v);
}
__global__ void k_pack_twi(u16* __restrict__ dst){   // [48][384][8]: k=2kw+q, n=w
    int i = blockIdx.x*256+threadIdx.x; if(i >= 48*384*8) return;
    int e = i&7, n = (i>>3)%384, kg = i/(384*8);
    int k = kg*8+e, kw = k>>1, q = k&1;
    float v = 0.0f;
    if(k < 362 && n < 360){
        float inv = 1.0f/sqrtf(65160.0f);
        float eps = (kw==0 || kw==180) ? 1.0f : 2.0f;
        float th = 6.28318530717958647692f*(float)((n*kw)%360)/360.0f;
        v = q ? -eps*sinf(th)*inv : eps*cosf(th)*inv;
    }
    dst[i] = f2bf(v);
}
__global__ void k_pack_cw(const float* __restrict__ src, u16* __restrict__ dst,
                          int CIN, int COUT, int lss, int lsd){
    int z = blockIdx.z;
    int Npad = 2*COUT, KG = (2*CIN)/8;
    int tot = KG*Npad*8;
    int i = blockIdx.x*256+threadIdx.x; if(i >= tot) return;
    int e = i&7, n = (i>>3)%Npad, kg = i/(Npad*8);
    int k = kg*8+e, ci = k>>1, q = k&1, co = n>>1, p = n&1;
    float re = src[(size_t)z*lss + ci*COUT + co];
    float im = src[(size_t)z*lss + CIN*COUT + ci*COUT + co];
    float v = (p==0) ? (q==0? re : -im) : (q==0? im : re);
    dst[(size_t)z*lsd + i] = f2bf(v);
}
__global__ void k_pack_rw(const float* __restrict__ src, u16* __restrict__ dst,
                          int Nn, int Ks, int KG, int lss, int lsd){
    int z = blockIdx.z;
    int tot = KG*Nn*8;
    int i = blockIdx.x*256+threadIdx.x; if(i >= tot) return;
    int e = i&7, n = (i>>3)%Nn, kg = i/(Nn*8);
    int k = kg*8+e;
    float v = (k < Ks) ? src[(size_t)z*lss + n*Ks + k] : 0.0f;
    dst[(size_t)z*lsd + i] = f2bf(v);
}

// ============ pointwise ============
__global__ void k_enc0(const float* __restrict__ x, const float* __restrict__ w,
                       const float* __restrict__ b, u16* __restrict__ out){
    int i = blockIdx.x*256+threadIdx.x;
    if(i >= NP*16) return;
    int p = i>>4, c8 = (i&15)*8;
    float x0 = x[p], x1 = x[NP+p];
    us8 o;
    #pragma unroll
    for(int j=0;j<8;j++){
        int e = c8+j;
        float v = w[e*2]*x0 + w[e*2+1]*x1 + b[e];
        o[j] = f2bf(gelu_f(v));
    }
    *(us8*)(out + (size_t)p*128 + c8) = o;
}
__global__ void k_xt2(const float* __restrict__ x, u16* __restrict__ dst){
    int p = blockIdx.x*256+threadIdx.x; if(p >= NP) return;
    us8 z = {0,0,0,0,0,0,0,0};
    z[0] = f2bf(x[p]); z[1] = f2bf(x[NP+p]);
    *(us8*)(dst + (size_t)p*32) = z;
    us8 z2 = {0,0,0,0,0,0,0,0};
    *(us8*)(dst + (size_t)p*32 + 8)  = z2;
    *(us8*)(dst + (size_t)p*32 + 16) = z2;
    *(us8*)(dst + (size_t)p*32 + 24) = z2;
}
__global__ void k_dec1(const u16* __restrict__ hid, const float* __restrict__ w,
                       float* __restrict__ out){
    int p = blockIdx.x*256+threadIdx.x; if(p >= NP) return;
    float a0=0.0f, a1=0.0f;
    #pragma unroll 4
    for(int k8=0;k8<16;k8++){
        us8 v = *(const us8*)(hid + (size_t)p*128 + k8*8);
        #pragma unroll
        for(int j=0;j<8;j++){
            float f = bf2f(v[j]);
            a0 = fmaf(w[k8*8+j], f, a0);
            a1 = fmaf(w[128+k8*8+j], f, a1);
        }
    }
    out[p] = a0; out[NP+p] = a1;
}

// apply norm -> XNP [pt][128]; also XNC[(c*192+h)*384 + w]
__global__ __launch_bounds__(256) void k_apply_t(
    const u16* __restrict__ X, u16* __restrict__ outp, u16* __restrict__ outc,
    const float* __restrict__ stat, const float* __restrict__ gw, const float* __restrict__ gb)
{
    __shared__ u16 T[128][72];
    __shared__ float SA_[128], SB_[128];
    int t = threadIdx.x;
    if(t < 128){
        float mu = stat[t]*(1.0f/(float)NP);
        float var = stat[128+t]*(1.0f/(float)NP) - mu*mu;
        var = fmaxf(var, 0.0f);
        float rstd = 1.0f/sqrtf(var + 1e-6f);
        float a = rstd*gw[t];
        SA_[t] = a; SB_[t] = gb[t] - mu*a;
    }
    __syncthreads();
    int p0 = blockIdx.x*64;
    int pl = t>>2, cc = (t&3)*32;
    int p = p0 + pl;
    if(p < NP){
        #pragma unroll
        for(int jj=0;jj<4;jj++){
            us8 v = *(const us8*)(X + (size_t)p*128 + cc + jj*8);
            us8 o;
            #pragma unroll
            for(int j=0;j<8;j++){
                int c = cc + jj*8 + j;
                o[j] = f2bf(fmaf(bf2f(v[j]), SA_[c], SB_[c]));
            }
            *(us8*)(outp + (size_t)p*128 + cc + jj*8) = o;
            #pragma unroll
            for(int j=0;j<8;j++) T[cc+jj*8+j][pl] = o[j];
        }
    }
    __syncthreads();
    int c = t>>1, half = t&1;
    int pbase = p0 + half*32;
    #pragma unroll
    for(int jj=0;jj<4;jj++){
        int pp = pbase + jj*8;
        if(pp + 8 <= NP){
            int hh = pp/360, ww = pp - hh*360;
            *(us8*)(outc + ((size_t)c*192 + hh)*384 + ww) = *(const us8*)(&T[c][half*32 + jj*8]);
        }
    }
}
__global__ __launch_bounds__(256) void k_post(const float* __restrict__ src, u16* __restrict__ dst){
    __shared__ u16 T[128][72];
    int t = threadIdx.x;
    int p0 = blockIdx.x*64;
    int c = t>>1, half = t&1;
    int pbase = p0 + half*32;
    #pragma unroll
    for(int jj=0;jj<4;jj++){
        int pp = pbase + jj*8;
        us8 v = {0,0,0,0,0,0,0,0};
        if(pp + 8 <= NP){
            #pragma unroll
            for(int j=0;j<8;j++) v[j] = f2bf(src[(size_t)c*NP + pp + j]);
        }
        *(us8*)(&T[c][half*32 + jj*8]) = v;
    }
    __syncthreads();
    int pl = t>>2, cc = (t&3)*32;
    int p = p0 + pl;
    if(p < NP){
        #pragma unroll
        for(int jj=0;jj<4;jj++){
            us8 o;
            #pragma unroll
            for(int j=0;j<8;j++) o[j] = T[cc+jj*8+j][pl];
            *(us8*)(dst + (size_t)p*128 + cc + jj*8) = o;
        }
    }
}

// ============ fused spectral channel-MLP (S3+S4+S5), 32 rows/block ============
__global__ __launch_bounds__(512, 4) void k_smlp(
    const u16* __restrict__ A3, const u16* __restrict__ W0,
    const u16* __restrict__ W1, const u16* __restrict__ WO,
    u16* __restrict__ A4)
{
    __shared__ u16 Hs0[32*520];
    __shared__ u16 Hs1[32*520];
    int tid = threadIdx.x;
    int l = tid & 63, wn = tid >> 6;     // 8 col-groups
    int lm = l & 15, kg = l >> 4;
    int m0 = blockIdx.x * 32;

    f32x4 acc[2][4];
    #pragma unroll
    for(int f=0;f<2;f++)
        #pragma unroll
        for(int j2=0;j2<4;j2++) acc[f][j2] = (f32x4){0.f,0.f,0.f,0.f};
    {
        const u16* ap = A3 + (size_t)(m0 + lm)*256 + kg*8;
        #pragma unroll
        for(int k0=0;k0<256;k0+=32){
            bf16x8 af[2];
            #pragma unroll
            for(int f=0;f<2;f++) af[f] = *(const bf16x8*)(ap + f*16*256 + k0);
            const u16* Bb = W0 + (size_t)((k0>>3)+kg)*4096 + (wn*64+lm)*8;
            #pragma unroll
            for(int j2=0;j2<4;j2++){
                bf16x8 bf = *(const bf16x8*)(Bb + j2*128);
                #pragma unroll
                for(int f=0;f<2;f++)
                    acc[f][j2] = __builtin_amdgcn_mfma_f32_16x16x32_bf16(af[f], bf, acc[f][j2], 0,0,0);
            }
        }
    }
    #pragma unroll
    for(int f=0;f<2;f++)
        #pragma unroll
        for(int j2=0;j2<4;j2++)
            #pragma unroll
            for(int r=0;r<4;r++){
                int row = f*16 + kg*4 + r;
                int col = wn*64 + j2*16 + lm;
                float v = acc[f][j2][r];
                if(!(col&1)) v = fmaxf(v, 0.0f);
                Hs0[row*520 + col] = f2bf(v);
            }
    __syncthreads();
    #pragma unroll
    for(int f=0;f<2;f++)
        #pragma unroll
        for(int j2=0;j2<4;j2++) acc[f][j2] = (f32x4){0.f,0.f,0.f,0.f};
    #pragma unroll 2
    for(int k0=0;k0<512;k0+=32){
        bf16x8 af[2];
        #pragma unroll
        for(int f=0;f<2;f++) af[f] = *(const bf16x8*)(&Hs0[(f*16+lm)*520 + k0 + kg*8]);
        const u16* Bb = W1 + (size_t)((k0>>3)+kg)*4096 + (wn*64+lm)*8;
        #pragma unroll
        for(int j2=0;j2<4;j2++){
            bf16x8 bf = *(const bf16x8*)(Bb + j2*128);
            #pragma unroll
            for(int f=0;f<2;f++)
                acc[f][j2] = __builtin_amdgcn_mfma_f32_16x16x32_bf16(af[f], bf, acc[f][j2], 0,0,0);
        }
    }
    #pragma unroll
    for(int f=0;f<2;f++)
        #pragma unroll
        for(int j2=0;j2<4;j2++)
            #pragma unroll
            for(int r=0;r<4;r++){
                int row = f*16 + kg*4 + r;
                int col = wn*64 + j2*16 + lm;
                float v = acc[f][j2][r];
                if(!(col&1)) v = fmaxf(v, 0.0f);
                Hs1[row*520 + col] = f2bf(v);
            }
    __syncthreads();
    f32x4 acc3[2][2];
    #pragma unroll
    for(int f=0;f<2;f++)
        #pragma unroll
        for(int j2=0;j2<2;j2++) acc3[f][j2] = (f32x4){0.f,0.f,0.f,0.f};
    #pragma unroll 2
    for(int k0=0;k0<512;k0+=32){
        bf16x8 af[2];
        #pragma unroll
        for(int f=0;f<2;f++) af[f] = *(const bf16x8*)(&Hs1[(f*16+lm)*520 + k0 + kg*8]);
        const u16* Bb = WO + (size_t)((k0>>3)+kg)*2048 + (wn*32+lm)*8;
        #pragma unroll
        for(int j2=0;j2<2;j2++){
            bf16x8 bf = *(const bf16x8*)(Bb + j2*128);
            #pragma unroll
            for(int f=0;f<2;f++)
                acc3[f][j2] = __builtin_amdgcn_mfma_f32_16x16x32_bf16(af[f], bf, acc3[f][j2], 0,0,0);
        }
    }
    #pragma unroll
    for(int f=0;f<2;f++)
        #pragma unroll
        for(int j2=0;j2<2;j2++)
            #pragma unroll
            for(int r=0;r<4;r++){
                int row = f*16 + kg*4 + r;
                int col = wn*32 + j2*16 + lm;
                Hs0[row*258 + col] = f2bf(acc3[f][j2][r]);
            }
    __syncthreads();
    int kw = m0 / 192;
    int kh0 = m0 - kw*192;
    int c = tid >> 2, q = tid & 3;
    long base = ((long)(c*192 + kw))*384 + 2*(kh0 + q*8);
    #pragma unroll
    for(int jj=0;jj<2;jj++){
        us8 v;
        #pragma unroll
        for(int i=0;i<4;i++){
            v[2*i]   = Hs0[(q*8 + jj*4 + i)*258 + 2*c];
            v[2*i+1] = Hs0[(q*8 + jj*4 + i)*258 + 2*c+1];
        }
        *(us8*)(A4 + base + jj*8) = v;
    }
}

// ============ fused spatial MLP: norm1+fc1+gelu+fc2+skip + stats, 128 rows ====
__global__ __launch_bounds__(512, 4) void k_pmlp(
    const u16* __restrict__ A, const u16* __restrict__ FC1, const u16* __restrict__ FC2,
    const float* __restrict__ b1, const float* __restrict__ b2,
    const float* __restrict__ stat, const float* __restrict__ gw, const float* __restrict__ gb,
    const u16* __restrict__ addb, u16* __restrict__ OUT, float* __restrict__ statout)
{
    __shared__ u16 Hs[128][264];
    __shared__ float SA_[128], SB_[128];
    __shared__ float SS[128], SS2[128];
    int tid = threadIdx.x;
    int l = tid & 63, wv = tid >> 6;
    int wm = wv >> 1, wn = wv & 1;
    int lm = l & 15, kg = l >> 4;
    int m0 = blockIdx.x * 128;
    if(tid < 128){
        float mu = stat[tid]*(1.0f/(float)NP);
        float var = stat[128+tid]*(1.0f/(float)NP) - mu*mu;
        var = fmaxf(var, 0.0f);
        float rstd = 1.0f/sqrtf(var + 1e-6f);
        float a = rstd*gw[tid];
        SA_[tid] = a; SB_[tid] = gb[tid] - mu*a;
        SS[tid] = 0.0f; SS2[tid] = 0.0f;
    }
    __syncthreads();

    f32x4 acc[2][8];
    #pragma unroll
    for(int f=0;f<2;f++)
        #pragma unroll
        for(int j=0;j<8;j++) acc[f][j] = (f32x4){0.f,0.f,0.f,0.f};
    {
        const u16* ap = A + (size_t)(m0 + wm*32 + lm)*128 + kg*8;
        #pragma unroll
        for(int k0=0;k0<128;k0+=32){
            bf16x8 af[2];
            #pragma unroll
            for(int f=0;f<2;f++){
                us8 raw = *(const us8*)(ap + f*16*128 + k0);
                #pragma unroll
                for(int j=0;j<8;j++){
                    int ch = kg*8 + k0 + j;
                    af[f][j] = (short)f2bf(fmaf(bf2f(raw[j]), SA_[ch], SB_[ch]));
                }
            }
            const u16* Bb = FC1 + (size_t)((k0>>3)+kg)*2048 + (wn*128+lm)*8;
            #pragma unroll
            for(int j2=0;j2<8;j2++){
                bf16x8 bf = *(const bf16x8*)(Bb + j2*128);
                #pragma unroll
                for(int f=0;f<2;f++)
                    acc[f][j2] = __builtin_amdgcn_mfma_f32_16x16x32_bf16(af[f], bf, acc[f][j2], 0,0,0);
            }
        }
    }
    #pragma unroll
    for(int f=0;f<2;f++)
        #pragma unroll
        for(int j2=0;j2<8;j2++)
            #pragma unroll
            for(int r=0;r<4;r++){
                int row = wm*32 + f*16 + kg*4 + r;
                int col = wn*128 + j2*16 + lm;
                Hs[row][col] = f2bf(gelu_f(acc[f][j2][r] + b1[col]));
            }
    __syncthreads();
    f32x4 acc2[2][4];
    #pragma unroll
    for(int f=0;f<2;f++)
        #pragma unroll
        for(int j=0;j<4;j++) acc2[f][j] = (f32x4){0.f,0.f,0.f,0.f};
    #pragma unroll
    for(int k0=0;k0<256;k0+=32){
        bf16x8 af[2];
        #pragma unroll
        for(int f=0;f<2;f++)
            af[f] = *(const bf16x8*)(&Hs[wm*32 + f*16 + lm][k0 + kg*8]);
        const u16* Bb = FC2 + (size_t)((k0>>3)+kg)*1024 + (wn*64+lm)*8;
        #pragma unroll
        for(int j2=0;j2<4;j2++){
            bf16x8 bf = *(const bf16x8*)(Bb + j2*128);
            #pragma unroll
            for(int f=0;f<2;f++)
                acc2[f][j2] = __builtin_amdgcn_mfma_f32_16x16x32_bf16(af[f], bf, acc2[f][j2], 0,0,0);
        }
    }
    float ts[4] = {0.f,0.f,0.f,0.f}, ts2[4] = {0.f,0.f,0.f,0.f};
    #pragma unroll
    for(int f=0;f<2;f++)
        #pragma unroll
        for(int j2=0;j2<4;j2++)
            #pragma unroll
            for(int r=0;r<4;r++){
                int row = wm*32 + f*16 + kg*4 + r;
                long p = m0 + row;
                if(p < NP){
                    int n = wn*64 + j2*16 + lm;
                    float v = acc2[f][j2][r] + b2[n] + bf2f(addb[p*128 + n]);
                    u16 hv = f2bf(v);
                    OUT[p*128 + n] = hv;
                    float vq = bf2f(hv);
                    ts[j2] += vq; ts2[j2] = fmaf(vq, vq, ts2[j2]);
                }
            }
    #pragma unroll
    for(int j2=0;j2<4;j2++){
        int n = wn*64 + j2*16 + lm;
        atomicAdd(&SS[n], ts[j2]);
        atomicAdd(&SS2[n], ts2[j2]);
    }
    __syncthreads();
    if(tid < 128){
        atomicAdd(&statout[tid], SS[tid]);
        atomicAdd(&statout[128+tid], SS2[tid]);
    }
}

// ============ WIDE spectral GEMM: 64 rows/block, full N=384, A read once ====
template<int TMODE>
__global__ __launch_bounds__(512, 4) void k_gemmw(
    const u16* __restrict__ A, const u16* __restrict__ B, u16* __restrict__ C)
{
    __shared__ u16 Ts[64*392];
    int tid = threadIdx.x;
    int l = tid & 63, wv = tid >> 6;
    int lm = l & 15, kg = l >> 4;
    int m0 = blockIdx.x * 64;

    const u16* ap = A + (size_t)(m0 + lm)*384 + kg*8;
    int bn[3];
    #pragma unroll
    for(int j2=0;j2<3;j2++) bn[j2] = (wv*48 + j2*16 + lm)*8 + kg*3072;

    f32x4 acc[4][3];
    #pragma unroll
    for(int f=0;f<4;f++)
        #pragma unroll
        for(int j2=0;j2<3;j2++) acc[f][j2] = (f32x4){0.f,0.f,0.f,0.f};

    #pragma unroll
    for(int ks=0; ks<12; ks++){
        const int k0 = ks*32;
        bf16x8 af[4];
        #pragma unroll
        for(int f=0;f<4;f++) af[f] = *(const bf16x8*)(ap + f*16*384 + k0);
        const u16* Bb = B + (size_t)(ks*4)*3072;
        bf16x8 bf[3];
        #pragma unroll
        for(int j2=0;j2<3;j2++) bf[j2] = *(const bf16x8*)(Bb + bn[j2]);
        #pragma unroll
        for(int f=0;f<4;f++)
            #pragma unroll
            for(int j2=0;j2<3;j2++)
                acc[f][j2] = __builtin_amdgcn_mfma_f32_16x16x32_bf16(af[f], bf[j2], acc[f][j2], 0,0,0);
    }

    #pragma unroll
    for(int f=0;f<4;f++)
        #pragma unroll
        for(int j2=0;j2<3;j2++)
            #pragma unroll
            for(int r=0;r<4;r++)
                Ts[(f*16 + kg*4 + r)*392 + wv*48 + j2*16 + lm] = f2bf(acc[f][j2][r]);
    __syncthreads();

    if constexpr (TMODE != 5){
        #pragma unroll
        for(int it=0; it<6; it++){
            int g = tid + it*512;
            int gn = g % 192, gm = g / 192;
            int ml = gm*4, nl = gn*2;
            int mg = m0 + ml, ng = nl;
            long base;
            if constexpr (TMODE == 1){
                int c = (int)(((unsigned)mg*43691u)>>23);
                int sub = mg - c*192;
                base = ((long)((ng>>1)*128 + c))*384 + 2*sub;
            } else {
                int kw = mg>>7, c = mg&127;
                base = ((long)(kw*192 + (ng>>1)))*256 + 2*c;
            }
            us8 v;
            #pragma unroll
            for(int i=0;i<4;i++){
                v[2*i]   = Ts[(ml+i)*392 + nl];
                v[2*i+1] = Ts[(ml+i)*392 + nl+1];
            }
            *(us8*)(C + base) = v;
        }
    } else {
        #pragma unroll
        for(int it=0; it<6; it++){
            int g = tid + it*512;
            int nl = g % 384, gm = g / 384;
            int ml = gm*8;
            int mg = m0 + ml;
            if(nl < 360){
                int h = mg >> 7;
                long base = ((long)(h*360 + nl))*128 + (mg & 127);
                us8 v;
                #pragma unroll
                for(int j=0;j<8;j++) v[j] = Ts[(ml+j)*392 + nl];
                *(us8*)(C + base) = v;
            }
        }
    }
}

// ============ row-major MFMA GEMM (encoder/skip/decoder), optional fused stats ====
template<int KSTEPS, bool SPLIT, bool STATS>
__global__ __launch_bounds__(256, 2) void k_gemm(
    const u16* __restrict__ A1, const u16* __restrict__ A2, int aksplit, int astr, int a2str,
    const u16* __restrict__ B, int bkstr,
    u16* __restrict__ C, int cstr,
    const float* __restrict__ bias, const u16* __restrict__ addb,
    float* __restrict__ statout,
    int Mvalid, int N, int flags)
{
    __shared__ float SS[128], SS2[128];
    int tid = threadIdx.x;
    int l = tid & 63, wv = tid >> 6;
    int wm = wv >> 1, wn = wv & 1;
    int lm = l & 15, kgl = l >> 4;
    int m0 = blockIdx.y*128 + wm*64;
    int n0 = blockIdx.x*128 + wn*64;

    if constexpr (STATS){
        if(tid < 128){ SS[tid] = 0.0f; SS2[tid] = 0.0f; }
        __syncthreads();
    }

    int ab1[4], ab2[4];
    #pragma unroll
    for(int i2=0;i2<4;i2++){
        int mi = m0 + i2*16 + lm;
        ab1[i2] = mi*astr + kgl*8;
        ab2[i2] = mi*a2str + kgl*8;
    }
    int bn[4];
    #pragma unroll
    for(int j2=0;j2<4;j2++) bn[j2] = (n0 + j2*16 + lm)*8 + kgl*bkstr;

    f32x4 acc[4][4];
    #pragma unroll
    for(int i2=0;i2<4;i2++)
        #pragma unroll
        for(int j2=0;j2<4;j2++)
            acc[i2][j2] = (f32x4){0.0f,0.0f,0.0f,0.0f};

    #pragma unroll
    for(int ks=0; ks<KSTEPS; ks++){
        const int k0 = ks*32;
        bf16x8 af[4];
        if constexpr (SPLIT){
            int kk = k0 + kgl*8;
            bool s1v = kk < aksplit;
            #pragma unroll
            for(int i2=0;i2<4;i2++)
                af[i2] = s1v ? *(const bf16x8*)(A1 + ab1[i2] + k0)
                             : *(const bf16x8*)(A2 + ab2[i2] + k0 - aksplit);
        } else {
            #pragma unroll
            for(int i2=0;i2<4;i2++)
                af[i2] = *(const bf16x8*)(A1 + ab1[i2] + k0);
        }
        const u16* Bb = B + (size_t)(ks*4)*bkstr;
        bf16x8 bf[4];
        #pragma unroll
        for(int j2=0;j2<4;j2++)
            bf[j2] = *(const bf16x8*)(Bb + bn[j2]);
        #pragma unroll
        for(int i2=0;i2<4;i2++)
            #pragma unroll
            for(int j2=0;j2<4;j2++)
                acc[i2][j2] = __builtin_amdgcn_mfma_f32_16x16x32_bf16(af[i2], bf[j2], acc[i2][j2], 0,0,0);
    }

    float ts[4] = {0.f,0.f,0.f,0.f}, ts2[4] = {0.f,0.f,0.f,0.f};
    #pragma unroll
    for(int i2=0;i2<4;i2++){
        #pragma unroll
        for(int r=0;r<4;r++){
            int m = m0 + i2*16 + kgl*4 + r;
            if(m >= Mvalid) continue;
            long mb = (long)m*cstr;
            #pragma unroll
            for(int j2=0;j2<4;j2++){
                int n = n0 + j2*16 + lm;
                if(n >= N) continue;
                float v = acc[i2][j2][r];
                if(bias) v += bias[n];
                if(flags & 1) v = gelu_f(v);
                long ca = mb + n;
                if(addb) v += bf2f(addb[ca]);
                u16 hv = f2bf(v);
                C[ca] = hv;
                if constexpr (STATS){
                    float vq = bf2f(hv);
                    ts[j2] += vq; ts2[j2] = fmaf(vq, vq, ts2[j2]);
                }
            }
        }
    }
    if constexpr (STATS){
        #pragma unroll
        for(int j2=0;j2<4;j2++){
            int n = n0 + j2*16 + lm;
            atomicAdd(&SS[n], ts[j2]);
            atomicAdd(&SS2[n], ts2[j2]);
        }
        __syncthreads();
        if(tid < 128){
            atomicAdd(&statout[tid], SS[tid]);
            atomicAdd(&statout[128+tid], SS2[tid]);
        }
    }
}

// ============ launch ============
extern "C" void kernel_launch(void* const* d_in, const int* in_sizes, int n_in,
                              void* d_out, int out_size, void* d_ws, size_t ws_size,
                              hipStream_t stream) {
    const float* x       = (const float*)d_in[0];
    const float* enc_w0  = (const float*)d_in[1];
    const float* enc_b0  = (const float*)d_in[2];
    const float* enc_w1  = (const float*)d_in[3];
    const float* pos     = (const float*)d_in[4];
    const float* n0w     = (const float*)d_in[5];
    const float* n0b     = (const float*)d_in[6];
    const float* w0      = (const float*)d_in[7];
    const float* w1      = (const float*)d_in[8];
    const float* wout    = (const float*)d_in[9];
    const float* isw     = (const float*)d_in[10];
    const float* isb     = (const float*)d_in[11];
    const float* n1w     = (const float*)d_in[12];
    const float* n1b     = (const float*)d_in[13];
    const float* fc1w    = (const float*)d_in[14];
    const float* fc1b    = (const float*)d_in[15];
    const float* fc2w    = (const float*)d_in[16];
    const float* fc2b    = (const float*)d_in[17];
    const float* dec_w0  = (const float*)d_in[18];
    const float* dec_b0  = (const float*)d_in[19];
    const float* dec_w1  = (const float*)d_in[20];
    float* out = (float*)d_out;

    u16* ws = (u16*)d_ws;
    size_t off = 0;
    auto al = [&](size_t n){ u16* p = ws + off; off += (n + 63) & ~(size_t)63; return p; };
    u16* TWF  = al(147456);
    u16* THF  = al(196608);
    u16* THI  = al(147456);
    u16* TWI  = al(147456);
    u16* W0P  = al(524288);
    u16* W1P  = al(1048576);
    u16* WOP  = al(524288);
    u16* ISWP = al(65536);
    u16* FC1P = al(131072);
    u16* FC2P = al(131072);
    u16* EW1P = al(16384);
    u16* DW0P = al(20480);
    u16* POSP = al((size_t)NPAD*128);
    u16* XT2  = al((size_t)NPAD*32);
    u16* CURP = al((size_t)NPAD*128);
    u16* XNP  = al((size_t)NPAD*128);
    u16* YP   = al((size_t)NPAD*128);
    u16* XNC  = al((size_t)24576*384);
    u16* A2b  = al((size_t)24576*384);
    u16* A3b  = al((size_t)36864*256);
    u16* A4b  = al((size_t)24576*384);
    u16* BIG  = al((size_t)NPAD*128);
    u16* IST  = al(5120);
    float* ISTAT = (float*)IST;
    u16* A5b = A2b;
    u16* ENC = BIG;

    dim3 blk(256);
    k_zero<<<dim3(4608), blk, 0, stream>>>(XNC, (long)24576*384);
    k_zero<<<dim3(3),    blk, 0, stream>>>(IST, 5120);

    // packs
    k_pack_twf<<<dim3((147456+255)/256), blk, 0, stream>>>(TWF);
    k_pack_thf<<<dim3((196608+255)/256), blk, 0, stream>>>(THF);
    k_pack_thi<<<dim3((147456+255)/256), blk, 0, stream>>>(THI);
    k_pack_twi<<<dim3((147456+255)/256), blk, 0, stream>>>(TWI);
    k_pack_cw<<<dim3((131072+255)/256,1,4), blk, 0, stream>>>(w0,   W0P, 128, 256, 2*128*256, 131072);
    k_pack_cw<<<dim3((262144+255)/256,1,4), blk, 0, stream>>>(w1,   W1P, 256, 256, 2*256*256, 262144);
    k_pack_cw<<<dim3((131072+255)/256,1,4), blk, 0, stream>>>(wout, WOP, 256, 128, 2*256*128, 131072);
    k_pack_rw<<<dim3((16384+255)/256,1,4),  blk, 0, stream>>>(isw,  ISWP, 128, 128, 16, 128*128, 16384);
    k_pack_rw<<<dim3((32768+255)/256,1,4),  blk, 0, stream>>>(fc1w, FC1P, 256, 128, 16, 256*128, 32768);
    k_pack_rw<<<dim3((32768+255)/256,1,4),  blk, 0, stream>>>(fc2w, FC2P, 128, 256, 32, 128*256, 32768);
    k_pack_rw<<<dim3((16384+255)/256,1,1),  blk, 0, stream>>>(enc_w1, EW1P, 128, 128, 16, 0, 0);
    k_pack_rw<<<dim3((20480+255)/256,1,1),  blk, 0, stream>>>(dec_w0, DW0P, 128, 130, 20, 0, 0);
    k_post<<<dim3(1019), blk, 0, stream>>>(pos, POSP);
    k_xt2 <<<dim3((NP+255)/256), blk, 0, stream>>>(x, XT2);

    const u16* nu = nullptr;
    const float* nf = nullptr;
    const int BIGV = 1<<28;

    // encoder (+ stats for layer-0 norm0)
    k_enc0<<<dim3((NP*16+255)/256), blk, 0, stream>>>(x, enc_w0, enc_b0, ENC);
    k_gemm<4,false,true><<<dim3(1,510), blk, 0, stream>>>(
        ENC, ENC, BIGV, 128, 128, EW1P, 1024, CURP, 128, nf, POSP,
        ISTAT + 0, NP, 128, 0);

    for(int l=0; l<4; l++){
        float* st0 = ISTAT + (2*l)*256;
        float* st1 = ISTAT + (2*l+1)*256;
        float* st0n = ISTAT + (2*l+2)*256;
        k_apply_t<<<dim3(1019), blk, 0, stream>>>(CURP, XNP, XNC, st0, n0w+l*128, n0b+l*128);
        k_gemmw<1><<<dim3(384), dim3(512), 0, stream>>>(XNC, TWF, A2b);
        k_gemmw<2><<<dim3(384), dim3(512), 0, stream>>>(A2b, THF, A3b);
        k_smlp<<<dim3(1152), dim3(512), 0, stream>>>(A3b,
            W0P + (size_t)l*131072, W1P + (size_t)l*262144, WOP + (size_t)l*131072, A4b);
        k_gemmw<1><<<dim3(384), dim3(512), 0, stream>>>(A4b, THI, A5b);
        k_gemmw<5><<<dim3(362), dim3(512), 0, stream>>>(A5b, TWI, YP);
        k_gemm<4,false,true><<<dim3(1,510), blk, 0, stream>>>(
            XNP, XNP, BIGV, 128, 128, ISWP + (size_t)l*16384, 1024, CURP, 128,
            isb+l*128, YP, st1, NP, 128, 0);
        k_pmlp<<<dim3(510), dim3(512), 0, stream>>>(CURP,
            FC1P + (size_t)l*32768, FC2P + (size_t)l*32768,
            fc1b + l*256, fc2b + l*128,
            st1, n1w + l*128, n1b + l*128, XNP, CURP, st0n);
    }
    k_gemm<5,true,false><<<dim3(1,510), blk, 0, stream>>>(
        CURP, XT2, 128, 128, 32, DW0P, 1024, XNP, 128, dec_b0, nu,
        (float*)nullptr, NP, 128, 1);
    k_dec1<<<dim3((NP+255)/256), blk, 0, stream>>>(XNP, dec_w1, out);
}

// Round 16
// 1317.938 us; speedup vs baseline: 1.2551x; 1.0300x over previous
//
#include <hip/hip_runtime.h>
#include <math.h>

#define NP 65160        // 181*360
#define NPAD 65280

typedef unsigned short u16;
typedef __attribute__((ext_vector_type(8))) short bf16x8;
typedef __attribute__((ext_vector_type(8))) unsigned short us8;
typedef __attribute__((ext_vector_type(4))) float f32x4;

__device__ __forceinline__ u16 f2bf(float f){
    unsigned u = __builtin_bit_cast(unsigned, f);
    return (u16)((u + 0x7FFFu + ((u>>16)&1u)) >> 16);
}
__device__ __forceinline__ float bf2f(u16 h){
    unsigned u = ((unsigned)h)<<16;
    return __builtin_bit_cast(float, u);
}
// tanh-form gelu, overflow-safe: t = 1 - 2/(e+1) saturates (never NaN)
__device__ __forceinline__ float gelu_f(float x){
    float z = 0.7978845608028654f*(x + 0.044715f*x*x*x);
    float e = __expf(2.0f*z);
    float t = 1.0f - 2.0f/(e + 1.0f);
    return 0.5f*x*(1.0f + t);
}

__global__ void k_zero(u16* __restrict__ p, long n){
    long i = ((long)blockIdx.x*256 + threadIdx.x)*8;
    if(i+8 <= n){ us8 z = {0,0,0,0,0,0,0,0}; *(us8*)(p+i) = z; }
}

// ============ B packs: dst[kg][n][8], k = kg*8+e, zero padded ============
__global__ void k_pack_twf(u16* __restrict__ dst){   // [48][384][8]: k=w, n=2kw+q
    int i = blockIdx.x*256+threadIdx.x; if(i >= 48*384*8) return;
    int e = i&7, n = (i>>3)%384, kg = i/(384*8);
    int k = kg*8+e, kw = n>>1, q = n&1;
    float v = 0.0f;
    if(k < 360 && kw < 181){
        float inv = 1.0f/sqrtf(65160.0f);
        float th = 6.28318530717958647692f*(float)((k*kw)%360)/360.0f;
        v = q ? -sinf(th)*inv : cosf(th)*inv;
    }
    dst[i] = f2bf(v);
}
__global__ void k_pack_thf(u16* __restrict__ dst){   // [64][384][8]: k=2h+q, n=2kh+p
    int i = blockIdx.x*256+threadIdx.x; if(i >= 64*384*8) return;
    int e = i&7, n = (i>>3)%384, kg = i/(384*8);
    int k = kg*8+e;
    float v = 0.0f;
    if(k < 362 && n < 362){
        int h = k>>1, q = k&1, kh = n>>1, p = n&1;
        float th = 6.28318530717958647692f*(float)((h*kh)%181)/181.0f;
        float c = cosf(th), s = sinf(th);
        v = (q==0) ? (p==0? c : -s) : (p==0? s : c);
    }
    dst[i] = f2bf(v);
}
__global__ void k_pack_thi(u16* __restrict__ dst){   // [48][384][8]: k=2kh+p, n=2h+q
    int i = blockIdx.x*256+threadIdx.x; if(i >= 48*384*8) return;
    int e = i&7, n = (i>>3)%384, kg = i/(384*8);
    int k = kg*8+e;
    float v = 0.0f;
    if(k < 362 && n < 362){
        int kh = k>>1, p = k&1, h = n>>1, q = n&1;
        float th = 6.28318530717958647692f*(float)((kh*h)%181)/181.0f;
        float c = cosf(th), s = sinf(th);
        v = (q==0) ? (p==0? c : -s) : (p==0? s : c);
    }
    dst[i] = f2bf(v);
}
__global__ void k_pack_twi(u16* __restrict__ dst){   // [48][384][8]: k=2kw+q, n=w
    int i = blockIdx.x*256+threadIdx.x; if(i >= 48*384*8) return;
    int e = i&7, n = (i>>3)%384, kg = i/(384*8);
    int k = kg*8+e, kw = k>>1, q = k&1;
    float v = 0.0f;
    if(k < 362 && n < 360){
        float inv = 1.0f/sqrtf(65160.0f);
        float eps = (kw==0 || kw==180) ? 1.0f : 2.0f;
        float th = 6.28318530717958647692f*(float)((n*kw)%360)/360.0f;
        v = q ? -eps*sinf(th)*inv : eps*cosf(th)*inv;
    }
    dst[i] = f2bf(v);
}
__global__ void k_pack_cw(const float* __restrict__ src, u16* __restrict__ dst,
                          int CIN, int COUT, int lss, int lsd){
    int z = blockIdx.z;
    int Npad = 2*COUT, KG = (2*CIN)/8;
    int tot = KG*Npad*8;
    int i = blockIdx.x*256+threadIdx.x; if(i >= tot) return;
    int e = i&7, n = (i>>3)%Npad, kg = i/(Npad*8);
    int k = kg*8+e, ci = k>>1, q = k&1, co = n>>1, p = n&1;
    float re = src[(size_t)z*lss + ci*COUT + co];
    float im = src[(size_t)z*lss + CIN*COUT + ci*COUT + co];
    float v = (p==0) ? (q==0? re : -im) : (q==0? im : re);
    dst[(size_t)z*lsd + i] = f2bf(v);
}
__global__ void k_pack_rw(const float* __restrict__ src, u16* __restrict__ dst,
                          int Nn, int Ks, int KG, int lss, int lsd){
    int z = blockIdx.z;
    int tot = KG*Nn*8;
    int i = blockIdx.x*256+threadIdx.x; if(i >= tot) return;
    int e = i&7, n = (i>>3)%Nn, kg = i/(Nn*8);
    int k = kg*8+e;
    float v = (k < Ks) ? src[(size_t)z*lss + n*Ks + k] : 0.0f;
    dst[(size_t)z*lsd + i] = f2bf(v);
}

// ============ pointwise ============
__global__ void k_enc0(const float* __restrict__ x, const float* __restrict__ w,
                       const float* __restrict__ b, u16* __restrict__ out){
    int i = blockIdx.x*256+threadIdx.x;
    if(i >= NP*16) return;
    int p = i>>4, c8 = (i&15)*8;
    float x0 = x[p], x1 = x[NP+p];
    us8 o;
    #pragma unroll
    for(int j=0;j<8;j++){
        int e = c8+j;
        float v = w[e*2]*x0 + w[e*2+1]*x1 + b[e];
        o[j] = f2bf(gelu_f(v));
    }
    *(us8*)(out + (size_t)p*128 + c8) = o;
}
__global__ void k_xt2(const float* __restrict__ x, u16* __restrict__ dst){
    int p = blockIdx.x*256+threadIdx.x; if(p >= NP) return;
    us8 z = {0,0,0,0,0,0,0,0};
    z[0] = f2bf(x[p]); z[1] = f2bf(x[NP+p]);
    *(us8*)(dst + (size_t)p*32) = z;
    us8 z2 = {0,0,0,0,0,0,0,0};
    *(us8*)(dst + (size_t)p*32 + 8)  = z2;
    *(us8*)(dst + (size_t)p*32 + 16) = z2;
    *(us8*)(dst + (size_t)p*32 + 24) = z2;
}
__global__ void k_dec1(const u16* __restrict__ hid, const float* __restrict__ w,
                       float* __restrict__ out){
    int p = blockIdx.x*256+threadIdx.x; if(p >= NP) return;
    float a0=0.0f, a1=0.0f;
    #pragma unroll 4
    for(int k8=0;k8<16;k8++){
        us8 v = *(const us8*)(hid + (size_t)p*128 + k8*8);
        #pragma unroll
        for(int j=0;j<8;j++){
            float f = bf2f(v[j]);
            a0 = fmaf(w[k8*8+j], f, a0);
            a1 = fmaf(w[128+k8*8+j], f, a1);
        }
    }
    out[p] = a0; out[NP+p] = a1;
}

// apply norm -> XNP [pt][128]; also XNC[(c*192+h)*384 + w]
__global__ __launch_bounds__(256) void k_apply_t(
    const u16* __restrict__ X, u16* __restrict__ outp, u16* __restrict__ outc,
    const float* __restrict__ stat, const float* __restrict__ gw, const float* __restrict__ gb)
{
    __shared__ u16 T[128][72];
    __shared__ float SA_[128], SB_[128];
    int t = threadIdx.x;
    if(t < 128){
        float mu = stat[t]*(1.0f/(float)NP);
        float var = stat[128+t]*(1.0f/(float)NP) - mu*mu;
        var = fmaxf(var, 0.0f);
        float rstd = 1.0f/sqrtf(var + 1e-6f);
        float a = rstd*gw[t];
        SA_[t] = a; SB_[t] = gb[t] - mu*a;
    }
    __syncthreads();
    int p0 = blockIdx.x*64;
    int pl = t>>2, cc = (t&3)*32;
    int p = p0 + pl;
    if(p < NP){
        #pragma unroll
        for(int jj=0;jj<4;jj++){
            us8 v = *(const us8*)(X + (size_t)p*128 + cc + jj*8);
            us8 o;
            #pragma unroll
            for(int j=0;j<8;j++){
                int c = cc + jj*8 + j;
                o[j] = f2bf(fmaf(bf2f(v[j]), SA_[c], SB_[c]));
            }
            *(us8*)(outp + (size_t)p*128 + cc + jj*8) = o;
            #pragma unroll
            for(int j=0;j<8;j++) T[cc+jj*8+j][pl] = o[j];
        }
    }
    __syncthreads();
    int c = t>>1, half = t&1;
    int pbase = p0 + half*32;
    #pragma unroll
    for(int jj=0;jj<4;jj++){
        int pp = pbase + jj*8;
        if(pp + 8 <= NP){
            int hh = pp/360, ww = pp - hh*360;
            *(us8*)(outc + ((size_t)c*192 + hh)*384 + ww) = *(const us8*)(&T[c][half*32 + jj*8]);
        }
    }
}
__global__ __launch_bounds__(256) void k_post(const float* __restrict__ src, u16* __restrict__ dst){
    __shared__ u16 T[128][72];
    int t = threadIdx.x;
    int p0 = blockIdx.x*64;
    int c = t>>1, half = t&1;
    int pbase = p0 + half*32;
    #pragma unroll
    for(int jj=0;jj<4;jj++){
        int pp = pbase + jj*8;
        us8 v = {0,0,0,0,0,0,0,0};
        if(pp + 8 <= NP){
            #pragma unroll
            for(int j=0;j<8;j++) v[j] = f2bf(src[(size_t)c*NP + pp + j]);
        }
        *(us8*)(&T[c][half*32 + jj*8]) = v;
    }
    __syncthreads();
    int pl = t>>2, cc = (t&3)*32;
    int p = p0 + pl;
    if(p < NP){
        #pragma unroll
        for(int jj=0;jj<4;jj++){
            us8 o;
            #pragma unroll
            for(int j=0;j<8;j++) o[j] = T[cc+jj*8+j][pl];
            *(us8*)(dst + (size_t)p*128 + cc + jj*8) = o;
        }
    }
}

// ============ fused spectral channel-MLP (S3+S4+S5), 48 rows, single buffer ====
// LDS 49.9 KB -> 3 blocks/CU (24 waves). grid 768 = one full fill (no tail).
__global__ __launch_bounds__(512, 6) void k_smlp(
    const u16* __restrict__ A3, const u16* __restrict__ W0,
    const u16* __restrict__ W1, const u16* __restrict__ WO,
    u16* __restrict__ A4)
{
    __shared__ u16 Hs[48*520];
    int tid = threadIdx.x;
    int l = tid & 63, wn = tid >> 6;     // 8 col-groups
    int lm = l & 15, kg = l >> 4;
    int m0 = blockIdx.x * 48;

    f32x4 acc[3][4];
    // ---- stage 1: H1[48][512] = A3 x W0 (K=256), CReLU even col ----
    #pragma unroll
    for(int f=0;f<3;f++)
        #pragma unroll
        for(int j2=0;j2<4;j2++) acc[f][j2] = (f32x4){0.f,0.f,0.f,0.f};
    {
        const u16* ap = A3 + (size_t)(m0 + lm)*256 + kg*8;
        #pragma unroll
        for(int k0=0;k0<256;k0+=32){
            bf16x8 af[3];
            #pragma unroll
            for(int f=0;f<3;f++) af[f] = *(const bf16x8*)(ap + f*16*256 + k0);
            const u16* Bb = W0 + (size_t)((k0>>3)+kg)*4096 + (wn*64+lm)*8;
            #pragma unroll
            for(int j2=0;j2<4;j2++){
                bf16x8 bf = *(const bf16x8*)(Bb + j2*128);
                #pragma unroll
                for(int f=0;f<3;f++)
                    acc[f][j2] = __builtin_amdgcn_mfma_f32_16x16x32_bf16(af[f], bf, acc[f][j2], 0,0,0);
            }
        }
    }
    #pragma unroll
    for(int f=0;f<3;f++)
        #pragma unroll
        for(int j2=0;j2<4;j2++)
            #pragma unroll
            for(int r=0;r<4;r++){
                int row = f*16 + kg*4 + r;
                int col = wn*64 + j2*16 + lm;
                float v = acc[f][j2][r];
                if(!(col&1)) v = fmaxf(v, 0.0f);
                Hs[row*520 + col] = f2bf(v);
            }
    __syncthreads();
    // ---- stage 2: H2 = H1 x W1 (K=512), reads complete before in-place write ----
    #pragma unroll
    for(int f=0;f<3;f++)
        #pragma unroll
        for(int j2=0;j2<4;j2++) acc[f][j2] = (f32x4){0.f,0.f,0.f,0.f};
    #pragma unroll 2
    for(int k0=0;k0<512;k0+=32){
        bf16x8 af[3];
        #pragma unroll
        for(int f=0;f<3;f++) af[f] = *(const bf16x8*)(&Hs[(f*16+lm)*520 + k0 + kg*8]);
        const u16* Bb = W1 + (size_t)((k0>>3)+kg)*4096 + (wn*64+lm)*8;
        #pragma unroll
        for(int j2=0;j2<4;j2++){
            bf16x8 bf = *(const bf16x8*)(Bb + j2*128);
            #pragma unroll
            for(int f=0;f<3;f++)
                acc[f][j2] = __builtin_amdgcn_mfma_f32_16x16x32_bf16(af[f], bf, acc[f][j2], 0,0,0);
        }
    }
    __syncthreads();   // all H1 reads done
    #pragma unroll
    for(int f=0;f<3;f++)
        #pragma unroll
        for(int j2=0;j2<4;j2++)
            #pragma unroll
            for(int r=0;r<4;r++){
                int row = f*16 + kg*4 + r;
                int col = wn*64 + j2*16 + lm;
                float v = acc[f][j2][r];
                if(!(col&1)) v = fmaxf(v, 0.0f);
                Hs[row*520 + col] = f2bf(v);
            }
    __syncthreads();
    // ---- stage 3: O[48][256] = H2 x WO (K=512) ----
    f32x4 acc3[3][2];
    #pragma unroll
    for(int f=0;f<3;f++)
        #pragma unroll
        for(int j2=0;j2<2;j2++) acc3[f][j2] = (f32x4){0.f,0.f,0.f,0.f};
    #pragma unroll 2
    for(int k0=0;k0<512;k0+=32){
        bf16x8 af[3];
        #pragma unroll
        for(int f=0;f<3;f++) af[f] = *(const bf16x8*)(&Hs[(f*16+lm)*520 + k0 + kg*8]);
        const u16* Bb = WO + (size_t)((k0>>3)+kg)*2048 + (wn*32+lm)*8;
        #pragma unroll
        for(int j2=0;j2<2;j2++){
            bf16x8 bf = *(const bf16x8*)(Bb + j2*128);
            #pragma unroll
            for(int f=0;f<3;f++)
                acc3[f][j2] = __builtin_amdgcn_mfma_f32_16x16x32_bf16(af[f], bf, acc3[f][j2], 0,0,0);
        }
    }
    __syncthreads();   // all H2 reads done
    // O staged at stride 258 (overlay inside Hs)
    #pragma unroll
    for(int f=0;f<3;f++)
        #pragma unroll
        for(int j2=0;j2<2;j2++)
            #pragma unroll
            for(int r=0;r<4;r++){
                int row = f*16 + kg*4 + r;
                int col = wn*32 + j2*16 + lm;
                Hs[row*258 + col] = f2bf(acc3[f][j2][r]);
            }
    __syncthreads();
    // ---- coalesced store: A4[(c*192+kw)*384 + 2kh+p] ----
    int kw = m0 / 192;                 // 192%48==0 -> never straddles kw
    int kh0 = m0 - kw*192;
    int c = tid >> 2, q = tid & 3;     // q covers 12 rows each
    long base = ((long)(c*192 + kw))*384 + 2*(kh0 + q*12);
    #pragma unroll
    for(int jj=0;jj<3;jj++){
        us8 v;
        #pragma unroll
        for(int i=0;i<4;i++){
            v[2*i]   = Hs[(q*12 + jj*4 + i)*258 + 2*c];
            v[2*i+1] = Hs[(q*12 + jj*4 + i)*258 + 2*c+1];
        }
        *(us8*)(A4 + base + jj*8) = v;
    }
}

// ============ fused spatial MLP: norm1+fc1+gelu+fc2+skip + stats, 128 rows ====
__global__ __launch_bounds__(512, 4) void k_pmlp(
    const u16* __restrict__ A, const u16* __restrict__ FC1, const u16* __restrict__ FC2,
    const float* __restrict__ b1, const float* __restrict__ b2,
    const float* __restrict__ stat, const float* __restrict__ gw, const float* __restrict__ gb,
    const u16* __restrict__ addb, u16* __restrict__ OUT, float* __restrict__ statout)
{
    __shared__ u16 Hs[128][264];
    __shared__ float SA_[128], SB_[128];
    __shared__ float SS[128], SS2[128];
    int tid = threadIdx.x;
    int l = tid & 63, wv = tid >> 6;
    int wm = wv >> 1, wn = wv & 1;
    int lm = l & 15, kg = l >> 4;
    int m0 = blockIdx.x * 128;
    if(tid < 128){
        float mu = stat[tid]*(1.0f/(float)NP);
        float var = stat[128+tid]*(1.0f/(float)NP) - mu*mu;
        var = fmaxf(var, 0.0f);
        float rstd = 1.0f/sqrtf(var + 1e-6f);
        float a = rstd*gw[tid];
        SA_[tid] = a; SB_[tid] = gb[tid] - mu*a;
        SS[tid] = 0.0f; SS2[tid] = 0.0f;
    }
    __syncthreads();

    f32x4 acc[2][8];
    #pragma unroll
    for(int f=0;f<2;f++)
        #pragma unroll
        for(int j=0;j<8;j++) acc[f][j] = (f32x4){0.f,0.f,0.f,0.f};
    {
        const u16* ap = A + (size_t)(m0 + wm*32 + lm)*128 + kg*8;
        #pragma unroll
        for(int k0=0;k0<128;k0+=32){
            bf16x8 af[2];
            #pragma unroll
            for(int f=0;f<2;f++){
                us8 raw = *(const us8*)(ap + f*16*128 + k0);
                #pragma unroll
                for(int j=0;j<8;j++){
                    int ch = kg*8 + k0 + j;
                    af[f][j] = (short)f2bf(fmaf(bf2f(raw[j]), SA_[ch], SB_[ch]));
                }
            }
            const u16* Bb = FC1 + (size_t)((k0>>3)+kg)*2048 + (wn*128+lm)*8;
            #pragma unroll
            for(int j2=0;j2<8;j2++){
                bf16x8 bf = *(const bf16x8*)(Bb + j2*128);
                #pragma unroll
                for(int f=0;f<2;f++)
                    acc[f][j2] = __builtin_amdgcn_mfma_f32_16x16x32_bf16(af[f], bf, acc[f][j2], 0,0,0);
            }
        }
    }
    #pragma unroll
    for(int f=0;f<2;f++)
        #pragma unroll
        for(int j2=0;j2<8;j2++)
            #pragma unroll
            for(int r=0;r<4;r++){
                int row = wm*32 + f*16 + kg*4 + r;
                int col = wn*128 + j2*16 + lm;
                Hs[row][col] = f2bf(gelu_f(acc[f][j2][r] + b1[col]));
            }
    __syncthreads();
    f32x4 acc2[2][4];
    #pragma unroll
    for(int f=0;f<2;f++)
        #pragma unroll
        for(int j=0;j<4;j++) acc2[f][j] = (f32x4){0.f,0.f,0.f,0.f};
    #pragma unroll
    for(int k0=0;k0<256;k0+=32){
        bf16x8 af[2];
        #pragma unroll
        for(int f=0;f<2;f++)
            af[f] = *(const bf16x8*)(&Hs[wm*32 + f*16 + lm][k0 + kg*8]);
        const u16* Bb = FC2 + (size_t)((k0>>3)+kg)*1024 + (wn*64+lm)*8;
        #pragma unroll
        for(int j2=0;j2<4;j2++){
            bf16x8 bf = *(const bf16x8*)(Bb + j2*128);
            #pragma unroll
            for(int f=0;f<2;f++)
                acc2[f][j2] = __builtin_amdgcn_mfma_f32_16x16x32_bf16(af[f], bf, acc2[f][j2], 0,0,0);
        }
    }
    float ts[4] = {0.f,0.f,0.f,0.f}, ts2[4] = {0.f,0.f,0.f,0.f};
    #pragma unroll
    for(int f=0;f<2;f++)
        #pragma unroll
        for(int j2=0;j2<4;j2++)
            #pragma unroll
            for(int r=0;r<4;r++){
                int row = wm*32 + f*16 + kg*4 + r;
                long p = m0 + row;
                if(p < NP){
                    int n = wn*64 + j2*16 + lm;
                    float v = acc2[f][j2][r] + b2[n] + bf2f(addb[p*128 + n]);
                    u16 hv = f2bf(v);
                    OUT[p*128 + n] = hv;
                    float vq = bf2f(hv);
                    ts[j2] += vq; ts2[j2] = fmaf(vq, vq, ts2[j2]);
                }
            }
    #pragma unroll
    for(int j2=0;j2<4;j2++){
        int n = wn*64 + j2*16 + lm;
        atomicAdd(&SS[n], ts[j2]);
        atomicAdd(&SS2[n], ts2[j2]);
    }
    __syncthreads();
    if(tid < 128){
        atomicAdd(&statout[tid], SS[tid]);
        atomicAdd(&statout[128+tid], SS2[tid]);
    }
}

// ============ WIDE spectral GEMM: 48 rows/block, full N=384, 3 blocks/CU ====
template<int TMODE>
__global__ __launch_bounds__(512, 6) void k_gemmw(
    const u16* __restrict__ A, const u16* __restrict__ B, u16* __restrict__ C)
{
    __shared__ u16 Ts[48*392];
    int tid = threadIdx.x;
    int l = tid & 63, wv = tid >> 6;
    int lm = l & 15, kg = l >> 4;
    int m0 = blockIdx.x * 48;

    const u16* ap = A + (size_t)(m0 + lm)*384 + kg*8;
    int bn[3];
    #pragma unroll
    for(int j2=0;j2<3;j2++) bn[j2] = (wv*48 + j2*16 + lm)*8 + kg*3072;

    f32x4 acc[3][3];
    #pragma unroll
    for(int f=0;f<3;f++)
        #pragma unroll
        for(int j2=0;j2<3;j2++) acc[f][j2] = (f32x4){0.f,0.f,0.f,0.f};

    #pragma unroll
    for(int ks=0; ks<12; ks++){
        const int k0 = ks*32;
        bf16x8 af[3];
        #pragma unroll
        for(int f=0;f<3;f++) af[f] = *(const bf16x8*)(ap + f*16*384 + k0);
        const u16* Bb = B + (size_t)(ks*4)*3072;
        bf16x8 bf[3];
        #pragma unroll
        for(int j2=0;j2<3;j2++) bf[j2] = *(const bf16x8*)(Bb + bn[j2]);
        #pragma unroll
        for(int f=0;f<3;f++)
            #pragma unroll
            for(int j2=0;j2<3;j2++)
                acc[f][j2] = __builtin_amdgcn_mfma_f32_16x16x32_bf16(af[f], bf[j2], acc[f][j2], 0,0,0);
    }

    #pragma unroll
    for(int f=0;f<3;f++)
        #pragma unroll
        for(int j2=0;j2<3;j2++)
            #pragma unroll
            for(int r=0;r<4;r++)
                Ts[(f*16 + kg*4 + r)*392 + wv*48 + j2*16 + lm] = f2bf(acc[f][j2][r]);
    __syncthreads();

    if constexpr (TMODE != 5){
        #pragma unroll
        for(int it=0; it<5; it++){
            int g = tid + it*512;
            if(g >= 2304) break;
            int gn = g % 192, gm = g / 192;
            int ml = gm*4, nl = gn*2;
            int mg = m0 + ml, ng = nl;
            long base;
            if constexpr (TMODE == 1){
                int c = (int)(((unsigned)mg*43691u)>>23);
                int sub = mg - c*192;
                base = ((long)((ng>>1)*128 + c))*384 + 2*sub;
            } else {
                int kw = mg>>7, c = mg&127;
                base = ((long)(kw*192 + (ng>>1)))*256 + 2*c;
            }
            us8 v;
            #pragma unroll
            for(int i=0;i<4;i++){
                v[2*i]   = Ts[(ml+i)*392 + nl];
                v[2*i+1] = Ts[(ml+i)*392 + nl+1];
            }
            *(us8*)(C + base) = v;
        }
    } else {
        #pragma unroll
        for(int it=0; it<5; it++){
            int g = tid + it*512;
            if(g >= 2304) break;
            int nl = g % 384, gm = g / 384;
            int ml = gm*8;
            int mg = m0 + ml;
            if(nl < 360 && mg < 23168){
                int h = mg >> 7;
                long base = ((long)(h*360 + nl))*128 + (mg & 127);
                us8 v;
                #pragma unroll
                for(int j=0;j<8;j++) v[j] = Ts[(ml+j)*392 + nl];
                *(us8*)(C + base) = v;
            }
        }
    }
}

// ============ row-major MFMA GEMM (encoder/skip/decoder), optional fused stats ====
template<int KSTEPS, bool SPLIT, bool STATS>
__global__ __launch_bounds__(256, 2) void k_gemm(
    const u16* __restrict__ A1, const u16* __restrict__ A2, int aksplit, int astr, int a2str,
    const u16* __restrict__ B, int bkstr,
    u16* __restrict__ C, int cstr,
    const float* __restrict__ bias, const u16* __restrict__ addb,
    float* __restrict__ statout,
    int Mvalid, int N, int flags)
{
    __shared__ float SS[128], SS2[128];
    int tid = threadIdx.x;
    int l = tid & 63, wv = tid >> 6;
    int wm = wv >> 1, wn = wv & 1;
    int lm = l & 15, kgl = l >> 4;
    int m0 = blockIdx.y*128 + wm*64;
    int n0 = blockIdx.x*128 + wn*64;

    if constexpr (STATS){
        if(tid < 128){ SS[tid] = 0.0f; SS2[tid] = 0.0f; }
        __syncthreads();
    }

    int ab1[4], ab2[4];
    #pragma unroll
    for(int i2=0;i2<4;i2++){
        int mi = m0 + i2*16 + lm;
        ab1[i2] = mi*astr + kgl*8;
        ab2[i2] = mi*a2str + kgl*8;
    }
    int bn[4];
    #pragma unroll
    for(int j2=0;j2<4;j2++) bn[j2] = (n0 + j2*16 + lm)*8 + kgl*bkstr;

    f32x4 acc[4][4];
    #pragma unroll
    for(int i2=0;i2<4;i2++)
        #pragma unroll
        for(int j2=0;j2<4;j2++)
            acc[i2][j2] = (f32x4){0.0f,0.0f,0.0f,0.0f};

    #pragma unroll
    for(int ks=0; ks<KSTEPS; ks++){
        const int k0 = ks*32;
        bf16x8 af[4];
        if constexpr (SPLIT){
            int kk = k0 + kgl*8;
            bool s1v = kk < aksplit;
            #pragma unroll
            for(int i2=0;i2<4;i2++)
                af[i2] = s1v ? *(const bf16x8*)(A1 + ab1[i2] + k0)
                             : *(const bf16x8*)(A2 + ab2[i2] + k0 - aksplit);
        } else {
            #pragma unroll
            for(int i2=0;i2<4;i2++)
                af[i2] = *(const bf16x8*)(A1 + ab1[i2] + k0);
        }
        const u16* Bb = B + (size_t)(ks*4)*bkstr;
        bf16x8 bf[4];
        #pragma unroll
        for(int j2=0;j2<4;j2++)
            bf[j2] = *(const bf16x8*)(Bb + bn[j2]);
        #pragma unroll
        for(int i2=0;i2<4;i2++)
            #pragma unroll
            for(int j2=0;j2<4;j2++)
                acc[i2][j2] = __builtin_amdgcn_mfma_f32_16x16x32_bf16(af[i2], bf[j2], acc[i2][j2], 0,0,0);
    }

    float ts[4] = {0.f,0.f,0.f,0.f}, ts2[4] = {0.f,0.f,0.f,0.f};
    #pragma unroll
    for(int i2=0;i2<4;i2++){
        #pragma unroll
        for(int r=0;r<4;r++){
            int m = m0 + i2*16 + kgl*4 + r;
            if(m >= Mvalid) continue;
            long mb = (long)m*cstr;
            #pragma unroll
            for(int j2=0;j2<4;j2++){
                int n = n0 + j2*16 + lm;
                if(n >= N) continue;
                float v = acc[i2][j2][r];
                if(bias) v += bias[n];
                if(flags & 1) v = gelu_f(v);
                long ca = mb + n;
                if(addb) v += bf2f(addb[ca]);
                u16 hv = f2bf(v);
                C[ca] = hv;
                if constexpr (STATS){
                    float vq = bf2f(hv);
                    ts[j2] += vq; ts2[j2] = fmaf(vq, vq, ts2[j2]);
                }
            }
        }
    }
    if constexpr (STATS){
        #pragma unroll
        for(int j2=0;j2<4;j2++){
            int n = n0 + j2*16 + lm;
            atomicAdd(&SS[n], ts[j2]);
            atomicAdd(&SS2[n], ts2[j2]);
        }
        __syncthreads();
        if(tid < 128){
            atomicAdd(&statout[tid], SS[tid]);
            atomicAdd(&statout[128+tid], SS2[tid]);
        }
    }
}

// ============ launch ============
extern "C" void kernel_launch(void* const* d_in, const int* in_sizes, int n_in,
                              void* d_out, int out_size, void* d_ws, size_t ws_size,
                              hipStream_t stream) {
    const float* x       = (const float*)d_in[0];
    const float* enc_w0  = (const float*)d_in[1];
    const float* enc_b0  = (const float*)d_in[2];
    const float* enc_w1  = (const float*)d_in[3];
    const float* pos     = (const float*)d_in[4];
    const float* n0w     = (const float*)d_in[5];
    const float* n0b     = (const float*)d_in[6];
    const float* w0      = (const float*)d_in[7];
    const float* w1      = (const float*)d_in[8];
    const float* wout    = (const float*)d_in[9];
    const float* isw     = (const float*)d_in[10];
    const float* isb     = (const float*)d_in[11];
    const float* n1w     = (const float*)d_in[12];
    const float* n1b     = (const float*)d_in[13];
    const float* fc1w    = (const float*)d_in[14];
    const float* fc1b    = (const float*)d_in[15];
    const float* fc2w    = (const float*)d_in[16];
    const float* fc2b    = (const float*)d_in[17];
    const float* dec_w0  = (const float*)d_in[18];
    const float* dec_b0  = (const float*)d_in[19];
    const float* dec_w1  = (const float*)d_in[20];
    float* out = (float*)d_out;

    u16* ws = (u16*)d_ws;
    size_t off = 0;
    auto al = [&](size_t n){ u16* p = ws + off; off += (n + 63) & ~(size_t)63; return p; };
    u16* TWF  = al(147456);
    u16* THF  = al(196608);
    u16* THI  = al(147456);
    u16* TWI  = al(147456);
    u16* W0P  = al(524288);
    u16* W1P  = al(1048576);
    u16* WOP  = al(524288);
    u16* ISWP = al(65536);
    u16* FC1P = al(131072);
    u16* FC2P = al(131072);
    u16* EW1P = al(16384);
    u16* DW0P = al(20480);
    u16* POSP = al((size_t)NPAD*128);
    u16* XT2  = al((size_t)NPAD*32);
    u16* CURP = al((size_t)NPAD*128);
    u16* XNP  = al((size_t)NPAD*128);
    u16* YP   = al((size_t)NPAD*128);
    u16* XNC  = al((size_t)24576*384);
    u16* A2b  = al((size_t)24576*384);
    u16* A3b  = al((size_t)36864*256);
    u16* A4b  = al((size_t)24576*384);
    u16* BIG  = al((size_t)NPAD*128);
    u16* IST  = al(5120);
    float* ISTAT = (float*)IST;
    u16* A5b = A2b;
    u16* ENC = BIG;

    dim3 blk(256);
    k_zero<<<dim3(4608), blk, 0, stream>>>(XNC, (long)24576*384);
    k_zero<<<dim3(3),    blk, 0, stream>>>(IST, 5120);

    // packs
    k_pack_twf<<<dim3((147456+255)/256), blk, 0, stream>>>(TWF);
    k_pack_thf<<<dim3((196608+255)/256), blk, 0, stream>>>(THF);
    k_pack_thi<<<dim3((147456+255)/256), blk, 0, stream>>>(THI);
    k_pack_twi<<<dim3((147456+255)/256), blk, 0, stream>>>(TWI);
    k_pack_cw<<<dim3((131072+255)/256,1,4), blk, 0, stream>>>(w0,   W0P, 128, 256, 2*128*256, 131072);
    k_pack_cw<<<dim3((262144+255)/256,1,4), blk, 0, stream>>>(w1,   W1P, 256, 256, 2*256*256, 262144);
    k_pack_cw<<<dim3((131072+255)/256,1,4), blk, 0, stream>>>(wout, WOP, 256, 128, 2*256*128, 131072);
    k_pack_rw<<<dim3((16384+255)/256,1,4),  blk, 0, stream>>>(isw,  ISWP, 128, 128, 16, 128*128, 16384);
    k_pack_rw<<<dim3((32768+255)/256,1,4),  blk, 0, stream>>>(fc1w, FC1P, 256, 128, 16, 256*128, 32768);
    k_pack_rw<<<dim3((32768+255)/256,1,4),  blk, 0, stream>>>(fc2w, FC2P, 128, 256, 32, 128*256, 32768);
    k_pack_rw<<<dim3((16384+255)/256,1,1),  blk, 0, stream>>>(enc_w1, EW1P, 128, 128, 16, 0, 0);
    k_pack_rw<<<dim3((20480+255)/256,1,1),  blk, 0, stream>>>(dec_w0, DW0P, 128, 130, 20, 0, 0);
    k_post<<<dim3(1019), blk, 0, stream>>>(pos, POSP);
    k_xt2 <<<dim3((NP+255)/256), blk, 0, stream>>>(x, XT2);

    const u16* nu = nullptr;
    const float* nf = nullptr;
    const int BIGV = 1<<28;

    // encoder (+ stats for layer-0 norm0)
    k_enc0<<<dim3((NP*16+255)/256), blk, 0, stream>>>(x, enc_w0, enc_b0, ENC);
    k_gemm<4,false,true><<<dim3(1,510), blk, 0, stream>>>(
        ENC, ENC, BIGV, 128, 128, EW1P, 1024, CURP, 128, nf, POSP,
        ISTAT + 0, NP, 128, 0);

    for(int l=0; l<4; l++){
        float* st0 = ISTAT + (2*l)*256;
        float* st1 = ISTAT + (2*l+1)*256;
        float* st0n = ISTAT + (2*l+2)*256;
        k_apply_t<<<dim3(1019), blk, 0, stream>>>(CURP, XNP, XNC, st0, n0w+l*128, n0b+l*128);
        k_gemmw<1><<<dim3(512), dim3(512), 0, stream>>>(XNC, TWF, A2b);
        k_gemmw<2><<<dim3(512), dim3(512), 0, stream>>>(A2b, THF, A3b);
        k_smlp<<<dim3(768), dim3(512), 0, stream>>>(A3b,
            W0P + (size_t)l*131072, W1P + (size_t)l*262144, WOP + (size_t)l*131072, A4b);
        k_gemmw<1><<<dim3(512), dim3(512), 0, stream>>>(A4b, THI, A5b);
        k_gemmw<5><<<dim3(483), dim3(512), 0, stream>>>(A5b, TWI, YP);
        k_gemm<4,false,true><<<dim3(1,510), blk, 0, stream>>>(
            XNP, XNP, BIGV, 128, 128, ISWP + (size_t)l*16384, 1024, CURP, 128,
            isb+l*128, YP, st1, NP, 128, 0);
        k_pmlp<<<dim3(510), dim3(512), 0, stream>>>(CURP,
            FC1P + (size_t)l*32768, FC2P + (size_t)l*32768,
            fc1b + l*256, fc2b + l*128,
            st1, n1w + l*128, n1b + l*128, XNP, CURP, st0n);
    }
    k_gemm<5,true,false><<<dim3(1,510), blk, 0, stream>>>(
        CURP, XT2, 128, 128, 32, DW0P, 1024, XNP, 128, dec_b0, nu,
        (float*)nullptr, NP, 128, 1);
    k_dec1<<<dim3((NP+255)/256), blk, 0, stream>>>(XNP, dec_w1, out);
}

// Round 17
// 1279.100 us; speedup vs baseline: 1.2932x; 1.0304x over previous
//
#include <hip/hip_runtime.h>
#include <math.h>

#define NP 65160        // 181*360
#define NPAD 65280

typedef unsigned short u16;
typedef __attribute__((ext_vector_type(8))) short bf16x8;
typedef __attribute__((ext_vector_type(8))) unsigned short us8;
typedef __attribute__((ext_vector_type(4))) float f32x4;

__device__ __forceinline__ u16 f2bf(float f){
    unsigned u = __builtin_bit_cast(unsigned, f);
    return (u16)((u + 0x7FFFu + ((u>>16)&1u)) >> 16);
}
__device__ __forceinline__ float bf2f(u16 h){
    unsigned u = ((unsigned)h)<<16;
    return __builtin_bit_cast(float, u);
}
// tanh-form gelu, overflow-safe: t = 1 - 2/(e+1) saturates (never NaN)
__device__ __forceinline__ float gelu_f(float x){
    float z = 0.7978845608028654f*(x + 0.044715f*x*x*x);
    float e = __expf(2.0f*z);
    float t = 1.0f - 2.0f/(e + 1.0f);
    return 0.5f*x*(1.0f + t);
}

__global__ void k_zero(u16* __restrict__ p, long n){
    long i = ((long)blockIdx.x*256 + threadIdx.x)*8;
    if(i+8 <= n){ us8 z = {0,0,0,0,0,0,0,0}; *(us8*)(p+i) = z; }
}

// ============ B packs: dst[kg][n][8], k = kg*8+e, zero padded ============
__global__ void k_pack_twf(u16* __restrict__ dst){   // [48][384][8]: k=w, n=2kw+q
    int i = blockIdx.x*256+threadIdx.x; if(i >= 48*384*8) return;
    int e = i&7, n = (i>>3)%384, kg = i/(384*8);
    int k = kg*8+e, kw = n>>1, q = n&1;
    float v = 0.0f;
    if(k < 360 && kw < 181){
        float inv = 1.0f/sqrtf(65160.0f);
        float th = 6.28318530717958647692f*(float)((k*kw)%360)/360.0f;
        v = q ? -sinf(th)*inv : cosf(th)*inv;
    }
    dst[i] = f2bf(v);
}
__global__ void k_pack_thf(u16* __restrict__ dst){   // [64][384][8]: k=2h+q, n=2kh+p
    int i = blockIdx.x*256+threadIdx.x; if(i >= 64*384*8) return;
    int e = i&7, n = (i>>3)%384, kg = i/(384*8);
    int k = kg*8+e;
    float v = 0.0f;
    if(k < 362 && n < 362){
        int h = k>>1, q = k&1, kh = n>>1, p = n&1;
        float th = 6.28318530717958647692f*(float)((h*kh)%181)/181.0f;
        float c = cosf(th), s = sinf(th);
        v = (q==0) ? (p==0? c : -s) : (p==0? s : c);
    }
    dst[i] = f2bf(v);
}
__global__ void k_pack_thi(u16* __restrict__ dst){   // [48][384][8]: k=2kh+p, n=2h+q
    int i = blockIdx.x*256+threadIdx.x; if(i >= 48*384*8) return;
    int e = i&7, n = (i>>3)%384, kg = i/(384*8);
    int k = kg*8+e;
    float v = 0.0f;
    if(k < 362 && n < 362){
        int kh = k>>1, p = k&1, h = n>>1, q = n&1;
        float th = 6.28318530717958647692f*(float)((kh*h)%181)/181.0f;
        float c = cosf(th), s = sinf(th);
        v = (q==0) ? (p==0? c : -s) : (p==0? s : c);
    }
    dst[i] = f2bf(v);
}
__global__ void k_pack_twi(u16* __restrict__ dst){   // [48][384][8]: k=2kw+q, n=w
    int i = blockIdx.x*256+threadIdx.x; if(i >= 48*384*8) return;
    int e = i&7, n = (i>>3)%384, kg = i/(384*8);
    int k = kg*8+e, kw = k>>1, q = k&1;
    float v = 0.0f;
    if(k < 362 && n < 360){
        float inv = 1.0f/sqrtf(65160.0f);
        float eps = (kw==0 || kw==180) ? 1.0f : 2.0f;
        float th = 6.28318530717958647692f*(float)((n*kw)%360)/360.0f;
        v = q ? -eps*sinf(th)*inv : eps*cosf(th)*inv;
    }
    dst[i] = f2bf(v);
}
__global__ void k_pack_cw(const float* __restrict__ src, u16* __restrict__ dst,
                          int CIN, int COUT, int lss, int lsd){
    int z = blockIdx.z;
    int Npad = 2*COUT, KG = (2*CIN)/8;
    int tot = KG*Npad*8;
    int i = blockIdx.x*256+threadIdx.x; if(i >= tot) return;
    int e = i&7, n = (i>>3)%Npad, kg = i/(Npad*8);
    int k = kg*8+e, ci = k>>1, q = k&1, co = n>>1, p = n&1;
    float re = src[(size_t)z*lss + ci*COUT + co];
    float im = src[(size_t)z*lss + CIN*COUT + ci*COUT + co];
    float v = (p==0) ? (q==0? re : -im) : (q==0? im : re);
    dst[(size_t)z*lsd + i] = f2bf(v);
}
__global__ void k_pack_rw(const float* __restrict__ src, u16* __restrict__ dst,
                          int Nn, int Ks, int KG, int lss, int lsd){
    int z = blockIdx.z;
    int tot = KG*Nn*8;
    int i = blockIdx.x*256+threadIdx.x; if(i >= tot) return;
    int e = i&7, n = (i>>3)%Nn, kg = i/(Nn*8);
    int k = kg*8+e;
    float v = (k < Ks) ? src[(size_t)z*lss + n*Ks + k] : 0.0f;
    dst[(size_t)z*lsd + i] = f2bf(v);
}

// ============ pointwise ============
__global__ void k_enc0(const float* __restrict__ x, const float* __restrict__ w,
                       const float* __restrict__ b, u16* __restrict__ out){
    int i = blockIdx.x*256+threadIdx.x;
    if(i >= NP*16) return;
    int p = i>>4, c8 = (i&15)*8;
    float x0 = x[p], x1 = x[NP+p];
    us8 o;
    #pragma unroll
    for(int j=0;j<8;j++){
        int e = c8+j;
        float v = w[e*2]*x0 + w[e*2+1]*x1 + b[e];
        o[j] = f2bf(gelu_f(v));
    }
    *(us8*)(out + (size_t)p*128 + c8) = o;
}
__global__ void k_xt2(const float* __restrict__ x, u16* __restrict__ dst){
    int p = blockIdx.x*256+threadIdx.x; if(p >= NP) return;
    us8 z = {0,0,0,0,0,0,0,0};
    z[0] = f2bf(x[p]); z[1] = f2bf(x[NP+p]);
    *(us8*)(dst + (size_t)p*32) = z;
    us8 z2 = {0,0,0,0,0,0,0,0};
    *(us8*)(dst + (size_t)p*32 + 8)  = z2;
    *(us8*)(dst + (size_t)p*32 + 16) = z2;
    *(us8*)(dst + (size_t)p*32 + 24) = z2;
}
__global__ void k_dec1(const u16* __restrict__ hid, const float* __restrict__ w,
                       float* __restrict__ out){
    int p = blockIdx.x*256+threadIdx.x; if(p >= NP) return;
    float a0=0.0f, a1=0.0f;
    #pragma unroll 4
    for(int k8=0;k8<16;k8++){
        us8 v = *(const us8*)(hid + (size_t)p*128 + k8*8);
        #pragma unroll
        for(int j=0;j<8;j++){
            float f = bf2f(v[j]);
            a0 = fmaf(w[k8*8+j], f, a0);
            a1 = fmaf(w[128+k8*8+j], f, a1);
        }
    }
    out[p] = a0; out[NP+p] = a1;
}

// apply norm -> XNP [pt][128]; also XNC[(c*192+h)*384 + w]
__global__ __launch_bounds__(256) void k_apply_t(
    const u16* __restrict__ X, u16* __restrict__ outp, u16* __restrict__ outc,
    const float* __restrict__ stat, const float* __restrict__ gw, const float* __restrict__ gb)
{
    __shared__ u16 T[128][72];
    __shared__ float SA_[128], SB_[128];
    int t = threadIdx.x;
    if(t < 128){
        float mu = stat[t]*(1.0f/(float)NP);
        float var = stat[128+t]*(1.0f/(float)NP) - mu*mu;
        var = fmaxf(var, 0.0f);
        float rstd = 1.0f/sqrtf(var + 1e-6f);
        float a = rstd*gw[t];
        SA_[t] = a; SB_[t] = gb[t] - mu*a;
    }
    __syncthreads();
    int p0 = blockIdx.x*64;
    int pl = t>>2, cc = (t&3)*32;
    int p = p0 + pl;
    if(p < NP){
        #pragma unroll
        for(int jj=0;jj<4;jj++){
            us8 v = *(const us8*)(X + (size_t)p*128 + cc + jj*8);
            us8 o;
            #pragma unroll
            for(int j=0;j<8;j++){
                int c = cc + jj*8 + j;
                o[j] = f2bf(fmaf(bf2f(v[j]), SA_[c], SB_[c]));
            }
            *(us8*)(outp + (size_t)p*128 + cc + jj*8) = o;
            #pragma unroll
            for(int j=0;j<8;j++) T[cc+jj*8+j][pl] = o[j];
        }
    }
    __syncthreads();
    int c = t>>1, half = t&1;
    int pbase = p0 + half*32;
    #pragma unroll
    for(int jj=0;jj<4;jj++){
        int pp = pbase + jj*8;
        if(pp + 8 <= NP){
            int hh = pp/360, ww = pp - hh*360;
            *(us8*)(outc + ((size_t)c*192 + hh)*384 + ww) = *(const us8*)(&T[c][half*32 + jj*8]);
        }
    }
}
__global__ __launch_bounds__(256) void k_post(const float* __restrict__ src, u16* __restrict__ dst){
    __shared__ u16 T[128][72];
    int t = threadIdx.x;
    int p0 = blockIdx.x*64;
    int c = t>>1, half = t&1;
    int pbase = p0 + half*32;
    #pragma unroll
    for(int jj=0;jj<4;jj++){
        int pp = pbase + jj*8;
        us8 v = {0,0,0,0,0,0,0,0};
        if(pp + 8 <= NP){
            #pragma unroll
            for(int j=0;j<8;j++) v[j] = f2bf(src[(size_t)c*NP + pp + j]);
        }
        *(us8*)(&T[c][half*32 + jj*8]) = v;
    }
    __syncthreads();
    int pl = t>>2, cc = (t&3)*32;
    int p = p0 + pl;
    if(p < NP){
        #pragma unroll
        for(int jj=0;jj<4;jj++){
            us8 o;
            #pragma unroll
            for(int j=0;j<8;j++) o[j] = T[cc+jj*8+j][pl];
            *(us8*)(dst + (size_t)p*128 + cc + jj*8) = o;
        }
    }
}

// ============ fused spectral channel-MLP (S3+S4+S5), 32 rows/block ============
// double-buffered, LDS 66.5 KB, (512,4): no spill, 2 blocks/CU.
__global__ __launch_bounds__(512, 4) void k_smlp(
    const u16* __restrict__ A3, const u16* __restrict__ W0,
    const u16* __restrict__ W1, const u16* __restrict__ WO,
    u16* __restrict__ A4)
{
    __shared__ u16 Hs0[32*520];
    __shared__ u16 Hs1[32*520];
    int tid = threadIdx.x;
    int l = tid & 63, wn = tid >> 6;     // 8 col-groups
    int lm = l & 15, kg = l >> 4;
    int m0 = blockIdx.x * 32;

    f32x4 acc[2][4];
    #pragma unroll
    for(int f=0;f<2;f++)
        #pragma unroll
        for(int j2=0;j2<4;j2++) acc[f][j2] = (f32x4){0.f,0.f,0.f,0.f};
    {
        const u16* ap = A3 + (size_t)(m0 + lm)*256 + kg*8;
        #pragma unroll
        for(int k0=0;k0<256;k0+=32){
            bf16x8 af[2];
            #pragma unroll
            for(int f=0;f<2;f++) af[f] = *(const bf16x8*)(ap + f*16*256 + k0);
            const u16* Bb = W0 + (size_t)((k0>>3)+kg)*4096 + (wn*64+lm)*8;
            #pragma unroll
            for(int j2=0;j2<4;j2++){
                bf16x8 bf = *(const bf16x8*)(Bb + j2*128);
                #pragma unroll
                for(int f=0;f<2;f++)
                    acc[f][j2] = __builtin_amdgcn_mfma_f32_16x16x32_bf16(af[f], bf, acc[f][j2], 0,0,0);
            }
        }
    }
    #pragma unroll
    for(int f=0;f<2;f++)
        #pragma unroll
        for(int j2=0;j2<4;j2++)
            #pragma unroll
            for(int r=0;r<4;r++){
                int row = f*16 + kg*4 + r;
                int col = wn*64 + j2*16 + lm;
                float v = acc[f][j2][r];
                if(!(col&1)) v = fmaxf(v, 0.0f);
                Hs0[row*520 + col] = f2bf(v);
            }
    __syncthreads();
    #pragma unroll
    for(int f=0;f<2;f++)
        #pragma unroll
        for(int j2=0;j2<4;j2++) acc[f][j2] = (f32x4){0.f,0.f,0.f,0.f};
    #pragma unroll 2
    for(int k0=0;k0<512;k0+=32){
        bf16x8 af[2];
        #pragma unroll
        for(int f=0;f<2;f++) af[f] = *(const bf16x8*)(&Hs0[(f*16+lm)*520 + k0 + kg*8]);
        const u16* Bb = W1 + (size_t)((k0>>3)+kg)*4096 + (wn*64+lm)*8;
        #pragma unroll
        for(int j2=0;j2<4;j2++){
            bf16x8 bf = *(const bf16x8*)(Bb + j2*128);
            #pragma unroll
            for(int f=0;f<2;f++)
                acc[f][j2] = __builtin_amdgcn_mfma_f32_16x16x32_bf16(af[f], bf, acc[f][j2], 0,0,0);
        }
    }
    #pragma unroll
    for(int f=0;f<2;f++)
        #pragma unroll
        for(int j2=0;j2<4;j2++)
            #pragma unroll
            for(int r=0;r<4;r++){
                int row = f*16 + kg*4 + r;
                int col = wn*64 + j2*16 + lm;
                float v = acc[f][j2][r];
                if(!(col&1)) v = fmaxf(v, 0.0f);
                Hs1[row*520 + col] = f2bf(v);
            }
    __syncthreads();
    f32x4 acc3[2][2];
    #pragma unroll
    for(int f=0;f<2;f++)
        #pragma unroll
        for(int j2=0;j2<2;j2++) acc3[f][j2] = (f32x4){0.f,0.f,0.f,0.f};
    #pragma unroll 2
    for(int k0=0;k0<512;k0+=32){
        bf16x8 af[2];
        #pragma unroll
        for(int f=0;f<2;f++) af[f] = *(const bf16x8*)(&Hs1[(f*16+lm)*520 + k0 + kg*8]);
        const u16* Bb = WO + (size_t)((k0>>3)+kg)*2048 + (wn*32+lm)*8;
        #pragma unroll
        for(int j2=0;j2<2;j2++){
            bf16x8 bf = *(const bf16x8*)(Bb + j2*128);
            #pragma unroll
            for(int f=0;f<2;f++)
                acc3[f][j2] = __builtin_amdgcn_mfma_f32_16x16x32_bf16(af[f], bf, acc3[f][j2], 0,0,0);
        }
    }
    #pragma unroll
    for(int f=0;f<2;f++)
        #pragma unroll
        for(int j2=0;j2<2;j2++)
            #pragma unroll
            for(int r=0;r<4;r++){
                int row = f*16 + kg*4 + r;
                int col = wn*32 + j2*16 + lm;
                Hs0[row*258 + col] = f2bf(acc3[f][j2][r]);
            }
    __syncthreads();
    int kw = m0 / 192;
    int kh0 = m0 - kw*192;
    int c = tid >> 2, q = tid & 3;
    long base = ((long)(c*192 + kw))*384 + 2*(kh0 + q*8);
    #pragma unroll
    for(int jj=0;jj<2;jj++){
        us8 v;
        #pragma unroll
        for(int i=0;i<4;i++){
            v[2*i]   = Hs0[(q*8 + jj*4 + i)*258 + 2*c];
            v[2*i+1] = Hs0[(q*8 + jj*4 + i)*258 + 2*c+1];
        }
        *(us8*)(A4 + base + jj*8) = v;
    }
}

// ============ fused spatial MLP: norm1+fc1+gelu+fc2+skip + stats, 128 rows ====
__global__ __launch_bounds__(512, 4) void k_pmlp(
    const u16* __restrict__ A, const u16* __restrict__ FC1, const u16* __restrict__ FC2,
    const float* __restrict__ b1, const float* __restrict__ b2,
    const float* __restrict__ stat, const float* __restrict__ gw, const float* __restrict__ gb,
    const u16* __restrict__ addb, u16* __restrict__ OUT, float* __restrict__ statout)
{
    __shared__ u16 Hs[128][264];
    __shared__ float SA_[128], SB_[128];
    __shared__ float SS[128], SS2[128];
    int tid = threadIdx.x;
    int l = tid & 63, wv = tid >> 6;
    int wm = wv >> 1, wn = wv & 1;
    int lm = l & 15, kg = l >> 4;
    int m0 = blockIdx.x * 128;
    if(tid < 128){
        float mu = stat[tid]*(1.0f/(float)NP);
        float var = stat[128+tid]*(1.0f/(float)NP) - mu*mu;
        var = fmaxf(var, 0.0f);
        float rstd = 1.0f/sqrtf(var + 1e-6f);
        float a = rstd*gw[tid];
        SA_[tid] = a; SB_[tid] = gb[tid] - mu*a;
        SS[tid] = 0.0f; SS2[tid] = 0.0f;
    }
    __syncthreads();

    f32x4 acc[2][8];
    #pragma unroll
    for(int f=0;f<2;f++)
        #pragma unroll
        for(int j=0;j<8;j++) acc[f][j] = (f32x4){0.f,0.f,0.f,0.f};
    {
        const u16* ap = A + (size_t)(m0 + wm*32 + lm)*128 + kg*8;
        #pragma unroll
        for(int k0=0;k0<128;k0+=32){
            bf16x8 af[2];
            #pragma unroll
            for(int f=0;f<2;f++){
                us8 raw = *(const us8*)(ap + f*16*128 + k0);
                #pragma unroll
                for(int j=0;j<8;j++){
                    int ch = kg*8 + k0 + j;
                    af[f][j] = (short)f2bf(fmaf(bf2f(raw[j]), SA_[ch], SB_[ch]));
                }
            }
            const u16* Bb = FC1 + (size_t)((k0>>3)+kg)*2048 + (wn*128+lm)*8;
            #pragma unroll
            for(int j2=0;j2<8;j2++){
                bf16x8 bf = *(const bf16x8*)(Bb + j2*128);
                #pragma unroll
                for(int f=0;f<2;f++)
                    acc[f][j2] = __builtin_amdgcn_mfma_f32_16x16x32_bf16(af[f], bf, acc[f][j2], 0,0,0);
            }
        }
    }
    #pragma unroll
    for(int f=0;f<2;f++)
        #pragma unroll
        for(int j2=0;j2<8;j2++)
            #pragma unroll
            for(int r=0;r<4;r++){
                int row = wm*32 + f*16 + kg*4 + r;
                int col = wn*128 + j2*16 + lm;
                Hs[row][col] = f2bf(gelu_f(acc[f][j2][r] + b1[col]));
            }
    __syncthreads();
    f32x4 acc2[2][4];
    #pragma unroll
    for(int f=0;f<2;f++)
        #pragma unroll
        for(int j=0;j<4;j++) acc2[f][j] = (f32x4){0.f,0.f,0.f,0.f};
    #pragma unroll
    for(int k0=0;k0<256;k0+=32){
        bf16x8 af[2];
        #pragma unroll
        for(int f=0;f<2;f++)
            af[f] = *(const bf16x8*)(&Hs[wm*32 + f*16 + lm][k0 + kg*8]);
        const u16* Bb = FC2 + (size_t)((k0>>3)+kg)*1024 + (wn*64+lm)*8;
        #pragma unroll
        for(int j2=0;j2<4;j2++){
            bf16x8 bf = *(const bf16x8*)(Bb + j2*128);
            #pragma unroll
            for(int f=0;f<2;f++)
                acc2[f][j2] = __builtin_amdgcn_mfma_f32_16x16x32_bf16(af[f], bf, acc2[f][j2], 0,0,0);
        }
    }
    float ts[4] = {0.f,0.f,0.f,0.f}, ts2[4] = {0.f,0.f,0.f,0.f};
    #pragma unroll
    for(int f=0;f<2;f++)
        #pragma unroll
        for(int j2=0;j2<4;j2++)
            #pragma unroll
            for(int r=0;r<4;r++){
                int row = wm*32 + f*16 + kg*4 + r;
                long p = m0 + row;
                if(p < NP){
                    int n = wn*64 + j2*16 + lm;
                    float v = acc2[f][j2][r] + b2[n] + bf2f(addb[p*128 + n]);
                    u16 hv = f2bf(v);
                    OUT[p*128 + n] = hv;
                    float vq = bf2f(hv);
                    ts[j2] += vq; ts2[j2] = fmaf(vq, vq, ts2[j2]);
                }
            }
    #pragma unroll
    for(int j2=0;j2<4;j2++){
        int n = wn*64 + j2*16 + lm;
        atomicAdd(&SS[n], ts[j2]);
        atomicAdd(&SS2[n], ts2[j2]);
    }
    __syncthreads();
    if(tid < 128){
        atomicAdd(&statout[tid], SS[tid]);
        atomicAdd(&statout[128+tid], SS2[tid]);
    }
}

// ============ WIDE spectral GEMM: 48 rows/block, full N=384, 3 blocks/CU ====
template<int TMODE>
__global__ __launch_bounds__(512, 6) void k_gemmw(
    const u16* __restrict__ A, const u16* __restrict__ B, u16* __restrict__ C)
{
    __shared__ u16 Ts[48*392];
    int tid = threadIdx.x;
    int l = tid & 63, wv = tid >> 6;
    int lm = l & 15, kg = l >> 4;
    int m0 = blockIdx.x * 48;

    const u16* ap = A + (size_t)(m0 + lm)*384 + kg*8;
    int bn[3];
    #pragma unroll
    for(int j2=0;j2<3;j2++) bn[j2] = (wv*48 + j2*16 + lm)*8 + kg*3072;

    f32x4 acc[3][3];
    #pragma unroll
    for(int f=0;f<3;f++)
        #pragma unroll
        for(int j2=0;j2<3;j2++) acc[f][j2] = (f32x4){0.f,0.f,0.f,0.f};

    #pragma unroll
    for(int ks=0; ks<12; ks++){
        const int k0 = ks*32;
        bf16x8 af[3];
        #pragma unroll
        for(int f=0;f<3;f++) af[f] = *(const bf16x8*)(ap + f*16*384 + k0);
        const u16* Bb = B + (size_t)(ks*4)*3072;
        bf16x8 bf[3];
        #pragma unroll
        for(int j2=0;j2<3;j2++) bf[j2] = *(const bf16x8*)(Bb + bn[j2]);
        #pragma unroll
        for(int f=0;f<3;f++)
            #pragma unroll
            for(int j2=0;j2<3;j2++)
                acc[f][j2] = __builtin_amdgcn_mfma_f32_16x16x32_bf16(af[f], bf[j2], acc[f][j2], 0,0,0);
    }

    #pragma unroll
    for(int f=0;f<3;f++)
        #pragma unroll
        for(int j2=0;j2<3;j2++)
            #pragma unroll
            for(int r=0;r<4;r++)
                Ts[(f*16 + kg*4 + r)*392 + wv*48 + j2*16 + lm] = f2bf(acc[f][j2][r]);
    __syncthreads();

    if constexpr (TMODE != 5){
        #pragma unroll
        for(int it=0; it<5; it++){
            int g = tid + it*512;
            if(g >= 2304) break;
            int gn = g % 192, gm = g / 192;
            int ml = gm*4, nl = gn*2;
            int mg = m0 + ml, ng = nl;
            long base;
            if constexpr (TMODE == 1){
                int c = (int)(((unsigned)mg*43691u)>>23);
                int sub = mg - c*192;
                base = ((long)((ng>>1)*128 + c))*384 + 2*sub;
            } else {
                int kw = mg>>7, c = mg&127;
                base = ((long)(kw*192 + (ng>>1)))*256 + 2*c;
            }
            us8 v;
            #pragma unroll
            for(int i=0;i<4;i++){
                v[2*i]   = Ts[(ml+i)*392 + nl];
                v[2*i+1] = Ts[(ml+i)*392 + nl+1];
            }
            *(us8*)(C + base) = v;
        }
    } else {
        #pragma unroll
        for(int it=0; it<5; it++){
            int g = tid + it*512;
            if(g >= 2304) break;
            int nl = g % 384, gm = g / 384;
            int ml = gm*8;
            int mg = m0 + ml;
            if(nl < 360 && mg < 23168){
                int h = mg >> 7;
                long base = ((long)(h*360 + nl))*128 + (mg & 127);
                us8 v;
                #pragma unroll
                for(int j=0;j<8;j++) v[j] = Ts[(ml+j)*392 + nl];
                *(us8*)(C + base) = v;
            }
        }
    }
}

// ============ row-major MFMA GEMM (encoder/skip/decoder), optional fused stats ====
template<int KSTEPS, bool SPLIT, bool STATS>
__global__ __launch_bounds__(256, 2) void k_gemm(
    const u16* __restrict__ A1, const u16* __restrict__ A2, int aksplit, int astr, int a2str,
    const u16* __restrict__ B, int bkstr,
    u16* __restrict__ C, int cstr,
    const float* __restrict__ bias, const u16* __restrict__ addb,
    float* __restrict__ statout,
    int Mvalid, int N, int flags)
{
    __shared__ float SS[128], SS2[128];
    int tid = threadIdx.x;
    int l = tid & 63, wv = tid >> 6;
    int wm = wv >> 1, wn = wv & 1;
    int lm = l & 15, kgl = l >> 4;
    int m0 = blockIdx.y*128 + wm*64;
    int n0 = blockIdx.x*128 + wn*64;

    if constexpr (STATS){
        if(tid < 128){ SS[tid] = 0.0f; SS2[tid] = 0.0f; }
        __syncthreads();
    }

    int ab1[4], ab2[4];
    #pragma unroll
    for(int i2=0;i2<4;i2++){
        int mi = m0 + i2*16 + lm;
        ab1[i2] = mi*astr + kgl*8;
        ab2[i2] = mi*a2str + kgl*8;
    }
    int bn[4];
    #pragma unroll
    for(int j2=0;j2<4;j2++) bn[j2] = (n0 + j2*16 + lm)*8 + kgl*bkstr;

    f32x4 acc[4][4];
    #pragma unroll
    for(int i2=0;i2<4;i2++)
        #pragma unroll
        for(int j2=0;j2<4;j2++)
            acc[i2][j2] = (f32x4){0.0f,0.0f,0.0f,0.0f};

    #pragma unroll
    for(int ks=0; ks<KSTEPS; ks++){
        const int k0 = ks*32;
        bf16x8 af[4];
        if constexpr (SPLIT){
            int kk = k0 + kgl*8;
            bool s1v = kk < aksplit;
            #pragma unroll
            for(int i2=0;i2<4;i2++)
                af[i2] = s1v ? *(const bf16x8*)(A1 + ab1[i2] + k0)
                             : *(const bf16x8*)(A2 + ab2[i2] + k0 - aksplit);
        } else {
            #pragma unroll
            for(int i2=0;i2<4;i2++)
                af[i2] = *(const bf16x8*)(A1 + ab1[i2] + k0);
        }
        const u16* Bb = B + (size_t)(ks*4)*bkstr;
        bf16x8 bf[4];
        #pragma unroll
        for(int j2=0;j2<4;j2++)
            bf[j2] = *(const bf16x8*)(Bb + bn[j2]);
        #pragma unroll
        for(int i2=0;i2<4;i2++)
            #pragma unroll
            for(int j2=0;j2<4;j2++)
                acc[i2][j2] = __builtin_amdgcn_mfma_f32_16x16x32_bf16(af[i2], bf[j2], acc[i2][j2], 0,0,0);
    }

    float ts[4] = {0.f,0.f,0.f,0.f}, ts2[4] = {0.f,0.f,0.f,0.f};
    #pragma unroll
    for(int i2=0;i2<4;i2++){
        #pragma unroll
        for(int r=0;r<4;r++){
            int m = m0 + i2*16 + kgl*4 + r;
            if(m >= Mvalid) continue;
            long mb = (long)m*cstr;
            #pragma unroll
            for(int j2=0;j2<4;j2++){
                int n = n0 + j2*16 + lm;
                if(n >= N) continue;
                float v = acc[i2][j2][r];
                if(bias) v += bias[n];
                if(flags & 1) v = gelu_f(v);
                long ca = mb + n;
                if(addb) v += bf2f(addb[ca]);
                u16 hv = f2bf(v);
                C[ca] = hv;
                if constexpr (STATS){
                    float vq = bf2f(hv);
                    ts[j2] += vq; ts2[j2] = fmaf(vq, vq, ts2[j2]);
                }
            }
        }
    }
    if constexpr (STATS){
        #pragma unroll
        for(int j2=0;j2<4;j2++){
            int n = n0 + j2*16 + lm;
            atomicAdd(&SS[n], ts[j2]);
            atomicAdd(&SS2[n], ts2[j2]);
        }
        __syncthreads();
        if(tid < 128){
            atomicAdd(&statout[tid], SS[tid]);
            atomicAdd(&statout[128+tid], SS2[tid]);
        }
    }
}

// ============ launch ============
extern "C" void kernel_launch(void* const* d_in, const int* in_sizes, int n_in,
                              void* d_out, int out_size, void* d_ws, size_t ws_size,
                              hipStream_t stream) {
    const float* x       = (const float*)d_in[0];
    const float* enc_w0  = (const float*)d_in[1];
    const float* enc_b0  = (const float*)d_in[2];
    const float* enc_w1  = (const float*)d_in[3];
    const float* pos     = (const float*)d_in[4];
    const float* n0w     = (const float*)d_in[5];
    const float* n0b     = (const float*)d_in[6];
    const float* w0      = (const float*)d_in[7];
    const float* w1      = (const float*)d_in[8];
    const float* wout    = (const float*)d_in[9];
    const float* isw     = (const float*)d_in[10];
    const float* isb     = (const float*)d_in[11];
    const float* n1w     = (const float*)d_in[12];
    const float* n1b     = (const float*)d_in[13];
    const float* fc1w    = (const float*)d_in[14];
    const float* fc1b    = (const float*)d_in[15];
    const float* fc2w    = (const float*)d_in[16];
    const float* fc2b    = (const float*)d_in[17];
    const float* dec_w0  = (const float*)d_in[18];
    const float* dec_b0  = (const float*)d_in[19];
    const float* dec_w1  = (const float*)d_in[20];
    float* out = (float*)d_out;

    u16* ws = (u16*)d_ws;
    size_t off = 0;
    auto al = [&](size_t n){ u16* p = ws + off; off += (n + 63) & ~(size_t)63; return p; };
    u16* TWF  = al(147456);
    u16* THF  = al(196608);
    u16* THI  = al(147456);
    u16* TWI  = al(147456);
    u16* W0P  = al(524288);
    u16* W1P  = al(1048576);
    u16* WOP  = al(524288);
    u16* ISWP = al(65536);
    u16* FC1P = al(131072);
    u16* FC2P = al(131072);
    u16* EW1P = al(16384);
    u16* DW0P = al(20480);
    u16* POSP = al((size_t)NPAD*128);
    u16* XT2  = al((size_t)NPAD*32);
    u16* CURP = al((size_t)NPAD*128);
    u16* XNP  = al((size_t)NPAD*128);
    u16* YP   = al((size_t)NPAD*128);
    u16* XNC  = al((size_t)24576*384);
    u16* A2b  = al((size_t)24576*384);
    u16* A3b  = al((size_t)36864*256);
    u16* A4b  = al((size_t)24576*384);
    u16* BIG  = al((size_t)NPAD*128);
    u16* IST  = al(5120);
    float* ISTAT = (float*)IST;
    u16* A5b = A2b;
    u16* ENC = BIG;

    dim3 blk(256);
    k_zero<<<dim3(4608), blk, 0, stream>>>(XNC, (long)24576*384);
    k_zero<<<dim3(3),    blk, 0, stream>>>(IST, 5120);

    // packs
    k_pack_twf<<<dim3((147456+255)/256), blk, 0, stream>>>(TWF);
    k_pack_thf<<<dim3((196608+255)/256), blk, 0, stream>>>(THF);
    k_pack_thi<<<dim3((147456+255)/256), blk, 0, stream>>>(THI);
    k_pack_twi<<<dim3((147456+255)/256), blk, 0, stream>>>(TWI);
    k_pack_cw<<<dim3((131072+255)/256,1,4), blk, 0, stream>>>(w0,   W0P, 128, 256, 2*128*256, 131072);
    k_pack_cw<<<dim3((262144+255)/256,1,4), blk, 0, stream>>>(w1,   W1P, 256, 256, 2*256*256, 262144);
    k_pack_cw<<<dim3((131072+255)/256,1,4), blk, 0, stream>>>(wout, WOP, 256, 128, 2*256*128, 131072);
    k_pack_rw<<<dim3((16384+255)/256,1,4),  blk, 0, stream>>>(isw,  ISWP, 128, 128, 16, 128*128, 16384);
    k_pack_rw<<<dim3((32768+255)/256,1,4),  blk, 0, stream>>>(fc1w, FC1P, 256, 128, 16, 256*128, 32768);
    k_pack_rw<<<dim3((32768+255)/256,1,4),  blk, 0, stream>>>(fc2w, FC2P, 128, 256, 32, 128*256, 32768);
    k_pack_rw<<<dim3((16384+255)/256,1,1),  blk, 0, stream>>>(enc_w1, EW1P, 128, 128, 16, 0, 0);
    k_pack_rw<<<dim3((20480+255)/256,1,1),  blk, 0, stream>>>(dec_w0, DW0P, 128, 130, 20, 0, 0);
    k_post<<<dim3(1019), blk, 0, stream>>>(pos, POSP);
    k_xt2 <<<dim3((NP+255)/256), blk, 0, stream>>>(x, XT2);

    const u16* nu = nullptr;
    const float* nf = nullptr;
    const int BIGV = 1<<28;

    // encoder (+ stats for layer-0 norm0)
    k_enc0<<<dim3((NP*16+255)/256), blk, 0, stream>>>(x, enc_w0, enc_b0, ENC);
    k_gemm<4,false,true><<<dim3(1,510), blk, 0, stream>>>(
        ENC, ENC, BIGV, 128, 128, EW1P, 1024, CURP, 128, nf, POSP,
        ISTAT + 0, NP, 128, 0);

    for(int l=0; l<4; l++){
        float* st0 = ISTAT + (2*l)*256;
        float* st1 = ISTAT + (2*l+1)*256;
        float* st0n = ISTAT + (2*l+2)*256;
        k_apply_t<<<dim3(1019), blk, 0, stream>>>(CURP, XNP, XNC, st0, n0w+l*128, n0b+l*128);
        k_gemmw<1><<<dim3(512), dim3(512), 0, stream>>>(XNC, TWF, A2b);
        k_gemmw<2><<<dim3(512), dim3(512), 0, stream>>>(A2b, THF, A3b);
        k_smlp<<<dim3(1152), dim3(512), 0, stream>>>(A3b,
            W0P + (size_t)l*131072, W1P + (size_t)l*262144, WOP + (size_t)l*131072, A4b);
        k_gemmw<1><<<dim3(512), dim3(512), 0, stream>>>(A4b, THI, A5b);
        k_gemmw<5><<<dim3(483), dim3(512), 0, stream>>>(A5b, TWI, YP);
        k_gemm<4,false,true><<<dim3(1,510), blk, 0, stream>>>(
            XNP, XNP, BIGV, 128, 128, ISWP + (size_t)l*16384, 1024, CURP, 128,
            isb+l*128, YP, st1, NP, 128, 0);
        k_pmlp<<<dim3(510), dim3(512), 0, stream>>>(CURP,
            FC1P + (size_t)l*32768, FC2P + (size_t)l*32768,
            fc1b + l*256, fc2b + l*128,
            st1, n1w + l*128, n1b + l*128, XNP, CURP, st0n);
    }
    k_gemm<5,true,false><<<dim3(1,510), blk, 0, stream>>>(
        CURP, XT2, 128, 128, 32, DW0P, 1024, XNP, 128, dec_b0, nu,
        (float*)nullptr, NP, 128, 1);
    k_dec1<<<dim3((NP+255)/256), blk, 0, stream>>>(XNP, dec_w1, out);
}

// Round 18
// 1238.459 us; speedup vs baseline: 1.3356x; 1.0328x over previous
//
#include <hip/hip_runtime.h>
#include <math.h>

#define NP 65160        // 181*360
#define NPAD 65280

typedef unsigned short u16;
typedef __attribute__((ext_vector_type(8))) short bf16x8;
typedef __attribute__((ext_vector_type(8))) unsigned short us8;
typedef __attribute__((ext_vector_type(4))) float f32x4;

__device__ __forceinline__ u16 f2bf(float f){
    unsigned u = __builtin_bit_cast(unsigned, f);
    return (u16)((u + 0x7FFFu + ((u>>16)&1u)) >> 16);
}
__device__ __forceinline__ float bf2f(u16 h){
    unsigned u = ((unsigned)h)<<16;
    return __builtin_bit_cast(float, u);
}
// tanh-form gelu, overflow-safe: t = 1 - 2/(e+1) saturates (never NaN)
__device__ __forceinline__ float gelu_f(float x){
    float z = 0.7978845608028654f*(x + 0.044715f*x*x*x);
    float e = __expf(2.0f*z);
    float t = 1.0f - 2.0f/(e + 1.0f);
    return 0.5f*x*(1.0f + t);
}

// ============ consolidated prep: packs + pos + xt2 + enc0 + pad/stat zero ====
// block ranges:
//  [0,576) twf | [576,1344) thf | [1344,1920) thi | [1920,2496) twi
//  [2496,4544) cw w0 | [4544,8640) cw w1 | [8640,10688) cw wout
//  [10688,10944) rw isw | [10944,11456) rw fc1 | [11456,11968) rw fc2
//  [11968,12032) rw enc_w1 | [12032,12112) rw dec_w0
//  [12112,13131) pos->POSP | [13131,13386) xt2 | [13386,17459) enc0
//  [17459,17723) XNC pad zero | [17723,17726) IST zero
__global__ __launch_bounds__(256) void k_prep(
    u16* __restrict__ TWF, u16* __restrict__ THF, u16* __restrict__ THI, u16* __restrict__ TWI,
    const float* __restrict__ w0, u16* __restrict__ W0P,
    const float* __restrict__ w1, u16* __restrict__ W1P,
    const float* __restrict__ wout, u16* __restrict__ WOP,
    const float* __restrict__ isw, u16* __restrict__ ISWP,
    const float* __restrict__ fc1w, u16* __restrict__ FC1P,
    const float* __restrict__ fc2w, u16* __restrict__ FC2P,
    const float* __restrict__ enc_w1, u16* __restrict__ EW1P,
    const float* __restrict__ dec_w0, u16* __restrict__ DW0P,
    const float* __restrict__ pos, u16* __restrict__ POSP,
    const float* __restrict__ x, u16* __restrict__ XT2,
    const float* __restrict__ enc_w0, const float* __restrict__ enc_b0, u16* __restrict__ ENC,
    u16* __restrict__ XNC, u16* __restrict__ IST)
{
    __shared__ u16 T[128*72];
    int bid = blockIdx.x;
    int t = threadIdx.x;
    const float TP = 6.28318530717958647692f;
    const float inv = 1.0f/sqrtf(65160.0f);

    if(bid < 576){                         // TWF [48][384][8]: k=w, n=2kw+q
        int i = bid*256 + t;
        int e = i&7, n = (i>>3)%384, kg = i/(384*8);
        int k = kg*8+e, kw = n>>1, q = n&1;
        float v = 0.0f;
        if(k < 360 && kw < 181){
            float th = TP*(float)((k*kw)%360)/360.0f;
            v = q ? -sinf(th)*inv : cosf(th)*inv;
        }
        TWF[i] = f2bf(v);
    } else if(bid < 1344){                 // THF [64][384][8]: k=2h+q, n=2kh+p
        int i = (bid-576)*256 + t;
        int e = i&7, n = (i>>3)%384, kg = i/(384*8);
        int k = kg*8+e;
        float v = 0.0f;
        if(k < 362 && n < 362){
            int h = k>>1, q = k&1, kh = n>>1, p = n&1;
            float th = TP*(float)((h*kh)%181)/181.0f;
            float c = cosf(th), s = sinf(th);
            v = (q==0) ? (p==0? c : -s) : (p==0? s : c);
        }
        THF[i] = f2bf(v);
    } else if(bid < 1920){                 // THI [48][384][8]: k=2kh+p, n=2h+q
        int i = (bid-1344)*256 + t;
        int e = i&7, n = (i>>3)%384, kg = i/(384*8);
        int k = kg*8+e;
        float v = 0.0f;
        if(k < 362 && n < 362){
            int kh = k>>1, p = k&1, h = n>>1, q = n&1;
            float th = TP*(float)((kh*h)%181)/181.0f;
            float c = cosf(th), s = sinf(th);
            v = (q==0) ? (p==0? c : -s) : (p==0? s : c);
        }
        THI[i] = f2bf(v);
    } else if(bid < 2496){                 // TWI [48][384][8]: k=2kw+q, n=w
        int i = (bid-1920)*256 + t;
        int e = i&7, n = (i>>3)%384, kg = i/(384*8);
        int k = kg*8+e, kw = k>>1, q = k&1;
        float v = 0.0f;
        if(k < 362 && n < 360){
            float eps = (kw==0 || kw==180) ? 1.0f : 2.0f;
            float th = TP*(float)((n*kw)%360)/360.0f;
            v = q ? -eps*sinf(th)*inv : eps*cosf(th)*inv;
        }
        TWI[i] = f2bf(v);
    } else if(bid < 4544){                 // cw w0: CIN=128,COUT=256
        int b = bid - 2496;
        int z = b >> 9, i = (b & 511)*256 + t;
        const int CIN=128, COUT=256, Npad=512;
        int e = i&7, n = (i>>3)%Npad, kg = i/(Npad*8);
        int k = kg*8+e, ci = k>>1, q = k&1, co = n>>1, p = n&1;
        const float* src = w0 + (size_t)z*2*CIN*COUT;
        float re = src[ci*COUT + co];
        float im = src[CIN*COUT + ci*COUT + co];
        float v = (p==0) ? (q==0? re : -im) : (q==0? im : re);
        W0P[(size_t)z*131072 + i] = f2bf(v);
    } else if(bid < 8640){                 // cw w1: CIN=256,COUT=256
        int b = bid - 4544;
        int z = b >> 10, i = (b & 1023)*256 + t;
        const int CIN=256, COUT=256, Npad=512;
        int e = i&7, n = (i>>3)%Npad, kg = i/(Npad*8);
        int k = kg*8+e, ci = k>>1, q = k&1, co = n>>1, p = n&1;
        const float* src = w1 + (size_t)z*2*CIN*COUT;
        float re = src[ci*COUT + co];
        float im = src[CIN*COUT + ci*COUT + co];
        float v = (p==0) ? (q==0? re : -im) : (q==0? im : re);
        W1P[(size_t)z*262144 + i] = f2bf(v);
    } else if(bid < 10688){                // cw wout: CIN=256,COUT=128
        int b = bid - 8640;
        int z = b >> 9, i = (b & 511)*256 + t;
        const int CIN=256, COUT=128, Npad=256;
        int e = i&7, n = (i>>3)%Npad, kg = i/(Npad*8);
        int k = kg*8+e, ci = k>>1, q = k&1, co = n>>1, p = n&1;
        const float* src = wout + (size_t)z*2*CIN*COUT;
        float re = src[ci*COUT + co];
        float im = src[CIN*COUT + ci*COUT + co];
        float v = (p==0) ? (q==0? re : -im) : (q==0? im : re);
        WOP[(size_t)z*131072 + i] = f2bf(v);
    } else if(bid < 10944){                // rw isw: Nn=128,Ks=128,KG=16
        int b = bid - 10688;
        int z = b >> 6, i = (b & 63)*256 + t;
        int e = i&7, n = (i>>3)%128, kg = i/(128*8);
        int k = kg*8+e;
        float v = (k < 128) ? isw[(size_t)z*16384 + n*128 + k] : 0.0f;
        ISWP[(size_t)z*16384 + i] = f2bf(v);
    } else if(bid < 11456){                // rw fc1: Nn=256,Ks=128,KG=16
        int b = bid - 10944;
        int z = b >> 7, i = (b & 127)*256 + t;
        int e = i&7, n = (i>>3)%256, kg = i/(256*8);
        int k = kg*8+e;
        float v = (k < 128) ? fc1w[(size_t)z*32768 + n*128 + k] : 0.0f;
        FC1P[(size_t)z*32768 + i] = f2bf(v);
    } else if(bid < 11968){                // rw fc2: Nn=128,Ks=256,KG=32
        int b = bid - 11456;
        int z = b >> 7, i = (b & 127)*256 + t;
        int e = i&7, n = (i>>3)%128, kg = i/(128*8);
        int k = kg*8+e;
        float v = (k < 256) ? fc2w[(size_t)z*32768 + n*256 + k] : 0.0f;
        FC2P[(size_t)z*32768 + i] = f2bf(v);
    } else if(bid < 12032){                // rw enc_w1: Nn=128,Ks=128,KG=16
        int i = (bid-11968)*256 + t;
        int e = i&7, n = (i>>3)%128, kg = i/(128*8);
        int k = kg*8+e;
        float v = (k < 128) ? enc_w1[n*128 + k] : 0.0f;
        EW1P[i] = f2bf(v);
    } else if(bid < 12112){                // rw dec_w0: Nn=128,Ks=130,KG=20
        int i = (bid-12032)*256 + t;
        int e = i&7, n = (i>>3)%128, kg = i/(128*8);
        int k = kg*8+e;
        float v = (k < 130) ? dec_w0[n*130 + k] : 0.0f;
        DW0P[i] = f2bf(v);
    } else if(bid < 13131){                // pos f32 [128][NP] -> POSP [pt][128]
        int p0 = (bid-12112)*64;
        int c = t>>1, half = t&1;
        int pbase = p0 + half*32;
        #pragma unroll
        for(int jj=0;jj<4;jj++){
            int pp = pbase + jj*8;
            us8 v = {0,0,0,0,0,0,0,0};
            if(pp + 8 <= NP){
                #pragma unroll
                for(int j=0;j<8;j++) v[j] = f2bf(pos[(size_t)c*NP + pp + j]);
            }
            *(us8*)(&T[c*72 + half*32 + jj*8]) = v;
        }
        __syncthreads();
        int pl = t>>2, cc = (t&3)*32;
        int p = p0 + pl;
        if(p < NP){
            #pragma unroll
            for(int jj=0;jj<4;jj++){
                us8 o;
                #pragma unroll
                for(int j=0;j<8;j++) o[j] = T[(cc+jj*8+j)*72 + pl];
                *(us8*)(POSP + (size_t)p*128 + cc + jj*8) = o;
            }
        }
    } else if(bid < 13386){                // xt2
        int p = (bid-13131)*256 + t;
        if(p < NP){
            us8 z = {0,0,0,0,0,0,0,0};
            z[0] = f2bf(x[p]); z[1] = f2bf(x[NP+p]);
            *(us8*)(XT2 + (size_t)p*32) = z;
            us8 z2 = {0,0,0,0,0,0,0,0};
            *(us8*)(XT2 + (size_t)p*32 + 8)  = z2;
            *(us8*)(XT2 + (size_t)p*32 + 16) = z2;
            *(us8*)(XT2 + (size_t)p*32 + 24) = z2;
        }
    } else if(bid < 17459){                // enc0
        int i = (bid-13386)*256 + t;
        if(i < NP*16){
            int p = i>>4, c8 = (i&15)*8;
            float x0 = x[p], x1 = x[NP+p];
            us8 o;
            #pragma unroll
            for(int j=0;j<8;j++){
                int e = c8+j;
                float v = enc_w0[e*2]*x0 + enc_w0[e*2+1]*x1 + enc_b0[e];
                o[j] = f2bf(gelu_f(v));
            }
            *(us8*)(ENC + (size_t)p*128 + c8) = o;
        }
    } else if(bid < 17723){                // XNC pad rows zero: c*192+h, h in [181,192)
        int f = (bid-17459)*256 + t;       // us8 units
        if(f < 67584){
            int c = f / 528;               // 11*48
            int r = f - c*528;
            int hh = r / 48, w8 = r - hh*48;
            us8 z = {0,0,0,0,0,0,0,0};
            *(us8*)(XNC + ((size_t)(c*192 + 181 + hh))*384 + w8*8) = z;
        }
    } else {                               // IST zero (5120 u16)
        int i = ((bid-17723)*256 + t)*8;
        if(i + 8 <= 5120){
            us8 z = {0,0,0,0,0,0,0,0};
            *(us8*)(IST + i) = z;
        }
    }
}

__global__ void k_dec1(const u16* __restrict__ hid, const float* __restrict__ w,
                       float* __restrict__ out){
    int p = blockIdx.x*256+threadIdx.x; if(p >= NP) return;
    float a0=0.0f, a1=0.0f;
    #pragma unroll 4
    for(int k8=0;k8<16;k8++){
        us8 v = *(const us8*)(hid + (size_t)p*128 + k8*8);
        #pragma unroll
        for(int j=0;j<8;j++){
            float f = bf2f(v[j]);
            a0 = fmaf(w[k8*8+j], f, a0);
            a1 = fmaf(w[128+k8*8+j], f, a1);
        }
    }
    out[p] = a0; out[NP+p] = a1;
}

// apply norm -> XNP [pt][128]; also XNC[(c*192+h)*384 + w]
__global__ __launch_bounds__(256) void k_apply_t(
    const u16* __restrict__ X, u16* __restrict__ outp, u16* __restrict__ outc,
    const float* __restrict__ stat, const float* __restrict__ gw, const float* __restrict__ gb)
{
    __shared__ u16 T[128][72];
    __shared__ float SA_[128], SB_[128];
    int t = threadIdx.x;
    if(t < 128){
        float mu = stat[t]*(1.0f/(float)NP);
        float var = stat[128+t]*(1.0f/(float)NP) - mu*mu;
        var = fmaxf(var, 0.0f);
        float rstd = 1.0f/sqrtf(var + 1e-6f);
        float a = rstd*gw[t];
        SA_[t] = a; SB_[t] = gb[t] - mu*a;
    }
    __syncthreads();
    int p0 = blockIdx.x*64;
    int pl = t>>2, cc = (t&3)*32;
    int p = p0 + pl;
    if(p < NP){
        #pragma unroll
        for(int jj=0;jj<4;jj++){
            us8 v = *(const us8*)(X + (size_t)p*128 + cc + jj*8);
            us8 o;
            #pragma unroll
            for(int j=0;j<8;j++){
                int c = cc + jj*8 + j;
                o[j] = f2bf(fmaf(bf2f(v[j]), SA_[c], SB_[c]));
            }
            *(us8*)(outp + (size_t)p*128 + cc + jj*8) = o;
            #pragma unroll
            for(int j=0;j<8;j++) T[cc+jj*8+j][pl] = o[j];
        }
    }
    __syncthreads();
    int c = t>>1, half = t&1;
    int pbase = p0 + half*32;
    #pragma unroll
    for(int jj=0;jj<4;jj++){
        int pp = pbase + jj*8;
        if(pp + 8 <= NP){
            int hh = pp/360, ww = pp - hh*360;
            *(us8*)(outc + ((size_t)c*192 + hh)*384 + ww) = *(const us8*)(&T[c][half*32 + jj*8]);
        }
    }
}

// ============ fused spectral channel-MLP (S3+S4+S5), 32 rows/block ============
__global__ __launch_bounds__(512, 4) void k_smlp(
    const u16* __restrict__ A3, const u16* __restrict__ W0,
    const u16* __restrict__ W1, const u16* __restrict__ WO,
    u16* __restrict__ A4)
{
    __shared__ u16 Hs0[32*520];
    __shared__ u16 Hs1[32*520];
    int tid = threadIdx.x;
    int l = tid & 63, wn = tid >> 6;
    int lm = l & 15, kg = l >> 4;
    int m0 = blockIdx.x * 32;

    f32x4 acc[2][4];
    #pragma unroll
    for(int f=0;f<2;f++)
        #pragma unroll
        for(int j2=0;j2<4;j2++) acc[f][j2] = (f32x4){0.f,0.f,0.f,0.f};
    {
        const u16* ap = A3 + (size_t)(m0 + lm)*256 + kg*8;
        #pragma unroll
        for(int k0=0;k0<256;k0+=32){
            bf16x8 af[2];
            #pragma unroll
            for(int f=0;f<2;f++) af[f] = *(const bf16x8*)(ap + f*16*256 + k0);
            const u16* Bb = W0 + (size_t)((k0>>3)+kg)*4096 + (wn*64+lm)*8;
            #pragma unroll
            for(int j2=0;j2<4;j2++){
                bf16x8 bf = *(const bf16x8*)(Bb + j2*128);
                #pragma unroll
                for(int f=0;f<2;f++)
                    acc[f][j2] = __builtin_amdgcn_mfma_f32_16x16x32_bf16(af[f], bf, acc[f][j2], 0,0,0);
            }
        }
    }
    #pragma unroll
    for(int f=0;f<2;f++)
        #pragma unroll
        for(int j2=0;j2<4;j2++)
            #pragma unroll
            for(int r=0;r<4;r++){
                int row = f*16 + kg*4 + r;
                int col = wn*64 + j2*16 + lm;
                float v = acc[f][j2][r];
                if(!(col&1)) v = fmaxf(v, 0.0f);
                Hs0[row*520 + col] = f2bf(v);
            }
    __syncthreads();
    #pragma unroll
    for(int f=0;f<2;f++)
        #pragma unroll
        for(int j2=0;j2<4;j2++) acc[f][j2] = (f32x4){0.f,0.f,0.f,0.f};
    #pragma unroll 2
    for(int k0=0;k0<512;k0+=32){
        bf16x8 af[2];
        #pragma unroll
        for(int f=0;f<2;f++) af[f] = *(const bf16x8*)(&Hs0[(f*16+lm)*520 + k0 + kg*8]);
        const u16* Bb = W1 + (size_t)((k0>>3)+kg)*4096 + (wn*64+lm)*8;
        #pragma unroll
        for(int j2=0;j2<4;j2++){
            bf16x8 bf = *(const bf16x8*)(Bb + j2*128);
            #pragma unroll
            for(int f=0;f<2;f++)
                acc[f][j2] = __builtin_amdgcn_mfma_f32_16x16x32_bf16(af[f], bf, acc[f][j2], 0,0,0);
        }
    }
    #pragma unroll
    for(int f=0;f<2;f++)
        #pragma unroll
        for(int j2=0;j2<4;j2++)
            #pragma unroll
            for(int r=0;r<4;r++){
                int row = f*16 + kg*4 + r;
                int col = wn*64 + j2*16 + lm;
                float v = acc[f][j2][r];
                if(!(col&1)) v = fmaxf(v, 0.0f);
                Hs1[row*520 + col] = f2bf(v);
            }
    __syncthreads();
    f32x4 acc3[2][2];
    #pragma unroll
    for(int f=0;f<2;f++)
        #pragma unroll
        for(int j2=0;j2<2;j2++) acc3[f][j2] = (f32x4){0.f,0.f,0.f,0.f};
    #pragma unroll 2
    for(int k0=0;k0<512;k0+=32){
        bf16x8 af[2];
        #pragma unroll
        for(int f=0;f<2;f++) af[f] = *(const bf16x8*)(&Hs1[(f*16+lm)*520 + k0 + kg*8]);
        const u16* Bb = WO + (size_t)((k0>>3)+kg)*2048 + (wn*32+lm)*8;
        #pragma unroll
        for(int j2=0;j2<2;j2++){
            bf16x8 bf = *(const bf16x8*)(Bb + j2*128);
            #pragma unroll
            for(int f=0;f<2;f++)
                acc3[f][j2] = __builtin_amdgcn_mfma_f32_16x16x32_bf16(af[f], bf, acc3[f][j2], 0,0,0);
        }
    }
    #pragma unroll
    for(int f=0;f<2;f++)
        #pragma unroll
        for(int j2=0;j2<2;j2++)
            #pragma unroll
            for(int r=0;r<4;r++){
                int row = f*16 + kg*4 + r;
                int col = wn*32 + j2*16 + lm;
                Hs0[row*258 + col] = f2bf(acc3[f][j2][r]);
            }
    __syncthreads();
    int kw = m0 / 192;
    int kh0 = m0 - kw*192;
    int c = tid >> 2, q = tid & 3;
    long base = ((long)(c*192 + kw))*384 + 2*(kh0 + q*8);
    #pragma unroll
    for(int jj=0;jj<2;jj++){
        us8 v;
        #pragma unroll
        for(int i=0;i<4;i++){
            v[2*i]   = Hs0[(q*8 + jj*4 + i)*258 + 2*c];
            v[2*i+1] = Hs0[(q*8 + jj*4 + i)*258 + 2*c+1];
        }
        *(us8*)(A4 + base + jj*8) = v;
    }
}

// ============ fused spatial MLP: norm1+fc1+gelu+fc2+skip + stats, 128 rows ====
__global__ __launch_bounds__(512, 4) void k_pmlp(
    const u16* __restrict__ A, const u16* __restrict__ FC1, const u16* __restrict__ FC2,
    const float* __restrict__ b1, const float* __restrict__ b2,
    const float* __restrict__ stat, const float* __restrict__ gw, const float* __restrict__ gb,
    const u16* __restrict__ addb, u16* __restrict__ OUT, float* __restrict__ statout)
{
    __shared__ u16 Hs[128][264];
    __shared__ float SA_[128], SB_[128];
    __shared__ float SS[128], SS2[128];
    int tid = threadIdx.x;
    int l = tid & 63, wv = tid >> 6;
    int wm = wv >> 1, wn = wv & 1;
    int lm = l & 15, kg = l >> 4;
    int m0 = blockIdx.x * 128;
    if(tid < 128){
        float mu = stat[tid]*(1.0f/(float)NP);
        float var = stat[128+tid]*(1.0f/(float)NP) - mu*mu;
        var = fmaxf(var, 0.0f);
        float rstd = 1.0f/sqrtf(var + 1e-6f);
        float a = rstd*gw[tid];
        SA_[tid] = a; SB_[tid] = gb[tid] - mu*a;
        SS[tid] = 0.0f; SS2[tid] = 0.0f;
    }
    __syncthreads();

    f32x4 acc[2][8];
    #pragma unroll
    for(int f=0;f<2;f++)
        #pragma unroll
        for(int j=0;j<8;j++) acc[f][j] = (f32x4){0.f,0.f,0.f,0.f};
    {
        const u16* ap = A + (size_t)(m0 + wm*32 + lm)*128 + kg*8;
        #pragma unroll
        for(int k0=0;k0<128;k0+=32){
            bf16x8 af[2];
            #pragma unroll
            for(int f=0;f<2;f++){
                us8 raw = *(const us8*)(ap + f*16*128 + k0);
                #pragma unroll
                for(int j=0;j<8;j++){
                    int ch = kg*8 + k0 + j;
                    af[f][j] = (short)f2bf(fmaf(bf2f(raw[j]), SA_[ch], SB_[ch]));
                }
            }
            const u16* Bb = FC1 + (size_t)((k0>>3)+kg)*2048 + (wn*128+lm)*8;
            #pragma unroll
            for(int j2=0;j2<8;j2++){
                bf16x8 bf = *(const bf16x8*)(Bb + j2*128);
                #pragma unroll
                for(int f=0;f<2;f++)
                    acc[f][j2] = __builtin_amdgcn_mfma_f32_16x16x32_bf16(af[f], bf, acc[f][j2], 0,0,0);
            }
        }
    }
    #pragma unroll
    for(int f=0;f<2;f++)
        #pragma unroll
        for(int j2=0;j2<8;j2++)
            #pragma unroll
            for(int r=0;r<4;r++){
                int row = wm*32 + f*16 + kg*4 + r;
                int col = wn*128 + j2*16 + lm;
                Hs[row][col] = f2bf(gelu_f(acc[f][j2][r] + b1[col]));
            }
    __syncthreads();
    f32x4 acc2[2][4];
    #pragma unroll
    for(int f=0;f<2;f++)
        #pragma unroll
        for(int j=0;j<4;j++) acc2[f][j] = (f32x4){0.f,0.f,0.f,0.f};
    #pragma unroll
    for(int k0=0;k0<256;k0+=32){
        bf16x8 af[2];
        #pragma unroll
        for(int f=0;f<2;f++)
            af[f] = *(const bf16x8*)(&Hs[wm*32 + f*16 + lm][k0 + kg*8]);
        const u16* Bb = FC2 + (size_t)((k0>>3)+kg)*1024 + (wn*64+lm)*8;
        #pragma unroll
        for(int j2=0;j2<4;j2++){
            bf16x8 bf = *(const bf16x8*)(Bb + j2*128);
            #pragma unroll
            for(int f=0;f<2;f++)
                acc2[f][j2] = __builtin_amdgcn_mfma_f32_16x16x32_bf16(af[f], bf, acc2[f][j2], 0,0,0);
        }
    }
    float ts[4] = {0.f,0.f,0.f,0.f}, ts2[4] = {0.f,0.f,0.f,0.f};
    #pragma unroll
    for(int f=0;f<2;f++)
        #pragma unroll
        for(int j2=0;j2<4;j2++)
            #pragma unroll
            for(int r=0;r<4;r++){
                int row = wm*32 + f*16 + kg*4 + r;
                long p = m0 + row;
                if(p < NP){
                    int n = wn*64 + j2*16 + lm;
                    float v = acc2[f][j2][r] + b2[n] + bf2f(addb[p*128 + n]);
                    u16 hv = f2bf(v);
                    OUT[p*128 + n] = hv;
                    float vq = bf2f(hv);
                    ts[j2] += vq; ts2[j2] = fmaf(vq, vq, ts2[j2]);
                }
            }
    #pragma unroll
    for(int j2=0;j2<4;j2++){
        int n = wn*64 + j2*16 + lm;
        atomicAdd(&SS[n], ts[j2]);
        atomicAdd(&SS2[n], ts2[j2]);
    }
    __syncthreads();
    if(tid < 128){
        atomicAdd(&statout[tid], SS[tid]);
        atomicAdd(&statout[128+tid], SS2[tid]);
    }
}

// ============ WIDE spectral GEMM: 48 rows/block, full N=384, 3 blocks/CU ====
template<int TMODE>
__global__ __launch_bounds__(512, 6) void k_gemmw(
    const u16* __restrict__ A, const u16* __restrict__ B, u16* __restrict__ C)
{
    __shared__ u16 Ts[48*392];
    int tid = threadIdx.x;
    int l = tid & 63, wv = tid >> 6;
    int lm = l & 15, kg = l >> 4;
    int m0 = blockIdx.x * 48;

    const u16* ap = A + (size_t)(m0 + lm)*384 + kg*8;
    int bn[3];
    #pragma unroll
    for(int j2=0;j2<3;j2++) bn[j2] = (wv*48 + j2*16 + lm)*8 + kg*3072;

    f32x4 acc[3][3];
    #pragma unroll
    for(int f=0;f<3;f++)
        #pragma unroll
        for(int j2=0;j2<3;j2++) acc[f][j2] = (f32x4){0.f,0.f,0.f,0.f};

    #pragma unroll
    for(int ks=0; ks<12; ks++){
        const int k0 = ks*32;
        bf16x8 af[3];
        #pragma unroll
        for(int f=0;f<3;f++) af[f] = *(const bf16x8*)(ap + f*16*384 + k0);
        const u16* Bb = B + (size_t)(ks*4)*3072;
        bf16x8 bf[3];
        #pragma unroll
        for(int j2=0;j2<3;j2++) bf[j2] = *(const bf16x8*)(Bb + bn[j2]);
        #pragma unroll
        for(int f=0;f<3;f++)
            #pragma unroll
            for(int j2=0;j2<3;j2++)
                acc[f][j2] = __builtin_amdgcn_mfma_f32_16x16x32_bf16(af[f], bf[j2], acc[f][j2], 0,0,0);
    }

    #pragma unroll
    for(int f=0;f<3;f++)
        #pragma unroll
        for(int j2=0;j2<3;j2++)
            #pragma unroll
            for(int r=0;r<4;r++)
                Ts[(f*16 + kg*4 + r)*392 + wv*48 + j2*16 + lm] = f2bf(acc[f][j2][r]);
    __syncthreads();

    if constexpr (TMODE != 5){
        #pragma unroll
        for(int it=0; it<5; it++){
            int g = tid + it*512;
            if(g >= 2304) break;
            int gn = g % 192, gm = g / 192;
            int ml = gm*4, nl = gn*2;
            int mg = m0 + ml, ng = nl;
            long base;
            if constexpr (TMODE == 1){
                int c = (int)(((unsigned)mg*43691u)>>23);
                int sub = mg - c*192;
                base = ((long)((ng>>1)*128 + c))*384 + 2*sub;
            } else {
                int kw = mg>>7, c = mg&127;
                base = ((long)(kw*192 + (ng>>1)))*256 + 2*c;
            }
            us8 v;
            #pragma unroll
            for(int i=0;i<4;i++){
                v[2*i]   = Ts[(ml+i)*392 + nl];
                v[2*i+1] = Ts[(ml+i)*392 + nl+1];
            }
            *(us8*)(C + base) = v;
        }
    } else {
        #pragma unroll
        for(int it=0; it<5; it++){
            int g = tid + it*512;
            if(g >= 2304) break;
            int nl = g % 384, gm = g / 384;
            int ml = gm*8;
            int mg = m0 + ml;
            if(nl < 360 && mg < 23168){
                int h = mg >> 7;
                long base = ((long)(h*360 + nl))*128 + (mg & 127);
                us8 v;
                #pragma unroll
                for(int j=0;j<8;j++) v[j] = Ts[(ml+j)*392 + nl];
                *(us8*)(C + base) = v;
            }
        }
    }
}

// ============ row-major MFMA GEMM (encoder/skip/decoder), optional fused stats ====
template<int KSTEPS, bool SPLIT, bool STATS>
__global__ __launch_bounds__(256, 2) void k_gemm(
    const u16* __restrict__ A1, const u16* __restrict__ A2, int aksplit, int astr, int a2str,
    const u16* __restrict__ B, int bkstr,
    u16* __restrict__ C, int cstr,
    const float* __restrict__ bias, const u16* __restrict__ addb,
    float* __restrict__ statout,
    int Mvalid, int N, int flags)
{
    __shared__ float SS[128], SS2[128];
    int tid = threadIdx.x;
    int l = tid & 63, wv = tid >> 6;
    int wm = wv >> 1, wn = wv & 1;
    int lm = l & 15, kgl = l >> 4;
    int m0 = blockIdx.y*128 + wm*64;
    int n0 = blockIdx.x*128 + wn*64;

    if constexpr (STATS){
        if(tid < 128){ SS[tid] = 0.0f; SS2[tid] = 0.0f; }
        __syncthreads();
    }

    int ab1[4], ab2[4];
    #pragma unroll
    for(int i2=0;i2<4;i2++){
        int mi = m0 + i2*16 + lm;
        ab1[i2] = mi*astr + kgl*8;
        ab2[i2] = mi*a2str + kgl*8;
    }
    int bn[4];
    #pragma unroll
    for(int j2=0;j2<4;j2++) bn[j2] = (n0 + j2*16 + lm)*8 + kgl*bkstr;

    f32x4 acc[4][4];
    #pragma unroll
    for(int i2=0;i2<4;i2++)
        #pragma unroll
        for(int j2=0;j2<4;j2++)
            acc[i2][j2] = (f32x4){0.0f,0.0f,0.0f,0.0f};

    #pragma unroll
    for(int ks=0; ks<KSTEPS; ks++){
        const int k0 = ks*32;
        bf16x8 af[4];
        if constexpr (SPLIT){
            int kk = k0 + kgl*8;
            bool s1v = kk < aksplit;
            #pragma unroll
            for(int i2=0;i2<4;i2++)
                af[i2] = s1v ? *(const bf16x8*)(A1 + ab1[i2] + k0)
                             : *(const bf16x8*)(A2 + ab2[i2] + k0 - aksplit);
        } else {
            #pragma unroll
            for(int i2=0;i2<4;i2++)
                af[i2] = *(const bf16x8*)(A1 + ab1[i2] + k0);
        }
        const u16* Bb = B + (size_t)(ks*4)*bkstr;
        bf16x8 bf[4];
        #pragma unroll
        for(int j2=0;j2<4;j2++)
            bf[j2] = *(const bf16x8*)(Bb + bn[j2]);
        #pragma unroll
        for(int i2=0;i2<4;i2++)
            #pragma unroll
            for(int j2=0;j2<4;j2++)
                acc[i2][j2] = __builtin_amdgcn_mfma_f32_16x16x32_bf16(af[i2], bf[j2], acc[i2][j2], 0,0,0);
    }

    float ts[4] = {0.f,0.f,0.f,0.f}, ts2[4] = {0.f,0.f,0.f,0.f};
    #pragma unroll
    for(int i2=0;i2<4;i2++){
        #pragma unroll
        for(int r=0;r<4;r++){
            int m = m0 + i2*16 + kgl*4 + r;
            if(m >= Mvalid) continue;
            long mb = (long)m*cstr;
            #pragma unroll
            for(int j2=0;j2<4;j2++){
                int n = n0 + j2*16 + lm;
                if(n >= N) continue;
                float v = acc[i2][j2][r];
                if(bias) v += bias[n];
                if(flags & 1) v = gelu_f(v);
                long ca = mb + n;
                if(addb) v += bf2f(addb[ca]);
                u16 hv = f2bf(v);
                C[ca] = hv;
                if constexpr (STATS){
                    float vq = bf2f(hv);
                    ts[j2] += vq; ts2[j2] = fmaf(vq, vq, ts2[j2]);
                }
            }
        }
    }
    if constexpr (STATS){
        #pragma unroll
        for(int j2=0;j2<4;j2++){
            int n = n0 + j2*16 + lm;
            atomicAdd(&SS[n], ts[j2]);
            atomicAdd(&SS2[n], ts2[j2]);
        }
        __syncthreads();
        if(tid < 128){
            atomicAdd(&statout[tid], SS[tid]);
            atomicAdd(&statout[128+tid], SS2[tid]);
        }
    }
}

// ============ launch ============
extern "C" void kernel_launch(void* const* d_in, const int* in_sizes, int n_in,
                              void* d_out, int out_size, void* d_ws, size_t ws_size,
                              hipStream_t stream) {
    const float* x       = (const float*)d_in[0];
    const float* enc_w0  = (const float*)d_in[1];
    const float* enc_b0  = (const float*)d_in[2];
    const float* enc_w1  = (const float*)d_in[3];
    const float* pos     = (const float*)d_in[4];
    const float* n0w     = (const float*)d_in[5];
    const float* n0b     = (const float*)d_in[6];
    const float* w0      = (const float*)d_in[7];
    const float* w1      = (const float*)d_in[8];
    const float* wout    = (const float*)d_in[9];
    const float* isw     = (const float*)d_in[10];
    const float* isb     = (const float*)d_in[11];
    const float* n1w     = (const float*)d_in[12];
    const float* n1b     = (const float*)d_in[13];
    const float* fc1w    = (const float*)d_in[14];
    const float* fc1b    = (const float*)d_in[15];
    const float* fc2w    = (const float*)d_in[16];
    const float* fc2b    = (const float*)d_in[17];
    const float* dec_w0  = (const float*)d_in[18];
    const float* dec_b0  = (const float*)d_in[19];
    const float* dec_w1  = (const float*)d_in[20];
    float* out = (float*)d_out;

    u16* ws = (u16*)d_ws;
    size_t off = 0;
    auto al = [&](size_t n){ u16* p = ws + off; off += (n + 63) & ~(size_t)63; return p; };
    u16* TWF  = al(147456);
    u16* THF  = al(196608);
    u16* THI  = al(147456);
    u16* TWI  = al(147456);
    u16* W0P  = al(524288);
    u16* W1P  = al(1048576);
    u16* WOP  = al(524288);
    u16* ISWP = al(65536);
    u16* FC1P = al(131072);
    u16* FC2P = al(131072);
    u16* EW1P = al(16384);
    u16* DW0P = al(20480);
    u16* POSP = al((size_t)NPAD*128);
    u16* XT2  = al((size_t)NPAD*32);
    u16* CURP = al((size_t)NPAD*128);
    u16* XNP  = al((size_t)NPAD*128);
    u16* YP   = al((size_t)NPAD*128);
    u16* XNC  = al((size_t)24576*384);
    u16* A2b  = al((size_t)24576*384);
    u16* A3b  = al((size_t)36864*256);
    u16* A4b  = al((size_t)24576*384);
    u16* BIG  = al((size_t)NPAD*128);
    u16* IST  = al(5120);
    float* ISTAT = (float*)IST;
    u16* A5b = A2b;
    u16* ENC = BIG;

    dim3 blk(256);
    const u16* nu = nullptr;
    const float* nf = nullptr;
    const int BIGV = 1<<28;

    // consolidated prep (packs + pos + xt2 + enc0 + pad/stat zero)
    k_prep<<<dim3(17726), blk, 0, stream>>>(
        TWF, THF, THI, TWI,
        w0, W0P, w1, W1P, wout, WOP,
        isw, ISWP, fc1w, FC1P, fc2w, FC2P,
        enc_w1, EW1P, dec_w0, DW0P,
        pos, POSP, x, XT2,
        enc_w0, enc_b0, ENC, XNC, IST);

    // encoder (+ stats for layer-0 norm0)
    k_gemm<4,false,true><<<dim3(1,510), blk, 0, stream>>>(
        ENC, ENC, BIGV, 128, 128, EW1P, 1024, CURP, 128, nf, POSP,
        ISTAT + 0, NP, 128, 0);

    for(int l=0; l<4; l++){
        float* st0 = ISTAT + (2*l)*256;
        float* st1 = ISTAT + (2*l+1)*256;
        float* st0n = ISTAT + (2*l+2)*256;
        k_apply_t<<<dim3(1019), blk, 0, stream>>>(CURP, XNP, XNC, st0, n0w+l*128, n0b+l*128);
        k_gemmw<1><<<dim3(512), dim3(512), 0, stream>>>(XNC, TWF, A2b);
        k_gemmw<2><<<dim3(512), dim3(512), 0, stream>>>(A2b, THF, A3b);
        k_smlp<<<dim3(1152), dim3(512), 0, stream>>>(A3b,
            W0P + (size_t)l*131072, W1P + (size_t)l*262144, WOP + (size_t)l*131072, A4b);
        k_gemmw<1><<<dim3(512), dim3(512), 0, stream>>>(A4b, THI, A5b);
        k_gemmw<5><<<dim3(483), dim3(512), 0, stream>>>(A5b, TWI, YP);
        k_gemm<4,false,true><<<dim3(1,510), blk, 0, stream>>>(
            XNP, XNP, BIGV, 128, 128, ISWP + (size_t)l*16384, 1024, CURP, 128,
            isb+l*128, YP, st1, NP, 128, 0);
        k_pmlp<<<dim3(510), dim3(512), 0, stream>>>(CURP,
            FC1P + (size_t)l*32768, FC2P + (size_t)l*32768,
            fc1b + l*256, fc2b + l*128,
            st1, n1w + l*128, n1b + l*128, XNP, CURP, st0n);
    }
    k_gemm<5,true,false><<<dim3(1,510), blk, 0, stream>>>(
        CURP, XT2, 128, 128, 32, DW0P, 1024, XNP, 128, dec_b0, nu,
        (float*)nullptr, NP, 128, 1);
    k_dec1<<<dim3((NP+255)/256), blk, 0, stream>>>(XNP, dec_w1, out);
}